// Round 2
// baseline (1815.766 us; speedup 1.0000x reference)
//
#include <hip/hip_runtime.h>

// All inputs/outputs fp32 (reference is jnp.float32 throughout).

// ---------------------------------------------------------------------------
// RMSNorm fp32 -> fp32 (in-place safe). One block per row.
// ---------------------------------------------------------------------------
__launch_bounds__(256)
__global__ void rmsnorm_f32(const float* __restrict__ X, const float* __restrict__ w,
                            float* __restrict__ O, int cols)
{
    int r = blockIdx.x, tid = threadIdx.x;
    const float* xr = X + (size_t)r * cols;
    float ss = 0.f;
    for (int j = tid; j < cols; j += 256) { float v = xr[j]; ss += v * v; }
    __shared__ float red[256];
    red[tid] = ss; __syncthreads();
    for (int st = 128; st > 0; st >>= 1) { if (tid < st) red[tid] += red[tid + st]; __syncthreads(); }
    float scale = rsqrtf(red[0] / cols + 1e-6f);
    for (int j = tid; j < cols; j += 256)
        O[(size_t)r * cols + j] = xr[j] * scale * w[j];
}

// ---------------------------------------------------------------------------
// RoPE in-place on fp32 (S, nh*64). pair j: (x0*c - x1*s, x0*s + x1*c)
// ---------------------------------------------------------------------------
__global__ void rope_k(float* __restrict__ X, const float* __restrict__ C,
                       const float* __restrict__ Sn, int nh)
{
    int s = blockIdx.x;
    int n = nh * 32;
    for (int i = threadIdx.x; i < n; i += blockDim.x) {
        int h = i >> 5, j = i & 31;
        float c  = C[s * 32 + j];
        float sn = Sn[s * 32 + j];
        float* p = X + (size_t)s * nh * 64 + h * 64 + 2 * j;
        float x0 = p[0], x1 = p[1];
        p[0] = x0 * c - x1 * sn;
        p[1] = x0 * sn + x1 * c;
    }
}

// ---------------------------------------------------------------------------
// GEMM: C[M,N] = A[M,K] @ W[N,K]^T + bias.  EPI: 0 none, 1 += res (fp32).
// 64x64 tile, BK=16, 256 threads, 4x4 per thread.  M = grid.y*64 exact.
// ---------------------------------------------------------------------------
template<int EPI>
__launch_bounds__(256)
__global__ void gemm_k(const float* __restrict__ A, int lda,
                       const float* __restrict__ W, int ldw,
                       const float* __restrict__ bias,
                       float* __restrict__ C, int ldc, int K,
                       const float* __restrict__ res)
{
    __shared__ float As[16][64];
    __shared__ float Bs[16][64];
    int tid = threadIdx.x;
    int tx = tid & 15, ty = tid >> 4;
    int rowBase = blockIdx.y * 64, colBase = blockIdx.x * 64;
    int lm = tid >> 2;
    int lk = (tid & 3) << 2;
    float acc[4][4] = {};
    for (int k0 = 0; k0 < K; k0 += 16) {
        float4 av = *(const float4*)(A + (size_t)(rowBase + lm) * lda + k0 + lk);
        As[lk + 0][lm] = av.x; As[lk + 1][lm] = av.y;
        As[lk + 2][lm] = av.z; As[lk + 3][lm] = av.w;
        float4 wv = *(const float4*)(W + (size_t)(colBase + lm) * ldw + k0 + lk);
        Bs[lk + 0][lm] = wv.x; Bs[lk + 1][lm] = wv.y;
        Bs[lk + 2][lm] = wv.z; Bs[lk + 3][lm] = wv.w;
        __syncthreads();
#pragma unroll
        for (int kk = 0; kk < 16; ++kk) {
            float a[4], b[4];
#pragma unroll
            for (int i = 0; i < 4; i++) a[i] = As[kk][ty * 4 + i];
#pragma unroll
            for (int j = 0; j < 4; j++) b[j] = Bs[kk][tx * 4 + j];
#pragma unroll
            for (int i = 0; i < 4; i++)
#pragma unroll
                for (int j = 0; j < 4; j++) acc[i][j] += a[i] * b[j];
        }
        __syncthreads();
    }
#pragma unroll
    for (int i = 0; i < 4; i++) {
        int row = rowBase + ty * 4 + i;
#pragma unroll
        for (int j = 0; j < 4; j++) {
            int col = colBase + tx * 4 + j;
            float v = acc[i][j] + bias[col];
            if (EPI == 1) v += res[(size_t)row * ldc + col];
            C[(size_t)row * ldc + col] = v;
        }
    }
}

// ---------------------------------------------------------------------------
// GLU GEMM: C = silu(A@W1^T + b1) * (A@W3^T + b3).  Optional expert gather:
// blockIdx.z = expert; A row m is token lists[e*1024+m], M = counts[e].
// ---------------------------------------------------------------------------
__launch_bounds__(256)
__global__ void gemm_glu(const float* __restrict__ A, int lda,
                         const float* __restrict__ W1b, const float* __restrict__ B1b,
                         const float* __restrict__ W3b, const float* __restrict__ B3b,
                         int ldw, int K, float* __restrict__ Cb, int ldc,
                         size_t wstride, size_t bstride, size_t cstride,
                         const int* __restrict__ lists, const int* __restrict__ counts)
{
    int e = blockIdx.z;
    int cnt = counts ? counts[e] : 1024;
    int rowBase = blockIdx.y * 64;
    if (rowBase >= cnt) return;
    const float* W1 = W1b + (size_t)e * wstride;
    const float* B1 = B1b + (size_t)e * bstride;
    const float* W3 = W3b + (size_t)e * wstride;
    const float* B3 = B3b + (size_t)e * bstride;
    float* C = Cb + (size_t)e * cstride;
    const int* list = lists ? lists + e * 1024 : nullptr;

    __shared__ float As[16][64];
    __shared__ float B1s[16][64];
    __shared__ float B3s[16][64];
    int tid = threadIdx.x;
    int tx = tid & 15, ty = tid >> 4;
    int colBase = blockIdx.x * 64;
    int lm = tid >> 2;
    int lk = (tid & 3) << 2;
    int arow = rowBase + lm;
    int atok = arow;
    if (list) atok = list[arow < cnt ? arow : cnt - 1];
    const float* Arow = A + (size_t)atok * lda;
    float acc1[4][4] = {};
    float acc3[4][4] = {};
    for (int k0 = 0; k0 < K; k0 += 16) {
        float4 av = *(const float4*)(Arow + k0 + lk);
        As[lk + 0][lm] = av.x; As[lk + 1][lm] = av.y;
        As[lk + 2][lm] = av.z; As[lk + 3][lm] = av.w;
        float4 w1v = *(const float4*)(W1 + (size_t)(colBase + lm) * ldw + k0 + lk);
        B1s[lk + 0][lm] = w1v.x; B1s[lk + 1][lm] = w1v.y;
        B1s[lk + 2][lm] = w1v.z; B1s[lk + 3][lm] = w1v.w;
        float4 w3v = *(const float4*)(W3 + (size_t)(colBase + lm) * ldw + k0 + lk);
        B3s[lk + 0][lm] = w3v.x; B3s[lk + 1][lm] = w3v.y;
        B3s[lk + 2][lm] = w3v.z; B3s[lk + 3][lm] = w3v.w;
        __syncthreads();
#pragma unroll
        for (int kk = 0; kk < 16; ++kk) {
            float a[4], p[4], q[4];
#pragma unroll
            for (int i = 0; i < 4; i++) a[i] = As[kk][ty * 4 + i];
#pragma unroll
            for (int j = 0; j < 4; j++) { p[j] = B1s[kk][tx * 4 + j]; q[j] = B3s[kk][tx * 4 + j]; }
#pragma unroll
            for (int i = 0; i < 4; i++)
#pragma unroll
                for (int j = 0; j < 4; j++) {
                    acc1[i][j] += a[i] * p[j];
                    acc3[i][j] += a[i] * q[j];
                }
        }
        __syncthreads();
    }
#pragma unroll
    for (int i = 0; i < 4; i++) {
        int row = rowBase + ty * 4 + i;
        if (row >= cnt) continue;
#pragma unroll
        for (int j = 0; j < 4; j++) {
            int col = colBase + tx * 4 + j;
            float u  = acc1[i][j] + B1[col];
            float v3 = acc3[i][j] + B3[col];
            float sl = u / (1.f + expf(-u));
            C[(size_t)row * ldc + col] = sl * v3;
        }
    }
}

// ---------------------------------------------------------------------------
// MoE down: OUT[tok, n] += gate * (H1[e] @ ew2[e]^T + eb2[e]).  K=512.
// ---------------------------------------------------------------------------
__launch_bounds__(256)
__global__ void gemm_moe_down(const float* __restrict__ H1b,
                              const float* __restrict__ W2b, const float* __restrict__ B2b,
                              float* __restrict__ OUT,
                              const int* __restrict__ lists, const float* __restrict__ glist,
                              const int* __restrict__ counts)
{
    int e = blockIdx.z;
    int cnt = counts[e];
    int rowBase = blockIdx.y * 64;
    if (rowBase >= cnt) return;
    const float* A = H1b + (size_t)e * 1024 * 512;
    const float* W = W2b + (size_t)e * 1024 * 512;
    const float* B = B2b + (size_t)e * 1024;

    __shared__ float As[16][64];
    __shared__ float Bs[16][64];
    int tid = threadIdx.x;
    int tx = tid & 15, ty = tid >> 4;
    int colBase = blockIdx.x * 64;
    int lm = tid >> 2;
    int lk = (tid & 3) << 2;
    float acc[4][4] = {};
    for (int k0 = 0; k0 < 512; k0 += 16) {
        float4 av = *(const float4*)(A + (size_t)(rowBase + lm) * 512 + k0 + lk);
        As[lk + 0][lm] = av.x; As[lk + 1][lm] = av.y;
        As[lk + 2][lm] = av.z; As[lk + 3][lm] = av.w;
        float4 wv = *(const float4*)(W + (size_t)(colBase + lm) * 512 + k0 + lk);
        Bs[lk + 0][lm] = wv.x; Bs[lk + 1][lm] = wv.y;
        Bs[lk + 2][lm] = wv.z; Bs[lk + 3][lm] = wv.w;
        __syncthreads();
#pragma unroll
        for (int kk = 0; kk < 16; ++kk) {
            float a[4], b[4];
#pragma unroll
            for (int i = 0; i < 4; i++) a[i] = As[kk][ty * 4 + i];
#pragma unroll
            for (int j = 0; j < 4; j++) b[j] = Bs[kk][tx * 4 + j];
#pragma unroll
            for (int i = 0; i < 4; i++)
#pragma unroll
                for (int j = 0; j < 4; j++) acc[i][j] += a[i] * b[j];
        }
        __syncthreads();
    }
#pragma unroll
    for (int i = 0; i < 4; i++) {
        int row = rowBase + ty * 4 + i;
        if (row >= cnt) continue;
        int tok = lists[e * 1024 + row];
        float g = glist[e * 1024 + row];
#pragma unroll
        for (int j = 0; j < 4; j++) {
            int col = colBase + tx * 4 + j;
            atomicAdd(&OUT[(size_t)tok * 1024 + col], g * (acc[i][j] + B[col]));
        }
    }
}

// ---------------------------------------------------------------------------
// Attention: one block per (q, head). q=[qC(128),qR(64)], k=[kR(64),kC(128)].
// ---------------------------------------------------------------------------
__launch_bounds__(256)
__global__ void attn_kernel(const float* __restrict__ QC, const float* __restrict__ QR,
                            const float* __restrict__ KR, const float* __restrict__ KC,
                            const float* __restrict__ VC, float* __restrict__ O)
{
    int qi = blockIdx.x, h = blockIdx.y;
    __shared__ float qs[192];
    __shared__ float sc[1024];
    __shared__ float red[256];
    int tid = threadIdx.x;
    if (tid < 128)      qs[tid] = QC[(size_t)qi * 1024 + h * 128 + tid];
    else if (tid < 192) qs[tid] = QR[(size_t)qi * 512 + h * 64 + (tid - 128)];
    __syncthreads();
    int kn = qi + 1;
    const float scale = 0.07216878364870323f;  // 1/sqrt(192)
    float lmax = -3.4e38f;
    for (int k = tid; k < kn; k += 256) {
        const float* kr = KR + (size_t)k * 64;
        const float* kc = KC + (size_t)k * 1024 + h * 128;
        float s = 0.f;
#pragma unroll
        for (int d = 0; d < 64; d += 4) {
            float4 kv = *(const float4*)(kr + d);
            s += qs[d] * kv.x + qs[d + 1] * kv.y + qs[d + 2] * kv.z + qs[d + 3] * kv.w;
        }
#pragma unroll
        for (int d = 0; d < 128; d += 4) {
            float4 kv = *(const float4*)(kc + d);
            s += qs[64 + d] * kv.x + qs[65 + d] * kv.y + qs[66 + d] * kv.z + qs[67 + d] * kv.w;
        }
        s *= scale;
        sc[k] = s;
        lmax = fmaxf(lmax, s);
    }
    red[tid] = lmax; __syncthreads();
    for (int st = 128; st > 0; st >>= 1) { if (tid < st) red[tid] = fmaxf(red[tid], red[tid + st]); __syncthreads(); }
    float m = red[0];
    __syncthreads();
    float lsum = 0.f;
    for (int k = tid; k < kn; k += 256) { float ev = expf(sc[k] - m); sc[k] = ev; lsum += ev; }
    red[tid] = lsum; __syncthreads();
    for (int st = 128; st > 0; st >>= 1) { if (tid < st) red[tid] += red[tid + st]; __syncthreads(); }
    float Ssum = red[0];
    __syncthreads();
    int d = tid & 127, half = tid >> 7;
    float acc = 0.f;
    for (int k = half; k < kn; k += 2)
        acc += sc[k] * VC[(size_t)k * 1024 + h * 128 + d];
    red[tid] = acc; __syncthreads();
    if (tid < 128)
        O[(size_t)qi * 1024 + h * 128 + d] = (red[tid] + red[tid + 128]) / Ssum;
}

// ---------------------------------------------------------------------------
// Routing: affinity = sigmoid(y @ centroids^T); top-2 on affinity+bias
// (ties -> lower index, matching jax.lax.top_k); gates = softmax of gathered
// affinities; append token to per-expert lists.
// ---------------------------------------------------------------------------
__launch_bounds__(256)
__global__ void route_kernel(const float* __restrict__ Y, const float* __restrict__ cent,
                             const float* __restrict__ biases,
                             int* __restrict__ counts, int* __restrict__ lists,
                             float* __restrict__ glist)
{
    int t = blockIdx.x, tid = threadIdx.x;
    float acc[8] = {};
    for (int j = tid; j < 1024; j += 256) {
        float yv = Y[(size_t)t * 1024 + j];
#pragma unroll
        for (int e = 0; e < 8; e++) acc[e] += yv * cent[e * 1024 + j];
    }
    __shared__ float red[256];
    __shared__ float aff[8];
    for (int e = 0; e < 8; e++) {
        red[tid] = acc[e]; __syncthreads();
        for (int st = 128; st > 0; st >>= 1) { if (tid < st) red[tid] += red[tid + st]; __syncthreads(); }
        if (tid == 0) aff[e] = 1.f / (1.f + expf(-red[0]));
        __syncthreads();
    }
    if (tid == 0) {
        float sb[8];
#pragma unroll
        for (int e = 0; e < 8; e++) sb[e] = aff[e] + biases[e];
        int i0 = 0;
        for (int e = 1; e < 8; e++) if (sb[e] > sb[i0]) i0 = e;
        int i1 = -1;
        for (int e = 0; e < 8; e++) { if (e == i0) continue; if (i1 < 0 || sb[e] > sb[i1]) i1 = e; }
        float a0 = aff[i0], a1 = aff[i1];
        float mx = fmaxf(a0, a1);
        float e0 = expf(a0 - mx), e1 = expf(a1 - mx);
        float inv = 1.f / (e0 + e1);
        int p0 = atomicAdd(&counts[i0], 1);
        lists[i0 * 1024 + p0] = t; glist[i0 * 1024 + p0] = e0 * inv;
        int p1 = atomicAdd(&counts[i1], 1);
        lists[i1 * 1024 + p1] = t; glist[i1 * 1024 + p1] = e1 * inv;
    }
}

__global__ void zero_i(int* p, int n)
{
    int i = blockIdx.x * blockDim.x + threadIdx.x;
    if (i < n) p[i] = 0;
}

// ---------------------------------------------------------------------------
extern "C" void kernel_launch(void* const* d_in, const int* in_sizes, int n_in,
                              void* d_out, int out_size, void* d_ws, size_t ws_size,
                              hipStream_t stream)
{
    (void)in_sizes; (void)n_in; (void)ws_size; (void)out_size;
    const float* h       = (const float*)d_in[0];
    const float* fcos    = (const float*)d_in[1];
    const float* fsin    = (const float*)d_in[2];
    // d_in[3] = mask (causal, deterministic) — unused
    const float* attn_w  = (const float*)d_in[4];
    const float* ffn_w   = (const float*)d_in[5];
    const float* wq_down = (const float*)d_in[6];
    const float* bq_down = (const float*)d_in[7];
    const float* q_norm  = (const float*)d_in[8];
    const float* wqc     = (const float*)d_in[9];
    const float* bqc     = (const float*)d_in[10];
    const float* wqr     = (const float*)d_in[11];
    const float* bqr     = (const float*)d_in[12];
    const float* wkr     = (const float*)d_in[13];
    const float* bkr     = (const float*)d_in[14];
    const float* kr_norm = (const float*)d_in[15];
    const float* wkv     = (const float*)d_in[16];
    const float* bkv     = (const float*)d_in[17];
    const float* kv_norm = (const float*)d_in[18];
    const float* wkc     = (const float*)d_in[19];
    const float* bkc     = (const float*)d_in[20];
    const float* wvc     = (const float*)d_in[21];
    const float* bvc     = (const float*)d_in[22];
    const float* wo      = (const float*)d_in[23];
    const float* bo      = (const float*)d_in[24];
    const float* sw1     = (const float*)d_in[25];
    const float* sb1     = (const float*)d_in[26];
    const float* sw2     = (const float*)d_in[27];
    const float* sb2     = (const float*)d_in[28];
    const float* sw3     = (const float*)d_in[29];
    const float* sb3     = (const float*)d_in[30];
    const float* ew1     = (const float*)d_in[31];
    const float* eb1     = (const float*)d_in[32];
    const float* ew2     = (const float*)d_in[33];
    const float* eb2     = (const float*)d_in[34];
    const float* ew3     = (const float*)d_in[35];
    const float* eb3     = (const float*)d_in[36];
    const float* cent    = (const float*)d_in[37];
    const float* biases  = (const float*)d_in[38];

    float* ws = (float*)d_ws;
    size_t off = 0;
    float* X   = ws + off; off += 1048576;   // x (attn rmsnorm); later reused as ATT
    float* CQ  = ws + off; off += 786432;    // 1024x768
    float* CKV = ws + off; off += 262144;    // 1024x256
    float* KR  = ws + off; off += 65536;     // 1024x64
    float* QC  = ws + off; off += 1048576;   // 1024x1024
    float* QR  = ws + off; off += 524288;    // 1024x512; later reused as G
    float* KC  = ws + off; off += 1048576;   // 1024x1024
    float* VC  = ws + off; off += 1048576;   // 1024x1024
    float* X1  = ws + off; off += 1048576;
    float* Y   = ws + off; off += 1048576;
    float* H1  = ws + off; off += 4194304;   // 8 x 1024 x 512
    float* GL  = ws + off; off += 8192;      // gate per (expert, slot)
    int* counts = (int*)(ws + off); off += 8;
    int* lists  = (int*)(ws + off); off += 8192;
    float* ATT    = X;             // X dead after the 3 down-projections
    float* G      = QR;            // QR dead after attention
    float* OUTACC = (float*)d_out; // final accumulator IS the output

    // --- attention branch ---
    rmsnorm_f32<<<1024, 256, 0, stream>>>(h, attn_w, X, 1024);
    gemm_k<0><<<dim3(12, 16), 256, 0, stream>>>(X, 1024, wq_down, 1024, bq_down, CQ, 768, 1024, nullptr);
    gemm_k<0><<<dim3(1, 16), 256, 0, stream>>>(X, 1024, wkr, 1024, bkr, KR, 64, 1024, nullptr);
    gemm_k<0><<<dim3(4, 16), 256, 0, stream>>>(X, 1024, wkv, 1024, bkv, CKV, 256, 1024, nullptr);
    rmsnorm_f32<<<1024, 256, 0, stream>>>(CQ, q_norm, CQ, 768);
    rmsnorm_f32<<<1024, 256, 0, stream>>>(CKV, kv_norm, CKV, 256);
    rmsnorm_f32<<<1024, 256, 0, stream>>>(KR, kr_norm, KR, 64);
    rope_k<<<1024, 64, 0, stream>>>(KR, fcos, fsin, 1);
    gemm_k<0><<<dim3(16, 16), 256, 0, stream>>>(CQ, 768, wqc, 768, bqc, QC, 1024, 768, nullptr);
    gemm_k<0><<<dim3(8, 16), 256, 0, stream>>>(CQ, 768, wqr, 768, bqr, QR, 512, 768, nullptr);
    rope_k<<<1024, 256, 0, stream>>>(QR, fcos, fsin, 8);
    gemm_k<0><<<dim3(16, 16), 256, 0, stream>>>(CKV, 256, wkc, 256, bkc, KC, 1024, 256, nullptr);
    gemm_k<0><<<dim3(16, 16), 256, 0, stream>>>(CKV, 256, wvc, 256, bvc, VC, 1024, 256, nullptr);
    attn_kernel<<<dim3(1024, 8), 256, 0, stream>>>(QC, QR, KR, KC, VC, ATT);
    gemm_k<1><<<dim3(16, 16), 256, 0, stream>>>(ATT, 1024, wo, 1024, bo, X1, 1024, 1024, h);

    // --- FFN branch ---
    rmsnorm_f32<<<1024, 256, 0, stream>>>(X1, ffn_w, Y, 1024);
    gemm_glu<<<dim3(8, 16, 1), 256, 0, stream>>>(Y, 1024, sw1, sb1, sw3, sb3, 1024, 1024, G, 512,
                                                 (size_t)0, (size_t)0, (size_t)0, nullptr, nullptr);
    gemm_k<1><<<dim3(16, 16), 256, 0, stream>>>(G, 512, sw2, 512, sb2, OUTACC, 1024, 512, X1);

    // --- MoE ---
    zero_i<<<1, 64, 0, stream>>>(counts, 8);
    route_kernel<<<1024, 256, 0, stream>>>(Y, cent, biases, counts, lists, GL);
    gemm_glu<<<dim3(8, 16, 8), 256, 0, stream>>>(Y, 1024, ew1, eb1, ew3, eb3, 1024, 1024, H1, 512,
                                                 (size_t)(512 * 1024), (size_t)512, (size_t)(1024 * 512),
                                                 lists, counts);
    gemm_moe_down<<<dim3(16, 16, 8), 256, 0, stream>>>(H1, ew2, eb2, OUTACC, lists, GL, counts);
}

// Round 4
// 1208.146 us; speedup vs baseline: 1.5029x; 1.5029x over previous
//
#include <hip/hip_runtime.h>

// All inputs/outputs fp32 (reference is jnp.float32 throughout).

// ---------------------------------------------------------------------------
// RMSNorm fp32 -> fp32 (in-place safe). One block per row.
// ---------------------------------------------------------------------------
__launch_bounds__(256)
__global__ void rmsnorm_f32(const float* __restrict__ X, const float* __restrict__ w,
                            float* __restrict__ O, int cols)
{
    int r = blockIdx.x, tid = threadIdx.x;
    const float* xr = X + (size_t)r * cols;
    float ss = 0.f;
    for (int j = tid; j < cols; j += 256) { float v = xr[j]; ss += v * v; }
    __shared__ float red[256];
    red[tid] = ss; __syncthreads();
    for (int st = 128; st > 0; st >>= 1) { if (tid < st) red[tid] += red[tid + st]; __syncthreads(); }
    float scale = rsqrtf(red[0] / cols + 1e-6f);
    for (int j = tid; j < cols; j += 256)
        O[(size_t)r * cols + j] = xr[j] * scale * w[j];
}

// ---------------------------------------------------------------------------
// RoPE in-place on fp32 (S, nh*64). pair j: (x0*c - x1*s, x0*s + x1*c)
// ---------------------------------------------------------------------------
__global__ void rope_k(float* __restrict__ X, const float* __restrict__ C,
                       const float* __restrict__ Sn, int nh)
{
    int s = blockIdx.x;
    int n = nh * 32;
    for (int i = threadIdx.x; i < n; i += blockDim.x) {
        int h = i >> 5, j = i & 31;
        float c  = C[s * 32 + j];
        float sn = Sn[s * 32 + j];
        float* p = X + (size_t)s * nh * 64 + h * 64 + 2 * j;
        float x0 = p[0], x1 = p[1];
        p[0] = x0 * c - x1 * sn;
        p[1] = x0 * sn + x1 * c;
    }
}

// ---------------------------------------------------------------------------
// GEMM: C[M,N] = A[M,K] @ W[N,K]^T + bias.  EPI: 0 none, 1 += res (fp32).
// 64x64 tile, BK=16, 256 threads, 4x4 per thread.  M = grid.y*64 exact.
// ---------------------------------------------------------------------------
template<int EPI>
__launch_bounds__(256)
__global__ void gemm_k(const float* __restrict__ A, int lda,
                       const float* __restrict__ W, int ldw,
                       const float* __restrict__ bias,
                       float* __restrict__ C, int ldc, int K,
                       const float* __restrict__ res)
{
    __shared__ float As[16][64];
    __shared__ float Bs[16][64];
    int tid = threadIdx.x;
    int tx = tid & 15, ty = tid >> 4;
    int rowBase = blockIdx.y * 64, colBase = blockIdx.x * 64;
    int lm = tid >> 2;
    int lk = (tid & 3) << 2;
    float acc[4][4] = {};
    for (int k0 = 0; k0 < K; k0 += 16) {
        float4 av = *(const float4*)(A + (size_t)(rowBase + lm) * lda + k0 + lk);
        As[lk + 0][lm] = av.x; As[lk + 1][lm] = av.y;
        As[lk + 2][lm] = av.z; As[lk + 3][lm] = av.w;
        float4 wv = *(const float4*)(W + (size_t)(colBase + lm) * ldw + k0 + lk);
        Bs[lk + 0][lm] = wv.x; Bs[lk + 1][lm] = wv.y;
        Bs[lk + 2][lm] = wv.z; Bs[lk + 3][lm] = wv.w;
        __syncthreads();
#pragma unroll
        for (int kk = 0; kk < 16; ++kk) {
            float a[4], b[4];
#pragma unroll
            for (int i = 0; i < 4; i++) a[i] = As[kk][ty * 4 + i];
#pragma unroll
            for (int j = 0; j < 4; j++) b[j] = Bs[kk][tx * 4 + j];
#pragma unroll
            for (int i = 0; i < 4; i++)
#pragma unroll
                for (int j = 0; j < 4; j++) acc[i][j] += a[i] * b[j];
        }
        __syncthreads();
    }
#pragma unroll
    for (int i = 0; i < 4; i++) {
        int row = rowBase + ty * 4 + i;
#pragma unroll
        for (int j = 0; j < 4; j++) {
            int col = colBase + tx * 4 + j;
            float v = acc[i][j] + bias[col];
            if (EPI == 1) v += res[(size_t)row * ldc + col];
            C[(size_t)row * ldc + col] = v;
        }
    }
}

// ---------------------------------------------------------------------------
// GLU GEMM: C = silu(A@W1^T + b1) * (A@W3^T + b3).  Optional expert gather:
// blockIdx.z = expert; A row m is token lists[e*1024+m], M = counts[e].
// ---------------------------------------------------------------------------
__launch_bounds__(256)
__global__ void gemm_glu(const float* __restrict__ A, int lda,
                         const float* __restrict__ W1b, const float* __restrict__ B1b,
                         const float* __restrict__ W3b, const float* __restrict__ B3b,
                         int ldw, int K, float* __restrict__ Cb, int ldc,
                         size_t wstride, size_t bstride, size_t cstride,
                         const int* __restrict__ lists, const int* __restrict__ counts)
{
    int e = blockIdx.z;
    int cnt = counts ? counts[e] : 1024;
    int rowBase = blockIdx.y * 64;
    if (rowBase >= cnt) return;
    const float* W1 = W1b + (size_t)e * wstride;
    const float* B1 = B1b + (size_t)e * bstride;
    const float* W3 = W3b + (size_t)e * wstride;
    const float* B3 = B3b + (size_t)e * bstride;
    float* C = Cb + (size_t)e * cstride;
    const int* list = lists ? lists + e * 1024 : nullptr;

    __shared__ float As[16][64];
    __shared__ float B1s[16][64];
    __shared__ float B3s[16][64];
    int tid = threadIdx.x;
    int tx = tid & 15, ty = tid >> 4;
    int colBase = blockIdx.x * 64;
    int lm = tid >> 2;
    int lk = (tid & 3) << 2;
    int arow = rowBase + lm;
    int atok = arow;
    if (list) atok = list[arow < cnt ? arow : cnt - 1];
    const float* Arow = A + (size_t)atok * lda;
    float acc1[4][4] = {};
    float acc3[4][4] = {};
    for (int k0 = 0; k0 < K; k0 += 16) {
        float4 av = *(const float4*)(Arow + k0 + lk);
        As[lk + 0][lm] = av.x; As[lk + 1][lm] = av.y;
        As[lk + 2][lm] = av.z; As[lk + 3][lm] = av.w;
        float4 w1v = *(const float4*)(W1 + (size_t)(colBase + lm) * ldw + k0 + lk);
        B1s[lk + 0][lm] = w1v.x; B1s[lk + 1][lm] = w1v.y;
        B1s[lk + 2][lm] = w1v.z; B1s[lk + 3][lm] = w1v.w;
        float4 w3v = *(const float4*)(W3 + (size_t)(colBase + lm) * ldw + k0 + lk);
        B3s[lk + 0][lm] = w3v.x; B3s[lk + 1][lm] = w3v.y;
        B3s[lk + 2][lm] = w3v.z; B3s[lk + 3][lm] = w3v.w;
        __syncthreads();
#pragma unroll
        for (int kk = 0; kk < 16; ++kk) {
            float a[4], p[4], q[4];
#pragma unroll
            for (int i = 0; i < 4; i++) a[i] = As[kk][ty * 4 + i];
#pragma unroll
            for (int j = 0; j < 4; j++) { p[j] = B1s[kk][tx * 4 + j]; q[j] = B3s[kk][tx * 4 + j]; }
#pragma unroll
            for (int i = 0; i < 4; i++)
#pragma unroll
                for (int j = 0; j < 4; j++) {
                    acc1[i][j] += a[i] * p[j];
                    acc3[i][j] += a[i] * q[j];
                }
        }
        __syncthreads();
    }
#pragma unroll
    for (int i = 0; i < 4; i++) {
        int row = rowBase + ty * 4 + i;
        if (row >= cnt) continue;
#pragma unroll
        for (int j = 0; j < 4; j++) {
            int col = colBase + tx * 4 + j;
            float u  = acc1[i][j] + B1[col];
            float v3 = acc3[i][j] + B3[col];
            float sl = u / (1.f + expf(-u));
            C[(size_t)row * ldc + col] = sl * v3;
        }
    }
}

// ---------------------------------------------------------------------------
// MoE down: OUT[tok, n] += gate * (H1[e] @ ew2[e]^T + eb2[e]).  K=512.
// ---------------------------------------------------------------------------
__launch_bounds__(256)
__global__ void gemm_moe_down(const float* __restrict__ H1b,
                              const float* __restrict__ W2b, const float* __restrict__ B2b,
                              float* __restrict__ OUT,
                              const int* __restrict__ lists, const float* __restrict__ glist,
                              const int* __restrict__ counts)
{
    int e = blockIdx.z;
    int cnt = counts[e];
    int rowBase = blockIdx.y * 64;
    if (rowBase >= cnt) return;
    const float* A = H1b + (size_t)e * 1024 * 512;
    const float* W = W2b + (size_t)e * 1024 * 512;
    const float* B = B2b + (size_t)e * 1024;

    __shared__ float As[16][64];
    __shared__ float Bs[16][64];
    int tid = threadIdx.x;
    int tx = tid & 15, ty = tid >> 4;
    int colBase = blockIdx.x * 64;
    int lm = tid >> 2;
    int lk = (tid & 3) << 2;
    float acc[4][4] = {};
    for (int k0 = 0; k0 < 512; k0 += 16) {
        float4 av = *(const float4*)(A + (size_t)(rowBase + lm) * 512 + k0 + lk);
        As[lk + 0][lm] = av.x; As[lk + 1][lm] = av.y;
        As[lk + 2][lm] = av.z; As[lk + 3][lm] = av.w;
        float4 wv = *(const float4*)(W + (size_t)(colBase + lm) * 512 + k0 + lk);
        Bs[lk + 0][lm] = wv.x; Bs[lk + 1][lm] = wv.y;
        Bs[lk + 2][lm] = wv.z; Bs[lk + 3][lm] = wv.w;
        __syncthreads();
#pragma unroll
        for (int kk = 0; kk < 16; ++kk) {
            float a[4], b[4];
#pragma unroll
            for (int i = 0; i < 4; i++) a[i] = As[kk][ty * 4 + i];
#pragma unroll
            for (int j = 0; j < 4; j++) b[j] = Bs[kk][tx * 4 + j];
#pragma unroll
            for (int i = 0; i < 4; i++)
#pragma unroll
                for (int j = 0; j < 4; j++) acc[i][j] += a[i] * b[j];
        }
        __syncthreads();
    }
#pragma unroll
    for (int i = 0; i < 4; i++) {
        int row = rowBase + ty * 4 + i;
        if (row >= cnt) continue;
        int tok = lists[e * 1024 + row];
        float g = glist[e * 1024 + row];
#pragma unroll
        for (int j = 0; j < 4; j++) {
            int col = colBase + tx * 4 + j;
            atomicAdd(&OUT[(size_t)tok * 1024 + col], g * (acc[i][j] + B[col]));
        }
    }
}

// ---------------------------------------------------------------------------
// Flash attention. Block = (q-tile of 32 rows, head). 256 threads.
// Streams K/V in 64-wide tiles with online softmax.
// IMPORTANT positional pairing (reference concatenates q and k DIFFERENTLY):
//   q[d]: d<128 -> qC[d],     d>=128 -> qR[d-128]
//   k[d]: d<64  -> kR[d],     d>=64  -> kC[d-64]
// So chunk c (16 dims): Q side c<8 -> QC+c*16, c>=8 -> QR+(c-8)*16;
//                       K side c<4 -> KR+c*16, c>=4 -> KC+(c-4)*16.
// ---------------------------------------------------------------------------
__launch_bounds__(256)
__global__ void attn_flash(const float* __restrict__ QC, const float* __restrict__ QR,
                           const float* __restrict__ KR, const float* __restrict__ KC,
                           const float* __restrict__ VC, float* __restrict__ O)
{
    const int qt = blockIdx.x, h = blockIdx.y;
    const int q0 = qt * 32;
    const int nkt = (q0 >> 6) + 1;
    const int tid = threadIdx.x;

    __shared__ float As[16][32];    // Q chunk (k-dim x q-row)
    __shared__ float Bs[16][64];    // K chunk (k-dim x k-row)
    __shared__ float Ss[32][65];    // scores / P
    __shared__ float Vs[16][128];   // V chunk
    __shared__ float m_s[32], l_s[32], alpha_s[32];
    __shared__ float redm[32][8], redl[32][8];

    // score-phase mapping: 2 q-rows x 4 k-cols per thread
    const int tx = tid & 15, ty = tid >> 4;
    // softmax mapping: 8 threads per row
    const int sr = tid >> 3, sc8 = tid & 7;
    // PV/output mapping: 4 q-rows x 4 d-cols per thread
    const int tx2 = tid & 31, ty2 = tid >> 5;

    if (tid < 32) { m_s[tid] = -1e30f; l_s[tid] = 0.f; }
    float accO[4][4] = {};
    const float scale = 0.07216878364870323f;  // 1/sqrt(192)
    __syncthreads();

    for (int kt = 0; kt < nkt; ++kt) {
        const int kt0 = kt * 64;
        // ---- score GEMM: S[32x64] = Q . K^T over 192 dims ----
        float acc[2][4] = {};
        const int lm = tid >> 2;          // 0..63
        const int lk = (tid & 3) << 2;    // 0,4,8,12
        for (int c = 0; c < 12; ++c) {
            if (tid < 128) {
                const float* qp = (c < 8)
                    ? QC + (size_t)(q0 + lm) * 1024 + h * 128 + c * 16 + lk
                    : QR + (size_t)(q0 + lm) * 512 + h * 64 + (c - 8) * 16 + lk;
                float4 av = *(const float4*)qp;
                As[lk + 0][lm] = av.x; As[lk + 1][lm] = av.y;
                As[lk + 2][lm] = av.z; As[lk + 3][lm] = av.w;
            }
            const float* kp = (c < 4)
                ? KR + (size_t)(kt0 + lm) * 64 + c * 16 + lk
                : KC + (size_t)(kt0 + lm) * 1024 + h * 128 + (c - 4) * 16 + lk;
            float4 bv = *(const float4*)kp;
            Bs[lk + 0][lm] = bv.x; Bs[lk + 1][lm] = bv.y;
            Bs[lk + 2][lm] = bv.z; Bs[lk + 3][lm] = bv.w;
            __syncthreads();
#pragma unroll
            for (int kk = 0; kk < 16; ++kk) {
                float a0 = As[kk][ty * 2], a1 = As[kk][ty * 2 + 1];
                float b[4];
#pragma unroll
                for (int j = 0; j < 4; j++) b[j] = Bs[kk][tx * 4 + j];
#pragma unroll
                for (int j = 0; j < 4; j++) {
                    acc[0][j] += a0 * b[j];
                    acc[1][j] += a1 * b[j];
                }
            }
            __syncthreads();
        }
        // masked, scaled scores -> LDS
#pragma unroll
        for (int i = 0; i < 2; i++) {
            int q = q0 + ty * 2 + i;
#pragma unroll
            for (int j = 0; j < 4; j++) {
                int k = kt0 + tx * 4 + j;
                Ss[ty * 2 + i][tx * 4 + j] = (k <= q) ? acc[i][j] * scale : -1e30f;
            }
        }
        __syncthreads();
        // ---- online softmax ----
        float pm = -1e30f;
#pragma unroll
        for (int c = 0; c < 8; c++) pm = fmaxf(pm, Ss[sr][sc8 * 8 + c]);
        redm[sr][sc8] = pm;
        __syncthreads();
        if (sc8 == 0) {
            float tm = redm[sr][0];
#pragma unroll
            for (int c = 1; c < 8; c++) tm = fmaxf(tm, redm[sr][c]);
            float mo = m_s[sr], mn = fmaxf(mo, tm);
            alpha_s[sr] = __expf(mo - mn);
            m_s[sr] = mn;
        }
        __syncthreads();
        float mn = m_s[sr];
        float ps = 0.f;
#pragma unroll
        for (int c = 0; c < 8; c++) {
            float p = __expf(Ss[sr][sc8 * 8 + c] - mn);
            Ss[sr][sc8 * 8 + c] = p;
            ps += p;
        }
        redl[sr][sc8] = ps;
        __syncthreads();
        if (sc8 == 0) {
            float sum = redl[sr][0];
#pragma unroll
            for (int c = 1; c < 8; c++) sum += redl[sr][c];
            l_s[sr] = l_s[sr] * alpha_s[sr] + sum;
        }
        __syncthreads();
        // ---- rescale O, then O += P.V ----
#pragma unroll
        for (int i = 0; i < 4; i++) {
            float a = alpha_s[ty2 * 4 + i];
#pragma unroll
            for (int j = 0; j < 4; j++) accO[i][j] *= a;
        }
        for (int kc = 0; kc < 4; ++kc) {
            __syncthreads();
            {
                int vr = tid >> 4, vcol = (tid & 15) * 8;
                const float* vp = VC + (size_t)(kt0 + kc * 16 + vr) * 1024 + h * 128 + vcol;
                *(float4*)&Vs[vr][vcol]     = *(const float4*)vp;
                *(float4*)&Vs[vr][vcol + 4] = *(const float4*)(vp + 4);
            }
            __syncthreads();
#pragma unroll
            for (int kk = 0; kk < 16; ++kk) {
                float4 v = *(const float4*)&Vs[kk][tx2 * 4];
#pragma unroll
                for (int i = 0; i < 4; i++) {
                    float p = Ss[ty2 * 4 + i][kc * 16 + kk];
                    accO[i][0] += p * v.x;
                    accO[i][1] += p * v.y;
                    accO[i][2] += p * v.z;
                    accO[i][3] += p * v.w;
                }
            }
        }
        __syncthreads();
    }
    // ---- epilogue: O / l ----
#pragma unroll
    for (int i = 0; i < 4; i++) {
        int q = q0 + ty2 * 4 + i;
        float inv = 1.f / l_s[ty2 * 4 + i];
        float4 o;
        o.x = accO[i][0] * inv; o.y = accO[i][1] * inv;
        o.z = accO[i][2] * inv; o.w = accO[i][3] * inv;
        *(float4*)&O[(size_t)q * 1024 + h * 128 + tx2 * 4] = o;
    }
}

// ---------------------------------------------------------------------------
// Routing: affinity = sigmoid(y @ centroids^T); top-2 on affinity+bias
// (ties -> lower index, matching jax.lax.top_k); gates = softmax of gathered
// affinities; append token to per-expert lists.
// ---------------------------------------------------------------------------
__launch_bounds__(256)
__global__ void route_kernel(const float* __restrict__ Y, const float* __restrict__ cent,
                             const float* __restrict__ biases,
                             int* __restrict__ counts, int* __restrict__ lists,
                             float* __restrict__ glist)
{
    int t = blockIdx.x, tid = threadIdx.x;
    float acc[8] = {};
    for (int j = tid; j < 1024; j += 256) {
        float yv = Y[(size_t)t * 1024 + j];
#pragma unroll
        for (int e = 0; e < 8; e++) acc[e] += yv * cent[e * 1024 + j];
    }
    __shared__ float red[256];
    __shared__ float aff[8];
    for (int e = 0; e < 8; e++) {
        red[tid] = acc[e]; __syncthreads();
        for (int st = 128; st > 0; st >>= 1) { if (tid < st) red[tid] += red[tid + st]; __syncthreads(); }
        if (tid == 0) aff[e] = 1.f / (1.f + expf(-red[0]));
        __syncthreads();
    }
    if (tid == 0) {
        float sb[8];
#pragma unroll
        for (int e = 0; e < 8; e++) sb[e] = aff[e] + biases[e];
        int i0 = 0;
        for (int e = 1; e < 8; e++) if (sb[e] > sb[i0]) i0 = e;
        int i1 = -1;
        for (int e = 0; e < 8; e++) { if (e == i0) continue; if (i1 < 0 || sb[e] > sb[i1]) i1 = e; }
        float a0 = aff[i0], a1 = aff[i1];
        float mx = fmaxf(a0, a1);
        float e0 = expf(a0 - mx), e1 = expf(a1 - mx);
        float inv = 1.f / (e0 + e1);
        int p0 = atomicAdd(&counts[i0], 1);
        lists[i0 * 1024 + p0] = t; glist[i0 * 1024 + p0] = e0 * inv;
        int p1 = atomicAdd(&counts[i1], 1);
        lists[i1 * 1024 + p1] = t; glist[i1 * 1024 + p1] = e1 * inv;
    }
}

__global__ void zero_i(int* p, int n)
{
    int i = blockIdx.x * blockDim.x + threadIdx.x;
    if (i < n) p[i] = 0;
}

// ---------------------------------------------------------------------------
extern "C" void kernel_launch(void* const* d_in, const int* in_sizes, int n_in,
                              void* d_out, int out_size, void* d_ws, size_t ws_size,
                              hipStream_t stream)
{
    (void)in_sizes; (void)n_in; (void)ws_size; (void)out_size;
    const float* h       = (const float*)d_in[0];
    const float* fcos    = (const float*)d_in[1];
    const float* fsin    = (const float*)d_in[2];
    // d_in[3] = mask (causal, deterministic) — unused
    const float* attn_w  = (const float*)d_in[4];
    const float* ffn_w   = (const float*)d_in[5];
    const float* wq_down = (const float*)d_in[6];
    const float* bq_down = (const float*)d_in[7];
    const float* q_norm  = (const float*)d_in[8];
    const float* wqc     = (const float*)d_in[9];
    const float* bqc     = (const float*)d_in[10];
    const float* wqr     = (const float*)d_in[11];
    const float* bqr     = (const float*)d_in[12];
    const float* wkr     = (const float*)d_in[13];
    const float* bkr     = (const float*)d_in[14];
    const float* kr_norm = (const float*)d_in[15];
    const float* wkv     = (const float*)d_in[16];
    const float* bkv     = (const float*)d_in[17];
    const float* kv_norm = (const float*)d_in[18];
    const float* wkc     = (const float*)d_in[19];
    const float* bkc     = (const float*)d_in[20];
    const float* wvc     = (const float*)d_in[21];
    const float* bvc     = (const float*)d_in[22];
    const float* wo      = (const float*)d_in[23];
    const float* bo      = (const float*)d_in[24];
    const float* sw1     = (const float*)d_in[25];
    const float* sb1     = (const float*)d_in[26];
    const float* sw2     = (const float*)d_in[27];
    const float* sb2     = (const float*)d_in[28];
    const float* sw3     = (const float*)d_in[29];
    const float* sb3     = (const float*)d_in[30];
    const float* ew1     = (const float*)d_in[31];
    const float* eb1     = (const float*)d_in[32];
    const float* ew2     = (const float*)d_in[33];
    const float* eb2     = (const float*)d_in[34];
    const float* ew3     = (const float*)d_in[35];
    const float* eb3     = (const float*)d_in[36];
    const float* cent    = (const float*)d_in[37];
    const float* biases  = (const float*)d_in[38];

    float* ws = (float*)d_ws;
    size_t off = 0;
    float* X   = ws + off; off += 1048576;   // x (attn rmsnorm); later reused as ATT
    float* CQ  = ws + off; off += 786432;    // 1024x768
    float* CKV = ws + off; off += 262144;    // 1024x256
    float* KR  = ws + off; off += 65536;     // 1024x64
    float* QC  = ws + off; off += 1048576;   // 1024x1024
    float* QR  = ws + off; off += 524288;    // 1024x512; later reused as G
    float* KC  = ws + off; off += 1048576;   // 1024x1024
    float* VC  = ws + off; off += 1048576;   // 1024x1024
    float* X1  = ws + off; off += 1048576;
    float* Y   = ws + off; off += 1048576;
    float* H1  = ws + off; off += 4194304;   // 8 x 1024 x 512
    float* GL  = ws + off; off += 8192;      // gate per (expert, slot)
    int* counts = (int*)(ws + off); off += 8;
    int* lists  = (int*)(ws + off); off += 8192;
    float* ATT    = X;             // X dead after the 3 down-projections
    float* G      = QR;            // QR dead after attention
    float* OUTACC = (float*)d_out; // final accumulator IS the output

    // --- attention branch ---
    rmsnorm_f32<<<1024, 256, 0, stream>>>(h, attn_w, X, 1024);
    gemm_k<0><<<dim3(12, 16), 256, 0, stream>>>(X, 1024, wq_down, 1024, bq_down, CQ, 768, 1024, nullptr);
    gemm_k<0><<<dim3(1, 16), 256, 0, stream>>>(X, 1024, wkr, 1024, bkr, KR, 64, 1024, nullptr);
    gemm_k<0><<<dim3(4, 16), 256, 0, stream>>>(X, 1024, wkv, 1024, bkv, CKV, 256, 1024, nullptr);
    rmsnorm_f32<<<1024, 256, 0, stream>>>(CQ, q_norm, CQ, 768);
    rmsnorm_f32<<<1024, 256, 0, stream>>>(CKV, kv_norm, CKV, 256);
    rmsnorm_f32<<<1024, 256, 0, stream>>>(KR, kr_norm, KR, 64);
    rope_k<<<1024, 64, 0, stream>>>(KR, fcos, fsin, 1);
    gemm_k<0><<<dim3(16, 16), 256, 0, stream>>>(CQ, 768, wqc, 768, bqc, QC, 1024, 768, nullptr);
    gemm_k<0><<<dim3(8, 16), 256, 0, stream>>>(CQ, 768, wqr, 768, bqr, QR, 512, 768, nullptr);
    rope_k<<<1024, 256, 0, stream>>>(QR, fcos, fsin, 8);
    gemm_k<0><<<dim3(16, 16), 256, 0, stream>>>(CKV, 256, wkc, 256, bkc, KC, 1024, 256, nullptr);
    gemm_k<0><<<dim3(16, 16), 256, 0, stream>>>(CKV, 256, wvc, 256, bvc, VC, 1024, 256, nullptr);
    attn_flash<<<dim3(32, 8), 256, 0, stream>>>(QC, QR, KR, KC, VC, ATT);
    gemm_k<1><<<dim3(16, 16), 256, 0, stream>>>(ATT, 1024, wo, 1024, bo, X1, 1024, 1024, h);

    // --- FFN branch ---
    rmsnorm_f32<<<1024, 256, 0, stream>>>(X1, ffn_w, Y, 1024);
    gemm_glu<<<dim3(8, 16, 1), 256, 0, stream>>>(Y, 1024, sw1, sb1, sw3, sb3, 1024, 1024, G, 512,
                                                 (size_t)0, (size_t)0, (size_t)0, nullptr, nullptr);
    gemm_k<1><<<dim3(16, 16), 256, 0, stream>>>(G, 512, sw2, 512, sb2, OUTACC, 1024, 512, X1);

    // --- MoE ---
    zero_i<<<1, 64, 0, stream>>>(counts, 8);
    route_kernel<<<1024, 256, 0, stream>>>(Y, cent, biases, counts, lists, GL);
    gemm_glu<<<dim3(8, 16, 8), 256, 0, stream>>>(Y, 1024, ew1, eb1, ew3, eb3, 1024, 1024, H1, 512,
                                                 (size_t)(512 * 1024), (size_t)512, (size_t)(1024 * 512),
                                                 lists, counts);
    gemm_moe_down<<<dim3(16, 16, 8), 256, 0, stream>>>(H1, ew2, eb2, OUTACC, lists, GL, counts);
}

// Round 5
// 797.168 us; speedup vs baseline: 2.2778x; 1.5155x over previous
//
#include <hip/hip_runtime.h>

typedef unsigned short u16;
typedef __attribute__((ext_vector_type(8))) short short8;   // 8 bf16 (4 VGPRs)
typedef __attribute__((ext_vector_type(4))) float f32x4;    // 4 fp32 acc

__device__ __forceinline__ float b2f(u16 u) { return __uint_as_float(((unsigned)u) << 16); }
__device__ __forceinline__ u16 f2b(float f) {
    unsigned x = __float_as_uint(f);
    return (u16)((x + 0x7fffu + ((x >> 16) & 1u)) >> 16);
}

// async global->LDS, 16B per lane; LDS dest = wave-uniform base + lane*16
#define GLDS16(gp, lp) __builtin_amdgcn_global_load_lds( \
    (const __attribute__((address_space(1))) void*)(gp), \
    (__attribute__((address_space(3))) void*)(lp), 16, 0, 0)

// ---------------------------------------------------------------------------
// MFMA GEMM: C[M,N] = A[M,K](bf16) @ W[N,K]^T(bf16) + bias(fp32)
// 128x128 tile, BK=32, 256 threads = 4 waves in 2x2, 16x16x32 bf16 MFMA.
// EPI: 0 fp32 out; 1 fp32 out += res; 2 atomicAdd(gate*(acc+bias)) [MoE down];
//      3 bf16 out.
// GATHER: A row r -> lists[e*1024 + r] (MoE up).
// Pairing: blocks with bx >= nsplit run the (W2,bias2,C2,ldc2) GEMM.
// ---------------------------------------------------------------------------
template<int EPI, int GATHER>
__launch_bounds__(256)
__global__ void mgemm(const u16* __restrict__ A, int lda, size_t astride,
                      const u16* __restrict__ W, int ldw, size_t wstride,
                      const float* __restrict__ bias, int bstride,
                      void* __restrict__ Cv, int ldc, size_t cstride,
                      int K,
                      const float* __restrict__ res,
                      const u16* __restrict__ W2, const float* __restrict__ bias2,
                      void* __restrict__ C2v, int ldc2, int nsplit,
                      const int* __restrict__ lists, const float* __restrict__ glist,
                      const int* __restrict__ counts)
{
    __shared__ u16 As[4096];   // [128][32] bf16
    __shared__ u16 Bs[4096];
    int bx = blockIdx.x, by = blockIdx.y, e = blockIdx.z;
    int cnt = 1 << 30;
    const int* list = nullptr; const float* gl = nullptr;
    if (counts) {
        cnt = counts[e];
        if (GATHER || EPI == 2) list = lists + (e << 10);
        if (EPI == 2) gl = glist + (e << 10);
    }
    int row0 = by * 128;
    if (counts && row0 >= cnt) return;
    const u16* Wp = W; const float* bp = bias; void* Cp = Cv; int ldco = ldc;
    if (W2 && bx >= nsplit) { Wp = W2; bp = bias2; Cp = C2v; ldco = ldc2; bx -= nsplit; }
    Wp += (size_t)e * wstride;
    bp += (size_t)e * bstride;
    const u16* Ap = A + (size_t)e * astride;
    int col0 = bx * 128;

    int tid = threadIdx.x;
    int lane = tid & 63, w = tid >> 6;
    // staging map: LDS elem offset = w*512 (+2048 for issue 2) + lane*8
    //   row r = w*16 (+64) + lane/4, k-offset = (lane&3)*8
    int r0 = (w << 4) + (lane >> 2), kc8 = (lane & 3) << 3;
    int ar0g = row0 + r0, ar1g = row0 + r0 + 64;
    if (GATHER) {
        int i0 = ar0g < cnt ? ar0g : cnt - 1;
        int i1 = ar1g < cnt ? ar1g : cnt - 1;
        ar0g = list[i0]; ar1g = list[i1];
    }
    const u16* ga0 = Ap + (size_t)ar0g * lda + kc8;
    const u16* ga1 = Ap + (size_t)ar1g * lda + kc8;
    const u16* gb0 = Wp + (size_t)(col0 + r0) * ldw + kc8;
    const u16* gb1 = Wp + (size_t)(col0 + r0 + 64) * ldw + kc8;
    u16* lA = As + (w << 9);
    u16* lB = Bs + (w << 9);

    int wrow = (w >> 1) << 6, wcol = (w & 1) << 6;
    int fm = lane & 15, fq = lane >> 4;
    f32x4 acc[4][4] = {};

    for (int k0 = 0; k0 < K; k0 += 32) {
        GLDS16(ga0 + k0, lA);
        GLDS16(ga1 + k0, lA + 2048);
        GLDS16(gb0 + k0, lB);
        GLDS16(gb1 + k0, lB + 2048);
        __syncthreads();   // drains vmcnt(0): LDS tiles ready
        short8 af[4], bf[4];
#pragma unroll
        for (int t = 0; t < 4; t++) {
            af[t] = *(const short8*)(As + (wrow + (t << 4) + fm) * 32 + fq * 8);
            bf[t] = *(const short8*)(Bs + (wcol + (t << 4) + fm) * 32 + fq * 8);
        }
#pragma unroll
        for (int mt = 0; mt < 4; mt++)
#pragma unroll
            for (int nt = 0; nt < 4; nt++)
                acc[mt][nt] = __builtin_amdgcn_mfma_f32_16x16x32_bf16(af[mt], bf[nt], acc[mt][nt], 0, 0, 0);
        __syncthreads();   // all waves done reading before next stage
    }

    // C/D layout: col = lane&15, row = (lane>>4)*4 + reg   [m89/m91]
#pragma unroll
    for (int mt = 0; mt < 4; mt++) {
        int rbase = row0 + wrow + (mt << 4) + (fq << 2);
#pragma unroll
        for (int nt = 0; nt < 4; nt++) {
            int c = col0 + wcol + (nt << 4) + fm;
            float bcol = bp[c];
#pragma unroll
            for (int reg = 0; reg < 4; reg++) {
                int r = rbase + reg;
                if (counts && r >= cnt) continue;
                float v = acc[mt][nt][reg] + bcol;
                if (EPI == 0)
                    ((float*)Cp)[(size_t)e * cstride + (size_t)r * ldco + c] = v;
                else if (EPI == 1)
                    ((float*)Cp)[(size_t)r * ldco + c] = v + res[(size_t)r * ldco + c];
                else if (EPI == 3)
                    ((u16*)Cp)[(size_t)e * cstride + (size_t)r * ldco + c] = f2b(v);
                else if (EPI == 2)
                    atomicAdd(&((float*)Cp)[(size_t)list[r] * ldco + c], gl[r] * v);
            }
        }
    }
}

// ---------------------------------------------------------------------------
// RMSNorm variants (fp32 in)
// ---------------------------------------------------------------------------
__launch_bounds__(256)
__global__ void rmsnorm_dual(const float* __restrict__ X, const float* __restrict__ w,
                             float* __restrict__ O32, u16* __restrict__ O16, int cols)
{
    int r = blockIdx.x, tid = threadIdx.x;
    const float* xr = X + (size_t)r * cols;
    float ss = 0.f;
    for (int j = tid; j < cols; j += 256) { float v = xr[j]; ss += v * v; }
    __shared__ float red[256];
    red[tid] = ss; __syncthreads();
    for (int st = 128; st > 0; st >>= 1) { if (tid < st) red[tid] += red[tid + st]; __syncthreads(); }
    float scale = rsqrtf(red[0] / cols + 1e-6f);
    for (int j = tid; j < cols; j += 256) {
        float v = xr[j] * scale * w[j];
        O32[(size_t)r * cols + j] = v;
        O16[(size_t)r * cols + j] = f2b(v);
    }
}

__launch_bounds__(256)
__global__ void rmsnorm_b16(const float* __restrict__ X, const float* __restrict__ w,
                            u16* __restrict__ O, int cols)
{
    int r = blockIdx.x, tid = threadIdx.x;
    const float* xr = X + (size_t)r * cols;
    float ss = 0.f;
    for (int j = tid; j < cols; j += 256) { float v = xr[j]; ss += v * v; }
    __shared__ float red[256];
    red[tid] = ss; __syncthreads();
    for (int st = 128; st > 0; st >>= 1) { if (tid < st) red[tid] += red[tid + st]; __syncthreads(); }
    float scale = rsqrtf(red[0] / cols + 1e-6f);
    for (int j = tid; j < cols; j += 256)
        O[(size_t)r * cols + j] = f2b(xr[j] * scale * w[j]);
}

__launch_bounds__(256)
__global__ void rmsnorm_f32(const float* __restrict__ X, const float* __restrict__ w,
                            float* __restrict__ O, int cols)
{
    int r = blockIdx.x, tid = threadIdx.x;
    const float* xr = X + (size_t)r * cols;
    float ss = 0.f;
    for (int j = tid; j < cols; j += 256) { float v = xr[j]; ss += v * v; }
    __shared__ float red[256];
    red[tid] = ss; __syncthreads();
    for (int st = 128; st > 0; st >>= 1) { if (tid < st) red[tid] += red[tid + st]; __syncthreads(); }
    float scale = rsqrtf(red[0] / cols + 1e-6f);
    for (int j = tid; j < cols; j += 256)
        O[(size_t)r * cols + j] = xr[j] * scale * w[j];
}

// ---------------------------------------------------------------------------
// RoPE in-place on fp32 (S, nh*64)
// ---------------------------------------------------------------------------
__global__ void rope_k(float* __restrict__ X, const float* __restrict__ C,
                       const float* __restrict__ Sn, int nh)
{
    int s = blockIdx.x;
    int n = nh * 32;
    for (int i = threadIdx.x; i < n; i += blockDim.x) {
        int h = i >> 5, j = i & 31;
        float c  = C[s * 32 + j];
        float sn = Sn[s * 32 + j];
        float* p = X + (size_t)s * nh * 64 + h * 64 + 2 * j;
        float x0 = p[0], x1 = p[1];
        p[0] = x0 * c - x1 * sn;
        p[1] = x0 * sn + x1 * c;
    }
}

// ---------------------------------------------------------------------------
// fp32 vector GEMM (kept only for wkr, N=64)
// ---------------------------------------------------------------------------
template<int EPI>
__launch_bounds__(256)
__global__ void gemm_k(const float* __restrict__ A, int lda,
                       const float* __restrict__ W, int ldw,
                       const float* __restrict__ bias,
                       float* __restrict__ C, int ldc, int K,
                       const float* __restrict__ res)
{
    __shared__ float As[16][64];
    __shared__ float Bs[16][64];
    int tid = threadIdx.x;
    int tx = tid & 15, ty = tid >> 4;
    int rowBase = blockIdx.y * 64, colBase = blockIdx.x * 64;
    int lm = tid >> 2;
    int lk = (tid & 3) << 2;
    float acc[4][4] = {};
    for (int k0 = 0; k0 < K; k0 += 16) {
        float4 av = *(const float4*)(A + (size_t)(rowBase + lm) * lda + k0 + lk);
        As[lk + 0][lm] = av.x; As[lk + 1][lm] = av.y;
        As[lk + 2][lm] = av.z; As[lk + 3][lm] = av.w;
        float4 wv = *(const float4*)(W + (size_t)(colBase + lm) * ldw + k0 + lk);
        Bs[lk + 0][lm] = wv.x; Bs[lk + 1][lm] = wv.y;
        Bs[lk + 2][lm] = wv.z; Bs[lk + 3][lm] = wv.w;
        __syncthreads();
#pragma unroll
        for (int kk = 0; kk < 16; ++kk) {
            float a[4], b[4];
#pragma unroll
            for (int i = 0; i < 4; i++) a[i] = As[kk][ty * 4 + i];
#pragma unroll
            for (int j = 0; j < 4; j++) b[j] = Bs[kk][tx * 4 + j];
#pragma unroll
            for (int i = 0; i < 4; i++)
#pragma unroll
                for (int j = 0; j < 4; j++) acc[i][j] += a[i] * b[j];
        }
        __syncthreads();
    }
#pragma unroll
    for (int i = 0; i < 4; i++) {
        int row = rowBase + ty * 4 + i;
#pragma unroll
        for (int j = 0; j < 4; j++) {
            int col = colBase + tx * 4 + j;
            float v = acc[i][j] + bias[col];
            if (EPI == 1) v += res[(size_t)row * ldc + col];
            C[(size_t)row * ldc + col] = v;
        }
    }
}

// ---------------------------------------------------------------------------
// silu-mul: G = bf16(silu(U) * V), U/V bf16 (biases already added in GEMM)
// ---------------------------------------------------------------------------
__launch_bounds__(256)
__global__ void silu_mul(const u16* __restrict__ U, const u16* __restrict__ V,
                         u16* __restrict__ G, int n)
{
    int i = blockIdx.x * 256 + threadIdx.x;
    if (i < n) {
        float u = b2f(U[i]), v = b2f(V[i]);
        G[i] = f2b(u / (1.f + expf(-u)) * v);
    }
}

// ---------------------------------------------------------------------------
// Flash attention (fp32 in, bf16 out). Positional pairing:
//   q[d]: d<128 -> qC[d], d>=128 -> qR[d-128]
//   k[d]: d<64  -> kR[d], d>=64  -> kC[d-64]
// ---------------------------------------------------------------------------
__launch_bounds__(256)
__global__ void attn_flash(const float* __restrict__ QC, const float* __restrict__ QR,
                           const float* __restrict__ KR, const float* __restrict__ KC,
                           const float* __restrict__ VC, u16* __restrict__ O)
{
    const int qt = blockIdx.x, h = blockIdx.y;
    const int q0 = qt * 32;
    const int nkt = (q0 >> 6) + 1;
    const int tid = threadIdx.x;

    __shared__ float As[16][32];
    __shared__ float Bs[16][64];
    __shared__ float Ss[32][65];
    __shared__ float Vs[16][128];
    __shared__ float m_s[32], l_s[32], alpha_s[32];
    __shared__ float redm[32][8], redl[32][8];

    const int tx = tid & 15, ty = tid >> 4;
    const int sr = tid >> 3, sc8 = tid & 7;
    const int tx2 = tid & 31, ty2 = tid >> 5;

    if (tid < 32) { m_s[tid] = -1e30f; l_s[tid] = 0.f; }
    float accO[4][4] = {};
    const float scale = 0.07216878364870323f;  // 1/sqrt(192)
    __syncthreads();

    for (int kt = 0; kt < nkt; ++kt) {
        const int kt0 = kt * 64;
        float acc[2][4] = {};
        const int lm = tid >> 2;
        const int lk = (tid & 3) << 2;
        for (int c = 0; c < 12; ++c) {
            if (tid < 128) {
                const float* qp = (c < 8)
                    ? QC + (size_t)(q0 + lm) * 1024 + h * 128 + c * 16 + lk
                    : QR + (size_t)(q0 + lm) * 512 + h * 64 + (c - 8) * 16 + lk;
                float4 av = *(const float4*)qp;
                As[lk + 0][lm] = av.x; As[lk + 1][lm] = av.y;
                As[lk + 2][lm] = av.z; As[lk + 3][lm] = av.w;
            }
            const float* kp = (c < 4)
                ? KR + (size_t)(kt0 + lm) * 64 + c * 16 + lk
                : KC + (size_t)(kt0 + lm) * 1024 + h * 128 + (c - 4) * 16 + lk;
            float4 bv = *(const float4*)kp;
            Bs[lk + 0][lm] = bv.x; Bs[lk + 1][lm] = bv.y;
            Bs[lk + 2][lm] = bv.z; Bs[lk + 3][lm] = bv.w;
            __syncthreads();
#pragma unroll
            for (int kk = 0; kk < 16; ++kk) {
                float a0 = As[kk][ty * 2], a1 = As[kk][ty * 2 + 1];
                float b[4];
#pragma unroll
                for (int j = 0; j < 4; j++) b[j] = Bs[kk][tx * 4 + j];
#pragma unroll
                for (int j = 0; j < 4; j++) {
                    acc[0][j] += a0 * b[j];
                    acc[1][j] += a1 * b[j];
                }
            }
            __syncthreads();
        }
#pragma unroll
        for (int i = 0; i < 2; i++) {
            int q = q0 + ty * 2 + i;
#pragma unroll
            for (int j = 0; j < 4; j++) {
                int k = kt0 + tx * 4 + j;
                Ss[ty * 2 + i][tx * 4 + j] = (k <= q) ? acc[i][j] * scale : -1e30f;
            }
        }
        __syncthreads();
        float pm = -1e30f;
#pragma unroll
        for (int c = 0; c < 8; c++) pm = fmaxf(pm, Ss[sr][sc8 * 8 + c]);
        redm[sr][sc8] = pm;
        __syncthreads();
        if (sc8 == 0) {
            float tm = redm[sr][0];
#pragma unroll
            for (int c = 1; c < 8; c++) tm = fmaxf(tm, redm[sr][c]);
            float mo = m_s[sr], mn = fmaxf(mo, tm);
            alpha_s[sr] = __expf(mo - mn);
            m_s[sr] = mn;
        }
        __syncthreads();
        float mn = m_s[sr];
        float ps = 0.f;
#pragma unroll
        for (int c = 0; c < 8; c++) {
            float p = __expf(Ss[sr][sc8 * 8 + c] - mn);
            Ss[sr][sc8 * 8 + c] = p;
            ps += p;
        }
        redl[sr][sc8] = ps;
        __syncthreads();
        if (sc8 == 0) {
            float sum = redl[sr][0];
#pragma unroll
            for (int c = 1; c < 8; c++) sum += redl[sr][c];
            l_s[sr] = l_s[sr] * alpha_s[sr] + sum;
        }
        __syncthreads();
#pragma unroll
        for (int i = 0; i < 4; i++) {
            float a = alpha_s[ty2 * 4 + i];
#pragma unroll
            for (int j = 0; j < 4; j++) accO[i][j] *= a;
        }
        for (int kc = 0; kc < 4; ++kc) {
            __syncthreads();
            {
                int vr = tid >> 4, vcol = (tid & 15) * 8;
                const float* vp = VC + (size_t)(kt0 + kc * 16 + vr) * 1024 + h * 128 + vcol;
                *(float4*)&Vs[vr][vcol]     = *(const float4*)vp;
                *(float4*)&Vs[vr][vcol + 4] = *(const float4*)(vp + 4);
            }
            __syncthreads();
#pragma unroll
            for (int kk = 0; kk < 16; ++kk) {
                float4 v = *(const float4*)&Vs[kk][tx2 * 4];
#pragma unroll
                for (int i = 0; i < 4; i++) {
                    float p = Ss[ty2 * 4 + i][kc * 16 + kk];
                    accO[i][0] += p * v.x;
                    accO[i][1] += p * v.y;
                    accO[i][2] += p * v.z;
                    accO[i][3] += p * v.w;
                }
            }
        }
        __syncthreads();
    }
#pragma unroll
    for (int i = 0; i < 4; i++) {
        int q = q0 + ty2 * 4 + i;
        float inv = 1.f / l_s[ty2 * 4 + i];
        u16* op = O + (size_t)q * 1024 + h * 128 + tx2 * 4;
        op[0] = f2b(accO[i][0] * inv);
        op[1] = f2b(accO[i][1] * inv);
        op[2] = f2b(accO[i][2] * inv);
        op[3] = f2b(accO[i][3] * inv);
    }
}

// ---------------------------------------------------------------------------
// Routing (fp32 — bf16 logit noise could flip top-2 near-ties)
// ---------------------------------------------------------------------------
__launch_bounds__(256)
__global__ void route_kernel(const float* __restrict__ Y, const float* __restrict__ cent,
                             const float* __restrict__ biases,
                             int* __restrict__ counts, int* __restrict__ lists,
                             float* __restrict__ glist)
{
    int t = blockIdx.x, tid = threadIdx.x;
    float acc[8] = {};
    for (int j = tid; j < 1024; j += 256) {
        float yv = Y[(size_t)t * 1024 + j];
#pragma unroll
        for (int e = 0; e < 8; e++) acc[e] += yv * cent[e * 1024 + j];
    }
    __shared__ float red[256];
    __shared__ float aff[8];
    for (int e = 0; e < 8; e++) {
        red[tid] = acc[e]; __syncthreads();
        for (int st = 128; st > 0; st >>= 1) { if (tid < st) red[tid] += red[tid + st]; __syncthreads(); }
        if (tid == 0) aff[e] = 1.f / (1.f + expf(-red[0]));
        __syncthreads();
    }
    if (tid == 0) {
        float sb[8];
#pragma unroll
        for (int e = 0; e < 8; e++) sb[e] = aff[e] + biases[e];
        int i0 = 0;
        for (int e = 1; e < 8; e++) if (sb[e] > sb[i0]) i0 = e;
        int i1 = -1;
        for (int e = 0; e < 8; e++) { if (e == i0) continue; if (i1 < 0 || sb[e] > sb[i1]) i1 = e; }
        float a0 = aff[i0], a1 = aff[i1];
        float mx = fmaxf(a0, a1);
        float e0 = expf(a0 - mx), e1 = expf(a1 - mx);
        float inv = 1.f / (e0 + e1);
        int p0 = atomicAdd(&counts[i0], 1);
        lists[i0 * 1024 + p0] = t; glist[i0 * 1024 + p0] = e0 * inv;
        int p1 = atomicAdd(&counts[i1], 1);
        lists[i1 * 1024 + p1] = t; glist[i1 * 1024 + p1] = e1 * inv;
    }
}

__global__ void zero_i(int* p, int n)
{
    int i = blockIdx.x * blockDim.x + threadIdx.x;
    if (i < n) p[i] = 0;
}

// ---------------------------------------------------------------------------
extern "C" void kernel_launch(void* const* d_in, const int* in_sizes, int n_in,
                              void* d_out, int out_size, void* d_ws, size_t ws_size,
                              hipStream_t stream)
{
    (void)in_sizes; (void)n_in; (void)ws_size; (void)out_size;
    const float* h       = (const float*)d_in[0];
    const float* fcos    = (const float*)d_in[1];
    const float* fsin    = (const float*)d_in[2];
    const float* attn_w  = (const float*)d_in[4];
    const float* ffn_w   = (const float*)d_in[5];
    const float* wq_down = (const float*)d_in[6];
    const float* bq_down = (const float*)d_in[7];
    const float* q_norm  = (const float*)d_in[8];
    const float* wqc     = (const float*)d_in[9];
    const float* bqc     = (const float*)d_in[10];
    const float* wqr     = (const float*)d_in[11];
    const float* bqr     = (const float*)d_in[12];
    const float* wkr     = (const float*)d_in[13];
    const float* bkr     = (const float*)d_in[14];
    const float* kr_norm = (const float*)d_in[15];
    const float* wkv     = (const float*)d_in[16];
    const float* bkv     = (const float*)d_in[17];
    const float* kv_norm = (const float*)d_in[18];
    const float* wkc     = (const float*)d_in[19];
    const float* bkc     = (const float*)d_in[20];
    const float* wvc     = (const float*)d_in[21];
    const float* bvc     = (const float*)d_in[22];
    const float* wo      = (const float*)d_in[23];
    const float* bo      = (const float*)d_in[24];
    const float* sw1     = (const float*)d_in[25];
    const float* sb1     = (const float*)d_in[26];
    const float* sw2     = (const float*)d_in[27];
    const float* sb2     = (const float*)d_in[28];
    const float* sw3     = (const float*)d_in[29];
    const float* sb3     = (const float*)d_in[30];
    const float* ew1     = (const float*)d_in[31];
    const float* eb1     = (const float*)d_in[32];
    const float* ew2     = (const float*)d_in[33];
    const float* eb2     = (const float*)d_in[34];
    const float* ew3     = (const float*)d_in[35];
    const float* eb3     = (const float*)d_in[36];
    const float* cent    = (const float*)d_in[37];
    const float* biases  = (const float*)d_in[38];

    // Weights are fp32 inputs; cast once per launch into bf16 workspace copies.
    char* wsb = (char*)d_ws;
    const size_t U5 = 512 * 1024;  // 0.5 MB unit
    // lifetimes allow these overlays (steps noted in round-5 journal):
    u16*   H1    = (u16*)(wsb + 0);            // 8 MB   (MoE glu out, late)
    float* X32   = (float*)(wsb + 0);          // 4 MB   (early)
    u16*   X16   = (u16*)(wsb + 8 * U5);       // 2 MB   (early)
    float* QR    = (float*)(wsb + 12 * U5);    // 2 MB
    float* CQraw = (float*)(wsb + 16 * U5);    // 3 MB   (early)
    u16*   ATT16 = (u16*)(wsb + 16 * U5);      // 2 MB   (mid)
    u16*   G16   = (u16*)(wsb + 20 * U5);      // 1 MB
    u16*   CQ16  = (u16*)(wsb + 22 * U5);      // 1.5 MB
    float* CKVraw= (float*)(wsb + 25 * U5);    // 1 MB
    u16*   CKV16 = (u16*)(wsb + 27 * U5);      // 0.5 MB
    float* KR    = (float*)(wsb + 28 * U5);    // 0.25 MB
    float* QC    = (float*)(wsb + 29 * U5);    // 4 MB   (dead after attn)
    float* KC    = (float*)(wsb + 37 * U5);    // 4 MB   (dead after attn)
    u16*   Vb    = (u16*)(wsb + 29 * U5);      // 8 MB   (MoE V, overlays QC+KC)
    float* VC    = (float*)(wsb + 45 * U5);    // 4 MB
    float* X1    = (float*)(wsb + 53 * U5);    // 4 MB
    float* Y32   = (float*)(wsb + 61 * U5);    // 4 MB
    u16*   Y16   = (u16*)(wsb + 69 * U5);      // 2 MB
    u16*   Ub    = (u16*)(wsb + 73 * U5);      // 8 MB
    float* GL    = (float*)(wsb + 89 * U5);
    int*   lists = (int*)(wsb + 89 * U5 + 32 * 1024);
    int*   counts= (int*)(wsb + 89 * U5 + 64 * 1024);

    // Convert fp32 weights to bf16 copies (needed by MFMA). Weight cast buffers:
    // total 17.8M elements -> 35.6 MB bf16. Place after Ub: offsets from 90*U5.
    u16* wb = (u16*)(wsb + 90 * U5);
    u16 *c_wq = wb;            // 768*1024
    u16 *c_wkv = c_wq + 786432;       // 256*1024
    u16 *c_wqc = c_wkv + 262144;      // 1024*768
    u16 *c_wqr = c_wqc + 786432;      // 512*768
    u16 *c_wkc = c_wqr + 393216;      // 1024*256
    u16 *c_wvc = c_wkc + 262144;      // 1024*256
    u16 *c_wo  = c_wvc + 262144;      // 1024*1024
    u16 *c_sw1 = c_wo + 1048576;      // 512*1024
    u16 *c_sw3 = c_sw1 + 524288;
    u16 *c_sw2 = c_sw3 + 524288;      // 1024*512
    u16 *c_ew1 = c_sw2 + 524288;      // 8*512*1024
    u16 *c_ew3 = c_ew1 + 4194304;
    u16 *c_ew2 = c_ew3 + 4194304;     // 8*1024*512

    // one cast kernel over all weights (copied into one call per array)
    struct WPair { const float* s; u16* d; int n; };
    // cast via a single grid-stride kernel per array using silu-less caster:
    // use lambda-style: reuse zero_i pattern with a dedicated kernel below.
    extern __global__ void cast_b16(const float*, u16*, int);
    cast_b16<<<3072, 256, 0, stream>>>(wq_down, c_wq, 786432);
    cast_b16<<<1024, 256, 0, stream>>>(wkv, c_wkv, 262144);
    cast_b16<<<3072, 256, 0, stream>>>(wqc, c_wqc, 786432);
    cast_b16<<<1536, 256, 0, stream>>>(wqr, c_wqr, 393216);
    cast_b16<<<1024, 256, 0, stream>>>(wkc, c_wkc, 262144);
    cast_b16<<<1024, 256, 0, stream>>>(wvc, c_wvc, 262144);
    cast_b16<<<4096, 256, 0, stream>>>(wo, c_wo, 1048576);
    cast_b16<<<2048, 256, 0, stream>>>(sw1, c_sw1, 524288);
    cast_b16<<<2048, 256, 0, stream>>>(sw3, c_sw3, 524288);
    cast_b16<<<2048, 256, 0, stream>>>(sw2, c_sw2, 524288);
    cast_b16<<<16384, 256, 0, stream>>>(ew1, c_ew1, 4194304);
    cast_b16<<<16384, 256, 0, stream>>>(ew3, c_ew3, 4194304);
    cast_b16<<<16384, 256, 0, stream>>>(ew2, c_ew2, 4194304);

    // --- attention branch ---
    rmsnorm_dual<<<1024, 256, 0, stream>>>(h, attn_w, X32, X16, 1024);
    mgemm<0, 0><<<dim3(8, 8), 256, 0, stream>>>(X16, 1024, 0, c_wq, 1024, 0, bq_down, 0,
        CQraw, 768, 0, 1024, nullptr, c_wkv, bkv, CKVraw, 256, 6, nullptr, nullptr, nullptr);
    gemm_k<0><<<dim3(1, 16), 256, 0, stream>>>(X32, 1024, wkr, 1024, bkr, KR, 64, 1024, nullptr);
    rmsnorm_b16<<<1024, 256, 0, stream>>>(CQraw, q_norm, CQ16, 768);
    rmsnorm_b16<<<1024, 256, 0, stream>>>(CKVraw, kv_norm, CKV16, 256);
    rmsnorm_f32<<<1024, 256, 0, stream>>>(KR, kr_norm, KR, 64);
    rope_k<<<1024, 64, 0, stream>>>(KR, fcos, fsin, 1);
    mgemm<0, 0><<<dim3(12, 8), 256, 0, stream>>>(CQ16, 768, 0, c_wqc, 768, 0, bqc, 0,
        QC, 1024, 0, 768, nullptr, c_wqr, bqr, QR, 512, 8, nullptr, nullptr, nullptr);
    rope_k<<<1024, 256, 0, stream>>>(QR, fcos, fsin, 8);
    mgemm<0, 0><<<dim3(16, 8), 256, 0, stream>>>(CKV16, 256, 0, c_wkc, 256, 0, bkc, 0,
        KC, 1024, 0, 256, nullptr, c_wvc, bvc, VC, 1024, 8, nullptr, nullptr, nullptr);
    attn_flash<<<dim3(32, 8), 256, 0, stream>>>(QC, QR, KR, KC, VC, ATT16);
    mgemm<1, 0><<<dim3(8, 8), 256, 0, stream>>>(ATT16, 1024, 0, c_wo, 1024, 0, bo, 0,
        X1, 1024, 0, 1024, h, nullptr, nullptr, nullptr, 0, 8, nullptr, nullptr, nullptr);

    // --- FFN branch ---
    rmsnorm_dual<<<1024, 256, 0, stream>>>(X1, ffn_w, Y32, Y16, 1024);
    mgemm<3, 0><<<dim3(8, 8), 256, 0, stream>>>(Y16, 1024, 0, c_sw1, 1024, 0, sb1, 0,
        Ub, 512, 0, 1024, nullptr, c_sw3, sb3, Vb, 512, 4, nullptr, nullptr, nullptr);
    silu_mul<<<2048, 256, 0, stream>>>(Ub, Vb, G16, 524288);
    mgemm<1, 0><<<dim3(8, 8), 256, 0, stream>>>(G16, 512, 0, c_sw2, 512, 0, sb2, 0,
        (float*)d_out, 1024, 0, 512, X1, nullptr, nullptr, nullptr, 0, 8, nullptr, nullptr, nullptr);

    // --- MoE ---
    zero_i<<<1, 64, 0, stream>>>(counts, 8);
    route_kernel<<<1024, 256, 0, stream>>>(Y32, cent, biases, counts, lists, GL);
    mgemm<3, 1><<<dim3(8, 8, 8), 256, 0, stream>>>(Y16, 1024, 0, c_ew1, 1024, (size_t)512 * 1024, eb1, 512,
        Ub, 512, (size_t)1024 * 512, 1024, nullptr, c_ew3, eb3, Vb, 512, 4, lists, nullptr, counts);
    silu_mul<<<16384, 256, 0, stream>>>(Ub, Vb, H1, 4194304);
    mgemm<2, 0><<<dim3(8, 8, 8), 256, 0, stream>>>(H1, 512, (size_t)1024 * 512, c_ew2, 512, (size_t)1024 * 512, eb2, 1024,
        (float*)d_out, 1024, 0, 512, nullptr, nullptr, nullptr, nullptr, 0, 8, lists, GL, counts);
}

// fp32 -> bf16 cast
__launch_bounds__(256)
__global__ void cast_b16(const float* __restrict__ S, u16* __restrict__ D, int n)
{
    int i = blockIdx.x * 256 + threadIdx.x;
    if (i < n) D[i] = f2b(S[i]);
}

// Round 6
// 615.335 us; speedup vs baseline: 2.9509x; 1.2955x over previous
//
#include <hip/hip_runtime.h>

typedef unsigned short u16;
typedef __attribute__((ext_vector_type(8))) short short8;   // 8 bf16 (4 VGPRs)
typedef __attribute__((ext_vector_type(4))) float f32x4;    // 4 fp32 acc

__device__ __forceinline__ float b2f(u16 u) { return __uint_as_float(((unsigned)u) << 16); }
__device__ __forceinline__ u16 f2b(float f) {
    unsigned x = __float_as_uint(f);
    return (u16)((x + 0x7fffu + ((x >> 16) & 1u)) >> 16);
}

// async global->LDS, 16B per lane; LDS dest = wave-uniform base + lane*16
// (global address is per-lane and may be strided; only LDS side is lane*16)
#define GLDS16(gp, lp) __builtin_amdgcn_global_load_lds( \
    (const __attribute__((address_space(1))) void*)(gp), \
    (__attribute__((address_space(3))) void*)(lp), 16, 0, 0)

// ---------------------------------------------------------------------------
// MFMA GEMM: C[M,N] = A[M,K](bf16) @ W[N,K]^T(bf16) + bias(fp32)
// 128x128 tile, BK=32, 256 threads = 4 waves in 2x2, 16x16x32 bf16 MFMA.
// EPI codes: 0 fp32 out; 1 fp32 out += res; 2 atomicAdd(gate*(acc+bias));
//            3 bf16 out.  EPI2 applies to the W2 (paired) half.
// GATHER: A row r -> lists[e*1024 + r] (MoE up).
// ---------------------------------------------------------------------------
template<int EPI, int EPI2, int GATHER>
__launch_bounds__(256)
__global__ void mgemm(const u16* __restrict__ A, int lda, size_t astride,
                      const u16* __restrict__ W, int ldw, size_t wstride,
                      const float* __restrict__ bias, int bstride,
                      void* __restrict__ Cv, int ldc, size_t cstride,
                      int K,
                      const float* __restrict__ res,
                      const u16* __restrict__ W2, const float* __restrict__ bias2,
                      void* __restrict__ C2v, int ldc2, int nsplit,
                      const int* __restrict__ lists, const float* __restrict__ glist,
                      const int* __restrict__ counts)
{
    __shared__ u16 As[4096];   // [128][32] bf16
    __shared__ u16 Bs[4096];
    int bx = blockIdx.x, by = blockIdx.y, e = blockIdx.z;
    int cnt = 1 << 30;
    const int* list = nullptr; const float* gl = nullptr;
    if (counts) {
        cnt = counts[e];
        if (GATHER || EPI == 2) list = lists + (e << 10);
        if (EPI == 2) gl = glist + (e << 10);
    }
    int row0 = by * 128;
    if (counts && row0 >= cnt) return;
    bool is2 = false;
    const u16* Wp = W; const float* bp = bias; void* Cp = Cv; int ldco = ldc;
    if (W2 && bx >= nsplit) { is2 = true; Wp = W2; bp = bias2; Cp = C2v; ldco = ldc2; bx -= nsplit; }
    Wp += (size_t)e * wstride;
    bp += (size_t)e * bstride;
    const u16* Ap = A + (size_t)e * astride;
    int col0 = bx * 128;

    int tid = threadIdx.x;
    int lane = tid & 63, w = tid >> 6;
    int r0 = (w << 4) + (lane >> 2), kc8 = (lane & 3) << 3;
    int ar0g = row0 + r0, ar1g = row0 + r0 + 64;
    if (GATHER) {
        int i0 = ar0g < cnt ? ar0g : cnt - 1;
        int i1 = ar1g < cnt ? ar1g : cnt - 1;
        ar0g = list[i0]; ar1g = list[i1];
    }
    const u16* ga0 = Ap + (size_t)ar0g * lda + kc8;
    const u16* ga1 = Ap + (size_t)ar1g * lda + kc8;
    const u16* gb0 = Wp + (size_t)(col0 + r0) * ldw + kc8;
    const u16* gb1 = Wp + (size_t)(col0 + r0 + 64) * ldw + kc8;
    u16* lA = As + (w << 9);
    u16* lB = Bs + (w << 9);

    int wrow = (w >> 1) << 6, wcol = (w & 1) << 6;
    int fm = lane & 15, fq = lane >> 4;
    f32x4 acc[4][4] = {};

    for (int k0 = 0; k0 < K; k0 += 32) {
        GLDS16(ga0 + k0, lA);
        GLDS16(ga1 + k0, lA + 2048);
        GLDS16(gb0 + k0, lB);
        GLDS16(gb1 + k0, lB + 2048);
        __syncthreads();
        short8 af[4], bf[4];
#pragma unroll
        for (int t = 0; t < 4; t++) {
            af[t] = *(const short8*)(As + (wrow + (t << 4) + fm) * 32 + fq * 8);
            bf[t] = *(const short8*)(Bs + (wcol + (t << 4) + fm) * 32 + fq * 8);
        }
#pragma unroll
        for (int mt = 0; mt < 4; mt++)
#pragma unroll
            for (int nt = 0; nt < 4; nt++)
                acc[mt][nt] = __builtin_amdgcn_mfma_f32_16x16x32_bf16(af[mt], bf[nt], acc[mt][nt], 0, 0, 0);
        __syncthreads();
    }

    const int epi = is2 ? EPI2 : EPI;
    // C/D layout: col = lane&15, row = (lane>>4)*4 + reg   [m89/m91]
#pragma unroll
    for (int mt = 0; mt < 4; mt++) {
        int rbase = row0 + wrow + (mt << 4) + (fq << 2);
#pragma unroll
        for (int nt = 0; nt < 4; nt++) {
            int c = col0 + wcol + (nt << 4) + fm;
            float bcol = bp[c];
#pragma unroll
            for (int reg = 0; reg < 4; reg++) {
                int r = rbase + reg;
                if (counts && r >= cnt) continue;
                float v = acc[mt][nt][reg] + bcol;
                if (epi == 0)
                    ((float*)Cp)[(size_t)e * cstride + (size_t)r * ldco + c] = v;
                else if (epi == 1)
                    ((float*)Cp)[(size_t)r * ldco + c] = v + res[(size_t)r * ldco + c];
                else if (epi == 3)
                    ((u16*)Cp)[(size_t)e * cstride + (size_t)r * ldco + c] = f2b(v);
                else
                    atomicAdd(&((float*)Cp)[(size_t)list[r] * ldco + c], gl[r] * v);
            }
        }
    }
}

// ---------------------------------------------------------------------------
// MFMA flash attention. Block = (64 q-rows, head); 4 waves; wave = 16 q-rows.
// Qp[h][s][192]=[qC|qR], Kp[h][s][192]=[kR|kC] (reference's asymmetric concat),
// VT[d][kv] bf16. Online softmax with shfl row reductions; P re-laid via LDS.
// ---------------------------------------------------------------------------
__launch_bounds__(256)
__global__ void attn_mfma(const u16* __restrict__ Qp, const u16* __restrict__ Kp,
                          const u16* __restrict__ VT, u16* __restrict__ O)
{
    const int qt = blockIdx.x, h = blockIdx.y;
    const int q0 = qt * 64;
    const int tid = threadIdx.x;
    const int lane = tid & 63, w = tid >> 6;
    const int fm = lane & 15, fq = lane >> 4;

    __shared__ u16 Ks[6 * 2048];   // [c][kv 64][32] — mgemm bank pattern
    __shared__ u16 Vs[2 * 4096];   // [kc][d 128][32]
    __shared__ u16 Ps[4 * 1024];   // [wave][kc][m 16][32]

    const u16* qrow = Qp + ((size_t)h * 1024 + q0 + w * 16 + fm) * 192;
    short8 qf[6];
#pragma unroll
    for (int c = 0; c < 6; c++)
        qf[c] = *(const short8*)(qrow + c * 32 + fq * 8);

    const u16* Kb = Kp + (size_t)h * 1024 * 192;
    const u16* Vb = VT + (size_t)h * 128 * 1024;

    float m_i[4], l_i[4];
#pragma unroll
    for (int r = 0; r < 4; r++) { m_i[r] = -1e30f; l_i[r] = 0.f; }
    f32x4 accO[8] = {};
    const float scale = 0.07216878364870323f;  // 1/sqrt(192)

    for (int kt = 0; kt <= qt; ++kt) {
        const int kt0 = kt * 64;
        // stage K: 24 x 1KB issues, wave-strided; per-lane strided global addrs
#pragma unroll
        for (int i = 0; i < 6; i++) {
            int idx = w + 4 * i;
            int c = idx >> 2, k4 = idx & 3;
            const u16* g = Kb + (size_t)(kt0 + k4 * 16 + (lane >> 2)) * 192 + c * 32 + (lane & 3) * 8;
            GLDS16(g, Ks + c * 2048 + k4 * 512 + lane * 8);
        }
        // stage V: 16 x 1KB issues
#pragma unroll
        for (int i = 0; i < 4; i++) {
            int idx = w + 4 * i;
            int kc = idx >> 3, k8 = idx & 7;
            const u16* g = Vb + (size_t)(k8 * 16 + (lane >> 2)) * 1024 + kt0 + kc * 32 + (lane & 3) * 8;
            GLDS16(g, Vs + kc * 4096 + k8 * 512 + lane * 8);
        }
        __syncthreads();
        // ---- S = Q K^T (24 MFMAs) ----
        f32x4 sacc[4] = {};
#pragma unroll
        for (int nt = 0; nt < 4; nt++)
#pragma unroll
            for (int c = 0; c < 6; c++) {
                short8 kf = *(const short8*)(Ks + c * 2048 + (nt * 16 + fm) * 32 + fq * 8);
                sacc[nt] = __builtin_amdgcn_mfma_f32_16x16x32_bf16(qf[c], kf, sacc[nt], 0, 0, 0);
            }
        // ---- online softmax in C-layout (row = w*16+fq*4+reg, col = nt*16+fm) ----
        const bool diag = (kt == qt);
        const int rbase = w * 16 + fq * 4;
        float pv[4][4], rmax[4];
#pragma unroll
        for (int reg = 0; reg < 4; reg++) {
            float mx = -1e30f;
#pragma unroll
            for (int nt = 0; nt < 4; nt++) {
                float s = sacc[nt][reg] * scale;
                if (diag && (nt * 16 + fm) > (rbase + reg)) s = -1e30f;
                pv[nt][reg] = s;
                mx = fmaxf(mx, s);
            }
            rmax[reg] = mx;
        }
#pragma unroll
        for (int m = 1; m < 16; m <<= 1)
#pragma unroll
            for (int reg = 0; reg < 4; reg++)
                rmax[reg] = fmaxf(rmax[reg], __shfl_xor(rmax[reg], m));
        float alpha[4], rsum[4];
#pragma unroll
        for (int reg = 0; reg < 4; reg++) {
            float mn = fmaxf(m_i[reg], rmax[reg]);
            alpha[reg] = __expf(m_i[reg] - mn);
            m_i[reg] = mn;
            float s = 0.f;
#pragma unroll
            for (int nt = 0; nt < 4; nt++) {
                float p = __expf(pv[nt][reg] - mn);
                pv[nt][reg] = p;
                s += p;
            }
            rsum[reg] = s;
        }
#pragma unroll
        for (int m = 1; m < 16; m <<= 1)
#pragma unroll
            for (int reg = 0; reg < 4; reg++)
                rsum[reg] += __shfl_xor(rsum[reg], m);
#pragma unroll
        for (int reg = 0; reg < 4; reg++)
            l_i[reg] = l_i[reg] * alpha[reg] + rsum[reg];
        // ---- P (C-layout) -> LDS (A-layout, bf16); per-wave private slice ----
#pragma unroll
        for (int nt = 0; nt < 4; nt++)
#pragma unroll
            for (int reg = 0; reg < 4; reg++)
                Ps[w * 1024 + (nt >> 1) * 512 + (fq * 4 + reg) * 32 + (nt & 1) * 16 + fm]
                    = f2b(pv[nt][reg]);
        // ---- rescale O, then O += P V (16 MFMAs) ----
#pragma unroll
        for (int n2 = 0; n2 < 8; n2++)
#pragma unroll
            for (int reg = 0; reg < 4; reg++)
                accO[n2][reg] *= alpha[reg];
        short8 pf[2];
#pragma unroll
        for (int kc = 0; kc < 2; kc++)
            pf[kc] = *(const short8*)(Ps + w * 1024 + kc * 512 + fm * 32 + fq * 8);
#pragma unroll
        for (int n2 = 0; n2 < 8; n2++)
#pragma unroll
            for (int kc = 0; kc < 2; kc++) {
                short8 vf = *(const short8*)(Vs + kc * 4096 + (n2 * 16 + fm) * 32 + fq * 8);
                accO[n2] = __builtin_amdgcn_mfma_f32_16x16x32_bf16(pf[kc], vf, accO[n2], 0, 0, 0);
            }
        __syncthreads();
    }
    // ---- epilogue: O / l -> bf16 ----
#pragma unroll
    for (int reg = 0; reg < 4; reg++) {
        int row = q0 + w * 16 + fq * 4 + reg;
        float inv = 1.f / l_i[reg];
#pragma unroll
        for (int n2 = 0; n2 < 8; n2++)
            O[(size_t)row * 1024 + h * 128 + n2 * 16 + fm] = f2b(accO[n2][reg] * inv);
    }
}

// ---------------------------------------------------------------------------
// pack Q/K into per-head bf16 [h][s][192] with the reference concat orders
// ---------------------------------------------------------------------------
__launch_bounds__(256)
__global__ void pack_qk(const float* __restrict__ QC, const float* __restrict__ QR,
                        const float* __restrict__ KR, const float* __restrict__ KC,
                        u16* __restrict__ Qp, u16* __restrict__ Kp)
{
    int s = blockIdx.x, tid = threadIdx.x;
    for (int e = tid; e < 1536; e += 256) {
        int h = e / 192, d = e % 192;
        float q = (d < 128) ? QC[(size_t)s * 1024 + h * 128 + d]
                            : QR[(size_t)s * 512 + h * 64 + d - 128];
        Qp[((size_t)h * 1024 + s) * 192 + d] = f2b(q);
        float k = (d < 64) ? KR[(size_t)s * 64 + d]
                           : KC[(size_t)s * 1024 + h * 128 + d - 64];
        Kp[((size_t)h * 1024 + s) * 192 + d] = f2b(k);
    }
}

// transpose bf16 [s][d] -> [d][s] (1024x1024), 64x64 tiles via LDS
__launch_bounds__(256)
__global__ void transpose_v(const u16* __restrict__ Vb, u16* __restrict__ VT)
{
    __shared__ u16 Ts[64][68];
    int s0 = blockIdx.x * 64, d0 = blockIdx.y * 64;
    int tid = threadIdx.x;
    for (int k = 0; k < 16; k++) {
        int e = tid + k * 256;
        int r = e >> 6, c = e & 63;
        Ts[r][c] = Vb[(size_t)(s0 + r) * 1024 + d0 + c];
    }
    __syncthreads();
    for (int k = 0; k < 16; k++) {
        int e = tid + k * 256;
        int d = e >> 6, s = e & 63;
        VT[(size_t)(d0 + d) * 1024 + s0 + s] = Ts[s][d];
    }
}

// ---------------------------------------------------------------------------
// RMSNorm variants (fp32 in)
// ---------------------------------------------------------------------------
__launch_bounds__(256)
__global__ void rmsnorm_dual(const float* __restrict__ X, const float* __restrict__ w,
                             float* __restrict__ O32, u16* __restrict__ O16, int cols)
{
    int r = blockIdx.x, tid = threadIdx.x;
    const float* xr = X + (size_t)r * cols;
    float ss = 0.f;
    for (int j = tid; j < cols; j += 256) { float v = xr[j]; ss += v * v; }
    __shared__ float red[256];
    red[tid] = ss; __syncthreads();
    for (int st = 128; st > 0; st >>= 1) { if (tid < st) red[tid] += red[tid + st]; __syncthreads(); }
    float scale = rsqrtf(red[0] / cols + 1e-6f);
    for (int j = tid; j < cols; j += 256) {
        float v = xr[j] * scale * w[j];
        O32[(size_t)r * cols + j] = v;
        O16[(size_t)r * cols + j] = f2b(v);
    }
}

__launch_bounds__(256)
__global__ void rmsnorm_b16(const float* __restrict__ X, const float* __restrict__ w,
                            u16* __restrict__ O, int cols)
{
    int r = blockIdx.x, tid = threadIdx.x;
    const float* xr = X + (size_t)r * cols;
    float ss = 0.f;
    for (int j = tid; j < cols; j += 256) { float v = xr[j]; ss += v * v; }
    __shared__ float red[256];
    red[tid] = ss; __syncthreads();
    for (int st = 128; st > 0; st >>= 1) { if (tid < st) red[tid] += red[tid + st]; __syncthreads(); }
    float scale = rsqrtf(red[0] / cols + 1e-6f);
    for (int j = tid; j < cols; j += 256)
        O[(size_t)r * cols + j] = f2b(xr[j] * scale * w[j]);
}

__launch_bounds__(256)
__global__ void rmsnorm_f32(const float* __restrict__ X, const float* __restrict__ w,
                            float* __restrict__ O, int cols)
{
    int r = blockIdx.x, tid = threadIdx.x;
    const float* xr = X + (size_t)r * cols;
    float ss = 0.f;
    for (int j = tid; j < cols; j += 256) { float v = xr[j]; ss += v * v; }
    __shared__ float red[256];
    red[tid] = ss; __syncthreads();
    for (int st = 128; st > 0; st >>= 1) { if (tid < st) red[tid] += red[tid + st]; __syncthreads(); }
    float scale = rsqrtf(red[0] / cols + 1e-6f);
    for (int j = tid; j < cols; j += 256)
        O[(size_t)r * cols + j] = xr[j] * scale * w[j];
}

// ---------------------------------------------------------------------------
// RoPE in-place on fp32 (S, nh*64)
// ---------------------------------------------------------------------------
__global__ void rope_k(float* __restrict__ X, const float* __restrict__ C,
                       const float* __restrict__ Sn, int nh)
{
    int s = blockIdx.x;
    int n = nh * 32;
    for (int i = threadIdx.x; i < n; i += blockDim.x) {
        int h = i >> 5, j = i & 31;
        float c  = C[s * 32 + j];
        float sn = Sn[s * 32 + j];
        float* p = X + (size_t)s * nh * 64 + h * 64 + 2 * j;
        float x0 = p[0], x1 = p[1];
        p[0] = x0 * c - x1 * sn;
        p[1] = x0 * sn + x1 * c;
    }
}

// ---------------------------------------------------------------------------
// fp32 vector GEMM (kept only for wkr, N=64)
// ---------------------------------------------------------------------------
template<int EPI>
__launch_bounds__(256)
__global__ void gemm_k(const float* __restrict__ A, int lda,
                       const float* __restrict__ W, int ldw,
                       const float* __restrict__ bias,
                       float* __restrict__ C, int ldc, int K,
                       const float* __restrict__ res)
{
    __shared__ float As[16][64];
    __shared__ float Bs[16][64];
    int tid = threadIdx.x;
    int tx = tid & 15, ty = tid >> 4;
    int rowBase = blockIdx.y * 64, colBase = blockIdx.x * 64;
    int lm = tid >> 2;
    int lk = (tid & 3) << 2;
    float acc[4][4] = {};
    for (int k0 = 0; k0 < K; k0 += 16) {
        float4 av = *(const float4*)(A + (size_t)(rowBase + lm) * lda + k0 + lk);
        As[lk + 0][lm] = av.x; As[lk + 1][lm] = av.y;
        As[lk + 2][lm] = av.z; As[lk + 3][lm] = av.w;
        float4 wv = *(const float4*)(W + (size_t)(colBase + lm) * ldw + k0 + lk);
        Bs[lk + 0][lm] = wv.x; Bs[lk + 1][lm] = wv.y;
        Bs[lk + 2][lm] = wv.z; Bs[lk + 3][lm] = wv.w;
        __syncthreads();
#pragma unroll
        for (int kk = 0; kk < 16; ++kk) {
            float a[4], b[4];
#pragma unroll
            for (int i = 0; i < 4; i++) a[i] = As[kk][ty * 4 + i];
#pragma unroll
            for (int j = 0; j < 4; j++) b[j] = Bs[kk][tx * 4 + j];
#pragma unroll
            for (int i = 0; i < 4; i++)
#pragma unroll
                for (int j = 0; j < 4; j++) acc[i][j] += a[i] * b[j];
        }
        __syncthreads();
    }
#pragma unroll
    for (int i = 0; i < 4; i++) {
        int row = rowBase + ty * 4 + i;
#pragma unroll
        for (int j = 0; j < 4; j++) {
            int col = colBase + tx * 4 + j;
            float v = acc[i][j] + bias[col];
            if (EPI == 1) v += res[(size_t)row * ldc + col];
            C[(size_t)row * ldc + col] = v;
        }
    }
}

// ---------------------------------------------------------------------------
// silu-mul: G = bf16(silu(U) * V)
// ---------------------------------------------------------------------------
__launch_bounds__(256)
__global__ void silu_mul(const u16* __restrict__ U, const u16* __restrict__ V,
                         u16* __restrict__ G, int n)
{
    int i = blockIdx.x * 256 + threadIdx.x;
    if (i < n) {
        float u = b2f(U[i]), v = b2f(V[i]);
        G[i] = f2b(u / (1.f + expf(-u)) * v);
    }
}

// ---------------------------------------------------------------------------
// Fused fp32->bf16 cast of all 13 weight arrays into the contiguous arena
// ---------------------------------------------------------------------------
__launch_bounds__(256)
__global__ void fused_cast(const float* p0, const float* p1, const float* p2,
                           const float* p3, const float* p4, const float* p5,
                           const float* p6, const float* p7, const float* p8,
                           const float* p9, const float* p10, const float* p11,
                           const float* p12, u16* __restrict__ dst)
{
    const int NQ = 17956864 / 4;
    for (int i = blockIdx.x * 256 + threadIdx.x; i < NQ; i += gridDim.x * 256) {
        int e = i * 4;
        const float* s; int base;
        if      (e <   786432) { s = p0;  base = 0; }
        else if (e <  1048576) { s = p1;  base =   786432; }
        else if (e <  1835008) { s = p2;  base =  1048576; }
        else if (e <  2228224) { s = p3;  base =  1835008; }
        else if (e <  2490368) { s = p4;  base =  2228224; }
        else if (e <  2752512) { s = p5;  base =  2490368; }
        else if (e <  3801088) { s = p6;  base =  2752512; }
        else if (e <  4325376) { s = p7;  base =  3801088; }
        else if (e <  4849664) { s = p8;  base =  4325376; }
        else if (e <  5373952) { s = p9;  base =  4849664; }
        else if (e <  9568256) { s = p10; base =  5373952; }
        else if (e < 13762560) { s = p11; base =  9568256; }
        else                   { s = p12; base = 13762560; }
        float4 v = *(const float4*)(s + (e - base));
        ushort4 o;
        o.x = f2b(v.x); o.y = f2b(v.y); o.z = f2b(v.z); o.w = f2b(v.w);
        *(ushort4*)(dst + e) = o;
    }
}

// ---------------------------------------------------------------------------
// Routing (fp32)
// ---------------------------------------------------------------------------
__launch_bounds__(256)
__global__ void route_kernel(const float* __restrict__ Y, const float* __restrict__ cent,
                             const float* __restrict__ biases,
                             int* __restrict__ counts, int* __restrict__ lists,
                             float* __restrict__ glist)
{
    int t = blockIdx.x, tid = threadIdx.x;
    float acc[8] = {};
    for (int j = tid; j < 1024; j += 256) {
        float yv = Y[(size_t)t * 1024 + j];
#pragma unroll
        for (int e = 0; e < 8; e++) acc[e] += yv * cent[e * 1024 + j];
    }
    __shared__ float red[256];
    __shared__ float aff[8];
    for (int e = 0; e < 8; e++) {
        red[tid] = acc[e]; __syncthreads();
        for (int st = 128; st > 0; st >>= 1) { if (tid < st) red[tid] += red[tid + st]; __syncthreads(); }
        if (tid == 0) aff[e] = 1.f / (1.f + expf(-red[0]));
        __syncthreads();
    }
    if (tid == 0) {
        float sb[8];
#pragma unroll
        for (int e = 0; e < 8; e++) sb[e] = aff[e] + biases[e];
        int i0 = 0;
        for (int e = 1; e < 8; e++) if (sb[e] > sb[i0]) i0 = e;
        int i1 = -1;
        for (int e = 0; e < 8; e++) { if (e == i0) continue; if (i1 < 0 || sb[e] > sb[i1]) i1 = e; }
        float a0 = aff[i0], a1 = aff[i1];
        float mx = fmaxf(a0, a1);
        float e0 = expf(a0 - mx), e1 = expf(a1 - mx);
        float inv = 1.f / (e0 + e1);
        int p0 = atomicAdd(&counts[i0], 1);
        lists[i0 * 1024 + p0] = t; glist[i0 * 1024 + p0] = e0 * inv;
        int p1 = atomicAdd(&counts[i1], 1);
        lists[i1 * 1024 + p1] = t; glist[i1 * 1024 + p1] = e1 * inv;
    }
}

__global__ void zero_i(int* p, int n)
{
    int i = blockIdx.x * blockDim.x + threadIdx.x;
    if (i < n) p[i] = 0;
}

// ---------------------------------------------------------------------------
extern "C" void kernel_launch(void* const* d_in, const int* in_sizes, int n_in,
                              void* d_out, int out_size, void* d_ws, size_t ws_size,
                              hipStream_t stream)
{
    (void)in_sizes; (void)n_in; (void)ws_size; (void)out_size;
    const float* h       = (const float*)d_in[0];
    const float* fcos    = (const float*)d_in[1];
    const float* fsin    = (const float*)d_in[2];
    const float* attn_w  = (const float*)d_in[4];
    const float* ffn_w   = (const float*)d_in[5];
    const float* wq_down = (const float*)d_in[6];
    const float* bq_down = (const float*)d_in[7];
    const float* q_norm  = (const float*)d_in[8];
    const float* wqc     = (const float*)d_in[9];
    const float* bqc     = (const float*)d_in[10];
    const float* wqr     = (const float*)d_in[11];
    const float* bqr     = (const float*)d_in[12];
    const float* wkr     = (const float*)d_in[13];
    const float* bkr     = (const float*)d_in[14];
    const float* kr_norm = (const float*)d_in[15];
    const float* wkv     = (const float*)d_in[16];
    const float* bkv     = (const float*)d_in[17];
    const float* kv_norm = (const float*)d_in[18];
    const float* wkc     = (const float*)d_in[19];
    const float* bkc     = (const float*)d_in[20];
    const float* wvc     = (const float*)d_in[21];
    const float* bvc     = (const float*)d_in[22];
    const float* wo      = (const float*)d_in[23];
    const float* bo      = (const float*)d_in[24];
    const float* sw1     = (const float*)d_in[25];
    const float* sb1     = (const float*)d_in[26];
    const float* sw2     = (const float*)d_in[27];
    const float* sb2     = (const float*)d_in[28];
    const float* sw3     = (const float*)d_in[29];
    const float* sb3     = (const float*)d_in[30];
    const float* ew1     = (const float*)d_in[31];
    const float* eb1     = (const float*)d_in[32];
    const float* ew2     = (const float*)d_in[33];
    const float* eb2     = (const float*)d_in[34];
    const float* ew3     = (const float*)d_in[35];
    const float* eb3     = (const float*)d_in[36];
    const float* cent    = (const float*)d_in[37];
    const float* biases  = (const float*)d_in[38];

    char* wsb = (char*)d_ws;
    const size_t U5 = 512 * 1024;  // 0.5 MB unit
    u16*   H1    = (u16*)(wsb + 0);            // 8 MB  (MoE phase)
    float* X32   = (float*)(wsb + 0);          // 4 MB  (early)
    u16*   X16   = (u16*)(wsb + 8 * U5);       // 2 MB  (early)
    float* QR    = (float*)(wsb + 12 * U5);    // 2 MB  (dead after pack)
    float* CQraw = (float*)(wsb + 16 * U5);    // 3 MB  (early)
    u16*   ATT16 = (u16*)(wsb + 16 * U5);      // 2 MB  (attn out)
    u16*   G16   = (u16*)(wsb + 20 * U5);      // 1 MB
    u16*   CQ16  = (u16*)(wsb + 22 * U5);      // 1.5 MB
    float* CKVraw= (float*)(wsb + 25 * U5);    // 1 MB
    u16*   CKV16 = (u16*)(wsb + 27 * U5);      // 0.5 MB
    float* KR    = (float*)(wsb + 28 * U5);    // 0.25 MB
    float* QC    = (float*)(wsb + 29 * U5);    // 4 MB  (dead after pack)
    float* KC    = (float*)(wsb + 37 * U5);    // 4 MB  (dead after pack)
    u16*   Vb    = (u16*)(wsb + 29 * U5);      // 8 MB  (MoE phase, overlays QC+KC)
    float* X1    = (float*)(wsb + 53 * U5);    // 4 MB
    float* Y32   = (float*)(wsb + 61 * U5);    // 4 MB
    u16*   Y16   = (u16*)(wsb + 69 * U5);      // 2 MB
    u16*   Ub    = (u16*)(wsb + 73 * U5);      // 8 MB
    float* GL    = (float*)(wsb + 89 * U5);
    int*   lists = (int*)(wsb + 89 * U5 + 32 * 1024);
    int*   counts= (int*)(wsb + 89 * U5 + 64 * 1024);

    // bf16 weight arena (contiguous, order matches fused_cast)
    u16* wb = (u16*)(wsb + 90 * U5);
    u16 *c_wq  = wb;
    u16 *c_wkv = c_wq  + 786432;
    u16 *c_wqc = c_wkv + 262144;
    u16 *c_wqr = c_wqc + 786432;
    u16 *c_wkc = c_wqr + 393216;
    u16 *c_wvc = c_wkc + 262144;
    u16 *c_wo  = c_wvc + 262144;
    u16 *c_sw1 = c_wo  + 1048576;
    u16 *c_sw3 = c_sw1 + 524288;
    u16 *c_sw2 = c_sw3 + 524288;
    u16 *c_ew1 = c_sw2 + 524288;
    u16 *c_ew3 = c_ew1 + 4194304;
    u16 *c_ew2 = c_ew3 + 4194304;
    // attention packed buffers after the arena (35,913,728 B)
    u16* VCb = (u16*)(wsb + 90 * U5 + 35913728);  // 2 MB  bf16 V [s][d]
    u16* VTp = VCb + 1048576;                     // 2 MB  bf16 V^T [d][s]
    u16* Qpk = VTp + 1048576;                     // 3 MB
    u16* Kpk = Qpk + 1572864;                     // 3 MB

    fused_cast<<<4096, 256, 0, stream>>>(wq_down, wkv, wqc, wqr, wkc, wvc, wo,
                                         sw1, sw3, sw2, ew1, ew3, ew2, wb);

    // --- attention branch ---
    rmsnorm_dual<<<1024, 256, 0, stream>>>(h, attn_w, X32, X16, 1024);
    mgemm<0, 0, 0><<<dim3(8, 8), 256, 0, stream>>>(X16, 1024, 0, c_wq, 1024, 0, bq_down, 0,
        CQraw, 768, 0, 1024, nullptr, c_wkv, bkv, CKVraw, 256, 6, nullptr, nullptr, nullptr);
    gemm_k<0><<<dim3(1, 16), 256, 0, stream>>>(X32, 1024, wkr, 1024, bkr, KR, 64, 1024, nullptr);
    rmsnorm_b16<<<1024, 256, 0, stream>>>(CQraw, q_norm, CQ16, 768);
    rmsnorm_b16<<<1024, 256, 0, stream>>>(CKVraw, kv_norm, CKV16, 256);
    rmsnorm_f32<<<1024, 256, 0, stream>>>(KR, kr_norm, KR, 64);
    rope_k<<<1024, 64, 0, stream>>>(KR, fcos, fsin, 1);
    mgemm<0, 0, 0><<<dim3(12, 8), 256, 0, stream>>>(CQ16, 768, 0, c_wqc, 768, 0, bqc, 0,
        QC, 1024, 0, 768, nullptr, c_wqr, bqr, QR, 512, 8, nullptr, nullptr, nullptr);
    rope_k<<<1024, 256, 0, stream>>>(QR, fcos, fsin, 8);
    mgemm<0, 3, 0><<<dim3(16, 8), 256, 0, stream>>>(CKV16, 256, 0, c_wkc, 256, 0, bkc, 0,
        KC, 1024, 0, 256, nullptr, c_wvc, bvc, VCb, 1024, 8, nullptr, nullptr, nullptr);
    pack_qk<<<1024, 256, 0, stream>>>(QC, QR, KR, KC, Qpk, Kpk);
    transpose_v<<<dim3(16, 16), 256, 0, stream>>>(VCb, VTp);
    attn_mfma<<<dim3(16, 8), 256, 0, stream>>>(Qpk, Kpk, VTp, ATT16);
    mgemm<1, 0, 0><<<dim3(8, 8), 256, 0, stream>>>(ATT16, 1024, 0, c_wo, 1024, 0, bo, 0,
        X1, 1024, 0, 1024, h, nullptr, nullptr, nullptr, 0, 8, nullptr, nullptr, nullptr);

    // --- FFN branch ---
    rmsnorm_dual<<<1024, 256, 0, stream>>>(X1, ffn_w, Y32, Y16, 1024);
    mgemm<3, 3, 0><<<dim3(8, 8), 256, 0, stream>>>(Y16, 1024, 0, c_sw1, 1024, 0, sb1, 0,
        Ub, 512, 0, 1024, nullptr, c_sw3, sb3, Vb, 512, 4, nullptr, nullptr, nullptr);
    silu_mul<<<2048, 256, 0, stream>>>(Ub, Vb, G16, 524288);
    mgemm<1, 0, 0><<<dim3(8, 8), 256, 0, stream>>>(G16, 512, 0, c_sw2, 512, 0, sb2, 0,
        (float*)d_out, 1024, 0, 512, X1, nullptr, nullptr, nullptr, 0, 8, nullptr, nullptr, nullptr);

    // --- MoE ---
    zero_i<<<1, 64, 0, stream>>>(counts, 8);
    route_kernel<<<1024, 256, 0, stream>>>(Y32, cent, biases, counts, lists, GL);
    mgemm<3, 3, 1><<<dim3(8, 8, 8), 256, 0, stream>>>(Y16, 1024, 0, c_ew1, 1024, (size_t)512 * 1024, eb1, 512,
        Ub, 512, (size_t)1024 * 512, 1024, nullptr, c_ew3, eb3, Vb, 512, 4, lists, nullptr, counts);
    silu_mul<<<16384, 256, 0, stream>>>(Ub, Vb, H1, 4194304);
    mgemm<2, 0, 0><<<dim3(8, 8, 8), 256, 0, stream>>>(H1, 512, (size_t)1024 * 512, c_ew2, 512, (size_t)1024 * 512, eb2, 1024,
        (float*)d_out, 1024, 0, 512, nullptr, nullptr, nullptr, nullptr, 0, 8, lists, GL, counts);
}

// Round 7
// 572.585 us; speedup vs baseline: 3.1712x; 1.0747x over previous
//
#include <hip/hip_runtime.h>

typedef unsigned short u16;
typedef __attribute__((ext_vector_type(8))) short short8;   // 8 bf16 (4 VGPRs)
typedef __attribute__((ext_vector_type(4))) float f32x4;    // 4 fp32 acc

__device__ __forceinline__ float b2f(u16 u) { return __uint_as_float(((unsigned)u) << 16); }
__device__ __forceinline__ u16 f2b(float f) {
    unsigned x = __float_as_uint(f);
    return (u16)((x + 0x7fffu + ((x >> 16) & 1u)) >> 16);
}

// async global->LDS, 16B per lane; LDS dest = wave-uniform base + lane*16
#define GLDS16(gp, lp) __builtin_amdgcn_global_load_lds( \
    (const __attribute__((address_space(1))) void*)(gp), \
    (__attribute__((address_space(3))) void*)(lp), 16, 0, 0)

// ---------------------------------------------------------------------------
// Grouped MFMA GEMM: up to 4 column-segments, 2 A operands.
// C[M, seg] = A[aidx] @ W^T + bias, 128x128 tile, BK=32, 4 waves 2x2.
// epi: 0 fp32 out; 1 fp32 out += res; 3 bf16 out.
// ---------------------------------------------------------------------------
struct Seg { const u16* W; const float* bias; void* C; int ldc; int epi; int bx0; int aidx; };
struct GArgs {
    const u16* A[2]; int lda[2]; int K[2];
    Seg seg[4]; int nseg;
    const float* res;
};

__launch_bounds__(256)
__global__ void mgemm4(GArgs ga)
{
    __shared__ u16 As[4096];   // [128][32] bf16
    __shared__ u16 Bs[4096];
    int bx = blockIdx.x, by = blockIdx.y;
    int si = 0;
#pragma unroll
    for (int i = 1; i < 4; i++)
        if (i < ga.nseg && bx >= ga.seg[i].bx0) si = i;
    const u16* Wp = ga.seg[si].W;
    const float* bp = ga.seg[si].bias;
    void* Cp = ga.seg[si].C;
    const int ldco = ga.seg[si].ldc;
    const int epi = ga.seg[si].epi;
    const int ai = ga.seg[si].aidx;
    const u16* Ap = ga.A[ai];
    const int lda = ga.lda[ai], K = ga.K[ai];
    const int col0 = (bx - ga.seg[si].bx0) * 128;
    const int row0 = by * 128;

    int tid = threadIdx.x;
    int lane = tid & 63, w = tid >> 6;
    int r0 = (w << 4) + (lane >> 2), kc8 = (lane & 3) << 3;
    const u16* ga0 = Ap + (size_t)(row0 + r0) * lda + kc8;
    const u16* ga1 = Ap + (size_t)(row0 + r0 + 64) * lda + kc8;
    const u16* gb0 = Wp + (size_t)(col0 + r0) * lda + kc8;        // ldw == lda (K-major)
    const u16* gb1 = Wp + (size_t)(col0 + r0 + 64) * lda + kc8;
    u16* lA = As + (w << 9);
    u16* lB = Bs + (w << 9);

    int wrow = (w >> 1) << 6, wcol = (w & 1) << 6;
    int fm = lane & 15, fq = lane >> 4;
    f32x4 acc[4][4] = {};

    for (int k0 = 0; k0 < K; k0 += 32) {
        GLDS16(ga0 + k0, lA);
        GLDS16(ga1 + k0, lA + 2048);
        GLDS16(gb0 + k0, lB);
        GLDS16(gb1 + k0, lB + 2048);
        __syncthreads();
        short8 af[4], bf[4];
#pragma unroll
        for (int t = 0; t < 4; t++) {
            af[t] = *(const short8*)(As + (wrow + (t << 4) + fm) * 32 + fq * 8);
            bf[t] = *(const short8*)(Bs + (wcol + (t << 4) + fm) * 32 + fq * 8);
        }
#pragma unroll
        for (int mt = 0; mt < 4; mt++)
#pragma unroll
            for (int nt = 0; nt < 4; nt++)
                acc[mt][nt] = __builtin_amdgcn_mfma_f32_16x16x32_bf16(af[mt], bf[nt], acc[mt][nt], 0, 0, 0);
        __syncthreads();
    }

    // C/D layout: col = lane&15, row = (lane>>4)*4 + reg   [m89/m91]
#pragma unroll
    for (int mt = 0; mt < 4; mt++) {
        int rbase = row0 + wrow + (mt << 4) + (fq << 2);
#pragma unroll
        for (int nt = 0; nt < 4; nt++) {
            int c = col0 + wcol + (nt << 4) + fm;
            float bcol = bp[c];
#pragma unroll
            for (int reg = 0; reg < 4; reg++) {
                int r = rbase + reg;
                float v = acc[mt][nt][reg] + bcol;
                if (epi == 3)
                    ((u16*)Cp)[(size_t)r * ldco + c] = f2b(v);
                else if (epi == 1)
                    ((float*)Cp)[(size_t)r * ldco + c] = v + ga.res[(size_t)r * ldco + c];
                else
                    ((float*)Cp)[(size_t)r * ldco + c] = v;
            }
        }
    }
}

// ---------------------------------------------------------------------------
// MoE MFMA GEMM (per-expert z-dim, gather / atomic-scatter). As round 6.
// EPI: 2 atomicAdd(gate*(acc+bias)); 3 bf16 out. GATHER: A row via lists.
// ---------------------------------------------------------------------------
template<int EPI, int EPI2, int GATHER>
__launch_bounds__(256)
__global__ void mgemm(const u16* __restrict__ A, int lda, size_t astride,
                      const u16* __restrict__ W, int ldw, size_t wstride,
                      const float* __restrict__ bias, int bstride,
                      void* __restrict__ Cv, int ldc, size_t cstride,
                      int K,
                      const u16* __restrict__ W2, const float* __restrict__ bias2,
                      void* __restrict__ C2v, int ldc2, int nsplit,
                      const int* __restrict__ lists, const float* __restrict__ glist,
                      const int* __restrict__ counts)
{
    __shared__ u16 As[4096];
    __shared__ u16 Bs[4096];
    int bx = blockIdx.x, by = blockIdx.y, e = blockIdx.z;
    int cnt = counts[e];
    const int* list = lists + (e << 10);
    const float* gl = (EPI == 2) ? glist + (e << 10) : nullptr;
    int row0 = by * 128;
    if (row0 >= cnt) return;
    bool is2 = false;
    const u16* Wp = W; const float* bp = bias; void* Cp = Cv; int ldco = ldc;
    if (W2 && bx >= nsplit) { is2 = true; Wp = W2; bp = bias2; Cp = C2v; ldco = ldc2; bx -= nsplit; }
    Wp += (size_t)e * wstride;
    bp += (size_t)e * bstride;
    const u16* Ap = A + (size_t)e * astride;
    int col0 = bx * 128;

    int tid = threadIdx.x;
    int lane = tid & 63, w = tid >> 6;
    int r0 = (w << 4) + (lane >> 2), kc8 = (lane & 3) << 3;
    int ar0g = row0 + r0, ar1g = row0 + r0 + 64;
    if (GATHER) {
        int i0 = ar0g < cnt ? ar0g : cnt - 1;
        int i1 = ar1g < cnt ? ar1g : cnt - 1;
        ar0g = list[i0]; ar1g = list[i1];
    }
    const u16* ga0 = Ap + (size_t)ar0g * lda + kc8;
    const u16* ga1 = Ap + (size_t)ar1g * lda + kc8;
    const u16* gb0 = Wp + (size_t)(col0 + r0) * ldw + kc8;
    const u16* gb1 = Wp + (size_t)(col0 + r0 + 64) * ldw + kc8;
    u16* lA = As + (w << 9);
    u16* lB = Bs + (w << 9);

    int wrow = (w >> 1) << 6, wcol = (w & 1) << 6;
    int fm = lane & 15, fq = lane >> 4;
    f32x4 acc[4][4] = {};

    for (int k0 = 0; k0 < K; k0 += 32) {
        GLDS16(ga0 + k0, lA);
        GLDS16(ga1 + k0, lA + 2048);
        GLDS16(gb0 + k0, lB);
        GLDS16(gb1 + k0, lB + 2048);
        __syncthreads();
        short8 af[4], bf[4];
#pragma unroll
        for (int t = 0; t < 4; t++) {
            af[t] = *(const short8*)(As + (wrow + (t << 4) + fm) * 32 + fq * 8);
            bf[t] = *(const short8*)(Bs + (wcol + (t << 4) + fm) * 32 + fq * 8);
        }
#pragma unroll
        for (int mt = 0; mt < 4; mt++)
#pragma unroll
            for (int nt = 0; nt < 4; nt++)
                acc[mt][nt] = __builtin_amdgcn_mfma_f32_16x16x32_bf16(af[mt], bf[nt], acc[mt][nt], 0, 0, 0);
        __syncthreads();
    }

    const int epi = is2 ? EPI2 : EPI;
#pragma unroll
    for (int mt = 0; mt < 4; mt++) {
        int rbase = row0 + wrow + (mt << 4) + (fq << 2);
#pragma unroll
        for (int nt = 0; nt < 4; nt++) {
            int c = col0 + wcol + (nt << 4) + fm;
            float bcol = bp[c];
#pragma unroll
            for (int reg = 0; reg < 4; reg++) {
                int r = rbase + reg;
                if (r >= cnt) continue;
                float v = acc[mt][nt][reg] + bcol;
                if (epi == 3)
                    ((u16*)Cp)[(size_t)e * cstride + (size_t)r * ldco + c] = f2b(v);
                else
                    atomicAdd(&((float*)Cp)[(size_t)list[r] * ldco + c], gl[r] * v);
            }
        }
    }
}

// ---------------------------------------------------------------------------
// MFMA flash attention (as round 6). Qp[h][s][192]=[qC|qR], Kp=[kR|kC], VT[d][kv].
// ---------------------------------------------------------------------------
__launch_bounds__(256)
__global__ void attn_mfma(const u16* __restrict__ Qp, const u16* __restrict__ Kp,
                          const u16* __restrict__ VT, u16* __restrict__ O)
{
    const int qt = blockIdx.x, h = blockIdx.y;
    const int q0 = qt * 64;
    const int tid = threadIdx.x;
    const int lane = tid & 63, w = tid >> 6;
    const int fm = lane & 15, fq = lane >> 4;

    __shared__ u16 Ks[6 * 2048];
    __shared__ u16 Vs[2 * 4096];
    __shared__ u16 Ps[4 * 1024];

    const u16* qrow = Qp + ((size_t)h * 1024 + q0 + w * 16 + fm) * 192;
    short8 qf[6];
#pragma unroll
    for (int c = 0; c < 6; c++)
        qf[c] = *(const short8*)(qrow + c * 32 + fq * 8);

    const u16* Kb = Kp + (size_t)h * 1024 * 192;
    const u16* Vb = VT + (size_t)h * 128 * 1024;

    float m_i[4], l_i[4];
#pragma unroll
    for (int r = 0; r < 4; r++) { m_i[r] = -1e30f; l_i[r] = 0.f; }
    f32x4 accO[8] = {};
    const float scale = 0.07216878364870323f;  // 1/sqrt(192)

    for (int kt = 0; kt <= qt; ++kt) {
        const int kt0 = kt * 64;
#pragma unroll
        for (int i = 0; i < 6; i++) {
            int idx = w + 4 * i;
            int c = idx >> 2, k4 = idx & 3;
            const u16* g = Kb + (size_t)(kt0 + k4 * 16 + (lane >> 2)) * 192 + c * 32 + (lane & 3) * 8;
            GLDS16(g, Ks + c * 2048 + k4 * 512 + lane * 8);
        }
#pragma unroll
        for (int i = 0; i < 4; i++) {
            int idx = w + 4 * i;
            int kc = idx >> 3, k8 = idx & 7;
            const u16* g = Vb + (size_t)(k8 * 16 + (lane >> 2)) * 1024 + kt0 + kc * 32 + (lane & 3) * 8;
            GLDS16(g, Vs + kc * 4096 + k8 * 512 + lane * 8);
        }
        __syncthreads();
        f32x4 sacc[4] = {};
#pragma unroll
        for (int nt = 0; nt < 4; nt++)
#pragma unroll
            for (int c = 0; c < 6; c++) {
                short8 kf = *(const short8*)(Ks + c * 2048 + (nt * 16 + fm) * 32 + fq * 8);
                sacc[nt] = __builtin_amdgcn_mfma_f32_16x16x32_bf16(qf[c], kf, sacc[nt], 0, 0, 0);
            }
        const bool diag = (kt == qt);
        const int rbase = w * 16 + fq * 4;
        float pv[4][4], rmax[4];
#pragma unroll
        for (int reg = 0; reg < 4; reg++) {
            float mx = -1e30f;
#pragma unroll
            for (int nt = 0; nt < 4; nt++) {
                float s = sacc[nt][reg] * scale;
                if (diag && (nt * 16 + fm) > (rbase + reg)) s = -1e30f;
                pv[nt][reg] = s;
                mx = fmaxf(mx, s);
            }
            rmax[reg] = mx;
        }
#pragma unroll
        for (int m = 1; m < 16; m <<= 1)
#pragma unroll
            for (int reg = 0; reg < 4; reg++)
                rmax[reg] = fmaxf(rmax[reg], __shfl_xor(rmax[reg], m));
        float alpha[4], rsum[4];
#pragma unroll
        for (int reg = 0; reg < 4; reg++) {
            float mn = fmaxf(m_i[reg], rmax[reg]);
            alpha[reg] = __expf(m_i[reg] - mn);
            m_i[reg] = mn;
            float s = 0.f;
#pragma unroll
            for (int nt = 0; nt < 4; nt++) {
                float p = __expf(pv[nt][reg] - mn);
                pv[nt][reg] = p;
                s += p;
            }
            rsum[reg] = s;
        }
#pragma unroll
        for (int m = 1; m < 16; m <<= 1)
#pragma unroll
            for (int reg = 0; reg < 4; reg++)
                rsum[reg] += __shfl_xor(rsum[reg], m);
#pragma unroll
        for (int reg = 0; reg < 4; reg++)
            l_i[reg] = l_i[reg] * alpha[reg] + rsum[reg];
#pragma unroll
        for (int nt = 0; nt < 4; nt++)
#pragma unroll
            for (int reg = 0; reg < 4; reg++)
                Ps[w * 1024 + (nt >> 1) * 512 + (fq * 4 + reg) * 32 + (nt & 1) * 16 + fm]
                    = f2b(pv[nt][reg]);
#pragma unroll
        for (int n2 = 0; n2 < 8; n2++)
#pragma unroll
            for (int reg = 0; reg < 4; reg++)
                accO[n2][reg] *= alpha[reg];
        short8 pf[2];
#pragma unroll
        for (int kc = 0; kc < 2; kc++)
            pf[kc] = *(const short8*)(Ps + w * 1024 + kc * 512 + fm * 32 + fq * 8);
#pragma unroll
        for (int n2 = 0; n2 < 8; n2++)
#pragma unroll
            for (int kc = 0; kc < 2; kc++) {
                short8 vf = *(const short8*)(Vs + kc * 4096 + (n2 * 16 + fm) * 32 + fq * 8);
                accO[n2] = __builtin_amdgcn_mfma_f32_16x16x32_bf16(pf[kc], vf, accO[n2], 0, 0, 0);
            }
        __syncthreads();
    }
#pragma unroll
    for (int reg = 0; reg < 4; reg++) {
        int row = q0 + w * 16 + fq * 4 + reg;
        float inv = 1.f / l_i[reg];
#pragma unroll
        for (int n2 = 0; n2 < 8; n2++)
            O[(size_t)row * 1024 + h * 128 + n2 * 16 + fm] = f2b(accO[n2][reg] * inv);
    }
}

// ---------------------------------------------------------------------------
// kr_fused: KR = rope(rmsnorm(X @ wkr^T + bkr, kr_norm)).  One block per token.
// wkr is 256 KB -> L2-resident.
// ---------------------------------------------------------------------------
__launch_bounds__(256)
__global__ void kr_fused(const float* __restrict__ X32, const float* __restrict__ wkr,
                         const float* __restrict__ bkr, const float* __restrict__ krw,
                         const float* __restrict__ fcos, const float* __restrict__ fsin,
                         float* __restrict__ KR)
{
    int s = blockIdx.x, tid = threadIdx.x;
    int n = tid >> 2, kq = tid & 3;
    const float* xr = X32 + (size_t)s * 1024 + kq * 256;
    const float* wr = wkr + (size_t)n * 1024 + kq * 256;
    float acc = 0.f;
#pragma unroll 8
    for (int k = 0; k < 256; k += 4) {
        float4 xv = *(const float4*)(xr + k);
        float4 wv = *(const float4*)(wr + k);
        acc += xv.x * wv.x + xv.y * wv.y + xv.z * wv.z + xv.w * wv.w;
    }
    acc += __shfl_xor(acc, 1);
    acc += __shfl_xor(acc, 2);
    __shared__ float kr[64];
    if (kq == 0) kr[n] = acc + bkr[n];
    __syncthreads();
    float ss = 0.f;
#pragma unroll
    for (int i = 0; i < 64; i++) { float v = kr[i]; ss += v * v; }
    float scale = rsqrtf(ss / 64.f + 1e-6f);
    if (tid < 32) {
        int j = tid;
        float c = fcos[s * 32 + j], sn = fsin[s * 32 + j];
        float x0 = kr[2 * j] * scale * krw[2 * j];
        float x1 = kr[2 * j + 1] * scale * krw[2 * j + 1];
        KR[(size_t)s * 64 + 2 * j]     = x0 * c - x1 * sn;
        KR[(size_t)s * 64 + 2 * j + 1] = x0 * sn + x1 * c;
    }
}

// ---------------------------------------------------------------------------
// RMSNorm: fp32 in -> fp32 + bf16 out
// ---------------------------------------------------------------------------
__launch_bounds__(256)
__global__ void rmsnorm_dual(const float* __restrict__ X, const float* __restrict__ w,
                             float* __restrict__ O32, u16* __restrict__ O16, int cols)
{
    int r = blockIdx.x, tid = threadIdx.x;
    const float* xr = X + (size_t)r * cols;
    float ss = 0.f;
    for (int j = tid; j < cols; j += 256) { float v = xr[j]; ss += v * v; }
    __shared__ float red[256];
    red[tid] = ss; __syncthreads();
    for (int st = 128; st > 0; st >>= 1) { if (tid < st) red[tid] += red[tid + st]; __syncthreads(); }
    float scale = rsqrtf(red[0] / cols + 1e-6f);
    for (int j = tid; j < cols; j += 256) {
        float v = xr[j] * scale * w[j];
        O32[(size_t)r * cols + j] = v;
        O16[(size_t)r * cols + j] = f2b(v);
    }
}

// two rmsnorms (bf16 out) in one launch: blocks [0,1024) -> (X0,c0), rest -> (X1,c1)
__launch_bounds__(256)
__global__ void rmsnorm2x(const float* __restrict__ X0, const float* __restrict__ w0,
                          u16* __restrict__ O0, int c0,
                          const float* __restrict__ X1, const float* __restrict__ w1,
                          u16* __restrict__ O1, int c1)
{
    int b = blockIdx.x, tid = threadIdx.x;
    const float* X; const float* w; u16* O; int cols; int r;
    if (b < 1024) { X = X0; w = w0; O = O0; cols = c0; r = b; }
    else          { X = X1; w = w1; O = O1; cols = c1; r = b - 1024; }
    const float* xr = X + (size_t)r * cols;
    float ss = 0.f;
    for (int j = tid; j < cols; j += 256) { float v = xr[j]; ss += v * v; }
    __shared__ float red[256];
    red[tid] = ss; __syncthreads();
    for (int st = 128; st > 0; st >>= 1) { if (tid < st) red[tid] += red[tid + st]; __syncthreads(); }
    float scale = rsqrtf(red[0] / cols + 1e-6f);
    for (int j = tid; j < cols; j += 256)
        O[(size_t)r * cols + j] = f2b(xr[j] * scale * w[j]);
}

// ---------------------------------------------------------------------------
// pack_all: blocks [0,1024) pack Q (with QR rope) and K; blocks [1024,1280)
// transpose V (bf16 [s][d] -> [d][s]).
// ---------------------------------------------------------------------------
__launch_bounds__(256)
__global__ void pack_all(const float* __restrict__ QC, const float* __restrict__ QRr,
                         const float* __restrict__ KR, const float* __restrict__ KC,
                         const u16* __restrict__ VCb,
                         const float* __restrict__ fcos, const float* __restrict__ fsin,
                         u16* __restrict__ Qp, u16* __restrict__ Kp, u16* __restrict__ VT)
{
    __shared__ u16 Ts[64][68];
    int b = blockIdx.x, tid = threadIdx.x;
    if (b < 1024) {
        int s = b;
        for (int e = tid; e < 1536; e += 256) {
            int h = e / 192, d = e % 192;
            float q;
            if (d < 128) {
                q = QC[(size_t)s * 1024 + h * 128 + d];
            } else {
                int dd = d - 128, j = dd >> 1;
                float c = fcos[s * 32 + j], sn = fsin[s * 32 + j];
                float x0 = QRr[(size_t)s * 512 + h * 64 + (dd & ~1)];
                float x1 = QRr[(size_t)s * 512 + h * 64 + (dd | 1)];
                q = (dd & 1) ? (x0 * sn + x1 * c) : (x0 * c - x1 * sn);
            }
            Qp[((size_t)h * 1024 + s) * 192 + d] = f2b(q);
            float k = (d < 64) ? KR[(size_t)s * 64 + d]
                               : KC[(size_t)s * 1024 + h * 128 + d - 64];
            Kp[((size_t)h * 1024 + s) * 192 + d] = f2b(k);
        }
    } else {
        int idx = b - 1024;
        int s0 = (idx & 15) * 64, d0 = (idx >> 4) * 64;
        for (int k = 0; k < 16; k++) {
            int e = tid + k * 256, r = e >> 6, c = e & 63;
            Ts[r][c] = VCb[(size_t)(s0 + r) * 1024 + d0 + c];
        }
        __syncthreads();
        for (int k = 0; k < 16; k++) {
            int e = tid + k * 256, d = e >> 6, s = e & 63;
            VT[(size_t)(d0 + d) * 1024 + s0 + s] = Ts[s][d];
        }
    }
}

// ---------------------------------------------------------------------------
// silu-mul: G = bf16(silu(U) * V)
// ---------------------------------------------------------------------------
__launch_bounds__(256)
__global__ void silu_mul(const u16* __restrict__ U, const u16* __restrict__ V,
                         u16* __restrict__ G, int n)
{
    int i = blockIdx.x * 256 + threadIdx.x;
    if (i < n) {
        float u = b2f(U[i]), v = b2f(V[i]);
        G[i] = f2b(u / (1.f + expf(-u)) * v);
    }
}

// ---------------------------------------------------------------------------
// Fused fp32->bf16 cast of all 13 weight arrays into the contiguous arena
// ---------------------------------------------------------------------------
__launch_bounds__(256)
__global__ void fused_cast(const float* p0, const float* p1, const float* p2,
                           const float* p3, const float* p4, const float* p5,
                           const float* p6, const float* p7, const float* p8,
                           const float* p9, const float* p10, const float* p11,
                           const float* p12, u16* __restrict__ dst)
{
    const int NQ = 17956864 / 4;
    for (int i = blockIdx.x * 256 + threadIdx.x; i < NQ; i += gridDim.x * 256) {
        int e = i * 4;
        const float* s; int base;
        if      (e <   786432) { s = p0;  base = 0; }
        else if (e <  1048576) { s = p1;  base =   786432; }
        else if (e <  1835008) { s = p2;  base =  1048576; }
        else if (e <  2228224) { s = p3;  base =  1835008; }
        else if (e <  2490368) { s = p4;  base =  2228224; }
        else if (e <  2752512) { s = p5;  base =  2490368; }
        else if (e <  3801088) { s = p6;  base =  2752512; }
        else if (e <  4325376) { s = p7;  base =  3801088; }
        else if (e <  4849664) { s = p8;  base =  4325376; }
        else if (e <  5373952) { s = p9;  base =  4849664; }
        else if (e <  9568256) { s = p10; base =  5373952; }
        else if (e < 13762560) { s = p11; base =  9568256; }
        else                   { s = p12; base = 13762560; }
        float4 v = *(const float4*)(s + (e - base));
        ushort4 o;
        o.x = f2b(v.x); o.y = f2b(v.y); o.z = f2b(v.z); o.w = f2b(v.w);
        *(ushort4*)(dst + e) = o;
    }
}

// ---------------------------------------------------------------------------
// Routing (fp32)
// ---------------------------------------------------------------------------
__launch_bounds__(256)
__global__ void route_kernel(const float* __restrict__ Y, const float* __restrict__ cent,
                             const float* __restrict__ biases,
                             int* __restrict__ counts, int* __restrict__ lists,
                             float* __restrict__ glist)
{
    int t = blockIdx.x, tid = threadIdx.x;
    float acc[8] = {};
    for (int j = tid; j < 1024; j += 256) {
        float yv = Y[(size_t)t * 1024 + j];
#pragma unroll
        for (int e = 0; e < 8; e++) acc[e] += yv * cent[e * 1024 + j];
    }
    __shared__ float red[256];
    __shared__ float aff[8];
    for (int e = 0; e < 8; e++) {
        red[tid] = acc[e]; __syncthreads();
        for (int st = 128; st > 0; st >>= 1) { if (tid < st) red[tid] += red[tid + st]; __syncthreads(); }
        if (tid == 0) aff[e] = 1.f / (1.f + expf(-red[0]));
        __syncthreads();
    }
    if (tid == 0) {
        float sb[8];
#pragma unroll
        for (int e = 0; e < 8; e++) sb[e] = aff[e] + biases[e];
        int i0 = 0;
        for (int e = 1; e < 8; e++) if (sb[e] > sb[i0]) i0 = e;
        int i1 = -1;
        for (int e = 0; e < 8; e++) { if (e == i0) continue; if (i1 < 0 || sb[e] > sb[i1]) i1 = e; }
        float a0 = aff[i0], a1 = aff[i1];
        float mx = fmaxf(a0, a1);
        float e0 = expf(a0 - mx), e1 = expf(a1 - mx);
        float inv = 1.f / (e0 + e1);
        int p0 = atomicAdd(&counts[i0], 1);
        lists[i0 * 1024 + p0] = t; glist[i0 * 1024 + p0] = e0 * inv;
        int p1 = atomicAdd(&counts[i1], 1);
        lists[i1 * 1024 + p1] = t; glist[i1 * 1024 + p1] = e1 * inv;
    }
}

// ---------------------------------------------------------------------------
extern "C" void kernel_launch(void* const* d_in, const int* in_sizes, int n_in,
                              void* d_out, int out_size, void* d_ws, size_t ws_size,
                              hipStream_t stream)
{
    (void)in_sizes; (void)n_in; (void)ws_size; (void)out_size;
    const float* h       = (const float*)d_in[0];
    const float* fcos    = (const float*)d_in[1];
    const float* fsin    = (const float*)d_in[2];
    const float* attn_w  = (const float*)d_in[4];
    const float* ffn_w   = (const float*)d_in[5];
    const float* wq_down = (const float*)d_in[6];
    const float* bq_down = (const float*)d_in[7];
    const float* q_norm  = (const float*)d_in[8];
    const float* wqc     = (const float*)d_in[9];
    const float* bqc     = (const float*)d_in[10];
    const float* wqr     = (const float*)d_in[11];
    const float* bqr     = (const float*)d_in[12];
    const float* wkr     = (const float*)d_in[13];
    const float* bkr     = (const float*)d_in[14];
    const float* kr_norm = (const float*)d_in[15];
    const float* wkv     = (const float*)d_in[16];
    const float* bkv     = (const float*)d_in[17];
    const float* kv_norm = (const float*)d_in[18];
    const float* wkc     = (const float*)d_in[19];
    const float* bkc     = (const float*)d_in[20];
    const float* wvc     = (const float*)d_in[21];
    const float* bvc     = (const float*)d_in[22];
    const float* wo      = (const float*)d_in[23];
    const float* bo      = (const float*)d_in[24];
    const float* sw1     = (const float*)d_in[25];
    const float* sb1     = (const float*)d_in[26];
    const float* sw2     = (const float*)d_in[27];
    const float* sb2     = (const float*)d_in[28];
    const float* sw3     = (const float*)d_in[29];
    const float* sb3     = (const float*)d_in[30];
    const float* ew1     = (const float*)d_in[31];
    const float* eb1     = (const float*)d_in[32];
    const float* ew2     = (const float*)d_in[33];
    const float* eb2     = (const float*)d_in[34];
    const float* ew3     = (const float*)d_in[35];
    const float* eb3     = (const float*)d_in[36];
    const float* cent    = (const float*)d_in[37];
    const float* biases  = (const float*)d_in[38];

    char* wsb = (char*)d_ws;
    const size_t U5 = 512 * 1024;  // 0.5 MB unit
    u16*   H1    = (u16*)(wsb + 0);            // 8 MB  (MoE phase; overlays X32)
    float* X32   = (float*)(wsb + 0);          // 4 MB  (early)
    u16*   X16   = (u16*)(wsb + 8 * U5);       // 2 MB
    float* QRr   = (float*)(wsb + 12 * U5);    // 2 MB  (raw QR, rope in pack)
    float* CQraw = (float*)(wsb + 16 * U5);    // 3 MB  (early)
    u16*   ATT16 = (u16*)(wsb + 16 * U5);      // 2 MB  (attn out, after CQraw dead)
    u16*   G16   = (u16*)(wsb + 20 * U5);      // 1 MB
    u16*   CQ16  = (u16*)(wsb + 22 * U5);      // 1.5 MB
    float* CKVraw= (float*)(wsb + 25 * U5);    // 1 MB
    u16*   CKV16 = (u16*)(wsb + 27 * U5);      // 0.5 MB
    float* KR    = (float*)(wsb + 28 * U5);    // 0.25 MB
    float* QC    = (float*)(wsb + 29 * U5);    // 4 MB  (dead after pack)
    float* KC    = (float*)(wsb + 37 * U5);    // 4 MB  (dead after pack)
    u16*   Vb    = (u16*)(wsb + 29 * U5);      // 8 MB  (GLU V; overlays QC+KC)
    float* X1    = (float*)(wsb + 53 * U5);    // 4 MB
    float* Y32   = (float*)(wsb + 61 * U5);    // 4 MB
    u16*   Y16   = (u16*)(wsb + 69 * U5);      // 2 MB
    u16*   Ub    = (u16*)(wsb + 73 * U5);      // 8 MB
    float* GL    = (float*)(wsb + 89 * U5);
    int*   lists = (int*)(wsb + 89 * U5 + 32 * 1024);
    int*   counts= (int*)(wsb + 89 * U5 + 64 * 1024);

    // bf16 weight arena (contiguous, order matches fused_cast)
    u16* wb = (u16*)(wsb + 90 * U5);
    u16 *c_wq  = wb;
    u16 *c_wkv = c_wq  + 786432;
    u16 *c_wqc = c_wkv + 262144;
    u16 *c_wqr = c_wqc + 786432;
    u16 *c_wkc = c_wqr + 393216;
    u16 *c_wvc = c_wkc + 262144;
    u16 *c_wo  = c_wvc + 262144;
    u16 *c_sw1 = c_wo  + 1048576;
    u16 *c_sw3 = c_sw1 + 524288;
    u16 *c_sw2 = c_sw3 + 524288;
    u16 *c_ew1 = c_sw2 + 524288;
    u16 *c_ew3 = c_ew1 + 4194304;
    u16 *c_ew2 = c_ew3 + 4194304;
    u16* VCb = (u16*)(wsb + 90 * U5 + 35913728);  // 2 MB  bf16 V [s][d]
    u16* VTp = VCb + 1048576;                     // 2 MB  bf16 V^T [d][s]
    u16* Qpk = VTp + 1048576;                     // 3 MB
    u16* Kpk = Qpk + 1572864;                     // 3 MB

    fused_cast<<<4096, 256, 0, stream>>>(wq_down, wkv, wqc, wqr, wkc, wvc, wo,
                                         sw1, sw3, sw2, ew1, ew3, ew2, wb);

    // --- attention branch ---
    rmsnorm_dual<<<1024, 256, 0, stream>>>(h, attn_w, X32, X16, 1024);
    kr_fused<<<1024, 256, 0, stream>>>(X32, wkr, bkr, kr_norm, fcos, fsin, KR);
    {
        GArgs g = {};
        g.A[0] = X16; g.lda[0] = 1024; g.K[0] = 1024;
        g.seg[0] = { c_wq,  bq_down, CQraw,  768, 0, 0, 0 };
        g.seg[1] = { c_wkv, bkv,     CKVraw, 256, 0, 6, 0 };
        g.nseg = 2; g.res = nullptr;
        mgemm4<<<dim3(8, 8), 256, 0, stream>>>(g);
    }
    rmsnorm2x<<<2048, 256, 0, stream>>>(CQraw, q_norm, CQ16, 768,
                                        CKVraw, kv_norm, CKV16, 256);
    {
        GArgs g = {};
        g.A[0] = CQ16;  g.lda[0] = 768; g.K[0] = 768;
        g.A[1] = CKV16; g.lda[1] = 256; g.K[1] = 256;
        g.seg[0] = { c_wqc, bqc, QC,   1024, 0, 0,  0 };
        g.seg[1] = { c_wqr, bqr, QRr,  512,  0, 8,  0 };
        g.seg[2] = { c_wkc, bkc, KC,   1024, 0, 12, 1 };
        g.seg[3] = { c_wvc, bvc, VCb,  1024, 3, 20, 1 };
        g.nseg = 4; g.res = nullptr;
        mgemm4<<<dim3(28, 8), 256, 0, stream>>>(g);
    }
    pack_all<<<1280, 256, 0, stream>>>(QC, QRr, KR, KC, VCb, fcos, fsin, Qpk, Kpk, VTp);
    attn_mfma<<<dim3(16, 8), 256, 0, stream>>>(Qpk, Kpk, VTp, ATT16);
    {
        GArgs g = {};
        g.A[0] = ATT16; g.lda[0] = 1024; g.K[0] = 1024;
        g.seg[0] = { c_wo, bo, X1, 1024, 1, 0, 0 };
        g.nseg = 1; g.res = h;
        mgemm4<<<dim3(8, 8), 256, 0, stream>>>(g);
    }

    // --- FFN branch + routing ---
    rmsnorm_dual<<<1024, 256, 0, stream>>>(X1, ffn_w, Y32, Y16, 1024);
    hipMemsetAsync(counts, 0, 32, stream);
    route_kernel<<<1024, 256, 0, stream>>>(Y32, cent, biases, counts, lists, GL);
    {
        GArgs g = {};
        g.A[0] = Y16; g.lda[0] = 1024; g.K[0] = 1024;
        g.seg[0] = { c_sw1, sb1, Ub, 512, 3, 0, 0 };
        g.seg[1] = { c_sw3, sb3, Vb, 512, 3, 4, 0 };
        g.nseg = 2; g.res = nullptr;
        mgemm4<<<dim3(8, 8), 256, 0, stream>>>(g);
    }
    silu_mul<<<2048, 256, 0, stream>>>(Ub, Vb, G16, 524288);
    {
        GArgs g = {};
        g.A[0] = G16; g.lda[0] = 512; g.K[0] = 512;
        g.seg[0] = { c_sw2, sb2, d_out, 1024, 1, 0, 0 };
        g.nseg = 1; g.res = X1;
        mgemm4<<<dim3(8, 8), 256, 0, stream>>>(g);
    }

    // --- MoE ---
    mgemm<3, 3, 1><<<dim3(8, 8, 8), 256, 0, stream>>>(Y16, 1024, 0, c_ew1, 1024, (size_t)512 * 1024, eb1, 512,
        Ub, 512, (size_t)1024 * 512, 1024, c_ew3, eb3, Vb, 512, 4, lists, nullptr, counts);
    silu_mul<<<16384, 256, 0, stream>>>(Ub, Vb, H1, 4194304);
    mgemm<2, 0, 0><<<dim3(8, 8, 8), 256, 0, stream>>>(H1, 512, (size_t)1024 * 512, c_ew2, 512, (size_t)1024 * 512, eb2, 1024,
        (float*)d_out, 1024, 0, 512, nullptr, nullptr, nullptr, 0, 8, lists, GL, counts);
}

// Round 8
// 523.132 us; speedup vs baseline: 3.4710x; 1.0945x over previous
//
#include <hip/hip_runtime.h>

typedef unsigned short u16;
typedef __attribute__((ext_vector_type(8))) short short8;   // 8 bf16 (4 VGPRs)
typedef __attribute__((ext_vector_type(4))) float f32x4;    // 4 fp32 acc

__device__ __forceinline__ float b2f(u16 u) { return __uint_as_float(((unsigned)u) << 16); }
__device__ __forceinline__ u16 f2b(float f) {
    unsigned x = __float_as_uint(f);
    return (u16)((x + 0x7fffu + ((x >> 16) & 1u)) >> 16);
}

// async global->LDS, 16B per lane; LDS dest = wave-uniform base + lane*16
#define GLDS16(gp, lp) __builtin_amdgcn_global_load_lds( \
    (const __attribute__((address_space(1))) void*)(gp), \
    (__attribute__((address_space(3))) void*)(lp), 16, 0, 0)

// ---------------------------------------------------------------------------
// Grouped MFMA GEMM: up to 4 column-segments, 2 A operands.
// C[M, seg] = A[aidx] @ W^T + bias, 128x128 tile, BK=32, 4 waves 2x2.
// epi: 0 fp32 out; 1 fp32 out += res; 3 bf16 out; 4 fp32 out col-guarded at ldc
//      (for N<128 padded segments; bias read also guarded).
// ---------------------------------------------------------------------------
struct Seg { const u16* W; const float* bias; void* C; int ldc; int epi; int bx0; int aidx; };
struct GArgs {
    const u16* A[2]; int lda[2]; int K[2];
    Seg seg[4]; int nseg;
    const float* res;
};

__launch_bounds__(256)
__global__ void mgemm4(GArgs ga)
{
    __shared__ u16 As[4096];   // [128][32] bf16
    __shared__ u16 Bs[4096];
    int bx = blockIdx.x, by = blockIdx.y;
    int si = 0;
#pragma unroll
    for (int i = 1; i < 4; i++)
        if (i < ga.nseg && bx >= ga.seg[i].bx0) si = i;
    const u16* Wp = ga.seg[si].W;
    const float* bp = ga.seg[si].bias;
    void* Cp = ga.seg[si].C;
    const int ldco = ga.seg[si].ldc;
    const int epi = ga.seg[si].epi;
    const int ai = ga.seg[si].aidx;
    const u16* Ap = ga.A[ai];
    const int lda = ga.lda[ai], K = ga.K[ai];
    const int col0 = (bx - ga.seg[si].bx0) * 128;
    const int row0 = by * 128;

    int tid = threadIdx.x;
    int lane = tid & 63, w = tid >> 6;
    int r0 = (w << 4) + (lane >> 2), kc8 = (lane & 3) << 3;
    const u16* ga0 = Ap + (size_t)(row0 + r0) * lda + kc8;
    const u16* ga1 = Ap + (size_t)(row0 + r0 + 64) * lda + kc8;
    const u16* gb0 = Wp + (size_t)(col0 + r0) * lda + kc8;        // ldw == lda (K-major)
    const u16* gb1 = Wp + (size_t)(col0 + r0 + 64) * lda + kc8;
    u16* lA = As + (w << 9);
    u16* lB = Bs + (w << 9);

    int wrow = (w >> 1) << 6, wcol = (w & 1) << 6;
    int fm = lane & 15, fq = lane >> 4;
    f32x4 acc[4][4] = {};

    for (int k0 = 0; k0 < K; k0 += 32) {
        GLDS16(ga0 + k0, lA);
        GLDS16(ga1 + k0, lA + 2048);
        GLDS16(gb0 + k0, lB);
        GLDS16(gb1 + k0, lB + 2048);
        __syncthreads();
        short8 af[4], bf[4];
#pragma unroll
        for (int t = 0; t < 4; t++) {
            af[t] = *(const short8*)(As + (wrow + (t << 4) + fm) * 32 + fq * 8);
            bf[t] = *(const short8*)(Bs + (wcol + (t << 4) + fm) * 32 + fq * 8);
        }
#pragma unroll
        for (int mt = 0; mt < 4; mt++)
#pragma unroll
            for (int nt = 0; nt < 4; nt++)
                acc[mt][nt] = __builtin_amdgcn_mfma_f32_16x16x32_bf16(af[mt], bf[nt], acc[mt][nt], 0, 0, 0);
        __syncthreads();
    }

    // C/D layout: col = lane&15, row = (lane>>4)*4 + reg   [m89/m91]
#pragma unroll
    for (int mt = 0; mt < 4; mt++) {
        int rbase = row0 + wrow + (mt << 4) + (fq << 2);
#pragma unroll
        for (int nt = 0; nt < 4; nt++) {
            int c = col0 + wcol + (nt << 4) + fm;
            float bcol = (epi == 4 && c >= ldco) ? 0.f : bp[c];
#pragma unroll
            for (int reg = 0; reg < 4; reg++) {
                int r = rbase + reg;
                float v = acc[mt][nt][reg] + bcol;
                if (epi == 3)
                    ((u16*)Cp)[(size_t)r * ldco + c] = f2b(v);
                else if (epi == 1)
                    ((float*)Cp)[(size_t)r * ldco + c] = v + ga.res[(size_t)r * ldco + c];
                else if (epi == 4) {
                    if (c < ldco) ((float*)Cp)[(size_t)r * ldco + c] = v;
                } else
                    ((float*)Cp)[(size_t)r * ldco + c] = v;
            }
        }
    }
}

// ---------------------------------------------------------------------------
// MoE MFMA GEMM (per-expert z-dim, gather / atomic-scatter).
// EPI: 2 atomicAdd(gate*(acc+bias)); 3 bf16 out. GATHER: A row via lists.
// ---------------------------------------------------------------------------
template<int EPI, int EPI2, int GATHER>
__launch_bounds__(256)
__global__ void mgemm(const u16* __restrict__ A, int lda, size_t astride,
                      const u16* __restrict__ W, int ldw, size_t wstride,
                      const float* __restrict__ bias, int bstride,
                      void* __restrict__ Cv, int ldc, size_t cstride,
                      int K,
                      const u16* __restrict__ W2, const float* __restrict__ bias2,
                      void* __restrict__ C2v, int ldc2, int nsplit,
                      const int* __restrict__ lists, const float* __restrict__ glist,
                      const int* __restrict__ counts)
{
    __shared__ u16 As[4096];
    __shared__ u16 Bs[4096];
    int bx = blockIdx.x, by = blockIdx.y, e = blockIdx.z;
    int cnt = counts[e];
    const int* list = lists + (e << 10);
    const float* gl = (EPI == 2) ? glist + (e << 10) : nullptr;
    int row0 = by * 128;
    if (row0 >= cnt) return;
    bool is2 = false;
    const u16* Wp = W; const float* bp = bias; void* Cp = Cv; int ldco = ldc;
    if (W2 && bx >= nsplit) { is2 = true; Wp = W2; bp = bias2; Cp = C2v; ldco = ldc2; bx -= nsplit; }
    Wp += (size_t)e * wstride;
    bp += (size_t)e * bstride;
    const u16* Ap = A + (size_t)e * astride;
    int col0 = bx * 128;

    int tid = threadIdx.x;
    int lane = tid & 63, w = tid >> 6;
    int r0 = (w << 4) + (lane >> 2), kc8 = (lane & 3) << 3;
    int ar0g = row0 + r0, ar1g = row0 + r0 + 64;
    if (GATHER) {
        int i0 = ar0g < cnt ? ar0g : cnt - 1;
        int i1 = ar1g < cnt ? ar1g : cnt - 1;
        ar0g = list[i0]; ar1g = list[i1];
    }
    const u16* ga0 = Ap + (size_t)ar0g * lda + kc8;
    const u16* ga1 = Ap + (size_t)ar1g * lda + kc8;
    const u16* gb0 = Wp + (size_t)(col0 + r0) * ldw + kc8;
    const u16* gb1 = Wp + (size_t)(col0 + r0 + 64) * ldw + kc8;
    u16* lA = As + (w << 9);
    u16* lB = Bs + (w << 9);

    int wrow = (w >> 1) << 6, wcol = (w & 1) << 6;
    int fm = lane & 15, fq = lane >> 4;
    f32x4 acc[4][4] = {};

    for (int k0 = 0; k0 < K; k0 += 32) {
        GLDS16(ga0 + k0, lA);
        GLDS16(ga1 + k0, lA + 2048);
        GLDS16(gb0 + k0, lB);
        GLDS16(gb1 + k0, lB + 2048);
        __syncthreads();
        short8 af[4], bf[4];
#pragma unroll
        for (int t = 0; t < 4; t++) {
            af[t] = *(const short8*)(As + (wrow + (t << 4) + fm) * 32 + fq * 8);
            bf[t] = *(const short8*)(Bs + (wcol + (t << 4) + fm) * 32 + fq * 8);
        }
#pragma unroll
        for (int mt = 0; mt < 4; mt++)
#pragma unroll
            for (int nt = 0; nt < 4; nt++)
                acc[mt][nt] = __builtin_amdgcn_mfma_f32_16x16x32_bf16(af[mt], bf[nt], acc[mt][nt], 0, 0, 0);
        __syncthreads();
    }

    const int epi = is2 ? EPI2 : EPI;
#pragma unroll
    for (int mt = 0; mt < 4; mt++) {
        int rbase = row0 + wrow + (mt << 4) + (fq << 2);
#pragma unroll
        for (int nt = 0; nt < 4; nt++) {
            int c = col0 + wcol + (nt << 4) + fm;
            float bcol = bp[c];
#pragma unroll
            for (int reg = 0; reg < 4; reg++) {
                int r = rbase + reg;
                if (r >= cnt) continue;
                float v = acc[mt][nt][reg] + bcol;
                if (epi == 3)
                    ((u16*)Cp)[(size_t)e * cstride + (size_t)r * ldco + c] = f2b(v);
                else
                    atomicAdd(&((float*)Cp)[(size_t)list[r] * ldco + c], gl[r] * v);
            }
        }
    }
}

// ---------------------------------------------------------------------------
// MFMA flash attention. Qp[h][s][192]=[qC|qR], Kp=[kR|kC], VT[d][kv].
// ---------------------------------------------------------------------------
__launch_bounds__(256)
__global__ void attn_mfma(const u16* __restrict__ Qp, const u16* __restrict__ Kp,
                          const u16* __restrict__ VT, u16* __restrict__ O)
{
    const int qt = blockIdx.x, h = blockIdx.y;
    const int q0 = qt * 64;
    const int tid = threadIdx.x;
    const int lane = tid & 63, w = tid >> 6;
    const int fm = lane & 15, fq = lane >> 4;

    __shared__ u16 Ks[6 * 2048];
    __shared__ u16 Vs[2 * 4096];
    __shared__ u16 Ps[4 * 1024];

    const u16* qrow = Qp + ((size_t)h * 1024 + q0 + w * 16 + fm) * 192;
    short8 qf[6];
#pragma unroll
    for (int c = 0; c < 6; c++)
        qf[c] = *(const short8*)(qrow + c * 32 + fq * 8);

    const u16* Kb = Kp + (size_t)h * 1024 * 192;
    const u16* Vb = VT + (size_t)h * 128 * 1024;

    float m_i[4], l_i[4];
#pragma unroll
    for (int r = 0; r < 4; r++) { m_i[r] = -1e30f; l_i[r] = 0.f; }
    f32x4 accO[8] = {};
    const float scale = 0.07216878364870323f;  // 1/sqrt(192)

    for (int kt = 0; kt <= qt; ++kt) {
        const int kt0 = kt * 64;
#pragma unroll
        for (int i = 0; i < 6; i++) {
            int idx = w + 4 * i;
            int c = idx >> 2, k4 = idx & 3;
            const u16* g = Kb + (size_t)(kt0 + k4 * 16 + (lane >> 2)) * 192 + c * 32 + (lane & 3) * 8;
            GLDS16(g, Ks + c * 2048 + k4 * 512 + lane * 8);
        }
#pragma unroll
        for (int i = 0; i < 4; i++) {
            int idx = w + 4 * i;
            int kc = idx >> 3, k8 = idx & 7;
            const u16* g = Vb + (size_t)(k8 * 16 + (lane >> 2)) * 1024 + kt0 + kc * 32 + (lane & 3) * 8;
            GLDS16(g, Vs + kc * 4096 + k8 * 512 + lane * 8);
        }
        __syncthreads();
        f32x4 sacc[4] = {};
#pragma unroll
        for (int nt = 0; nt < 4; nt++)
#pragma unroll
            for (int c = 0; c < 6; c++) {
                short8 kf = *(const short8*)(Ks + c * 2048 + (nt * 16 + fm) * 32 + fq * 8);
                sacc[nt] = __builtin_amdgcn_mfma_f32_16x16x32_bf16(qf[c], kf, sacc[nt], 0, 0, 0);
            }
        const bool diag = (kt == qt);
        const int rbase = w * 16 + fq * 4;
        float pv[4][4], rmax[4];
#pragma unroll
        for (int reg = 0; reg < 4; reg++) {
            float mx = -1e30f;
#pragma unroll
            for (int nt = 0; nt < 4; nt++) {
                float s = sacc[nt][reg] * scale;
                if (diag && (nt * 16 + fm) > (rbase + reg)) s = -1e30f;
                pv[nt][reg] = s;
                mx = fmaxf(mx, s);
            }
            rmax[reg] = mx;
        }
#pragma unroll
        for (int m = 1; m < 16; m <<= 1)
#pragma unroll
            for (int reg = 0; reg < 4; reg++)
                rmax[reg] = fmaxf(rmax[reg], __shfl_xor(rmax[reg], m));
        float alpha[4], rsum[4];
#pragma unroll
        for (int reg = 0; reg < 4; reg++) {
            float mn = fmaxf(m_i[reg], rmax[reg]);
            alpha[reg] = __expf(m_i[reg] - mn);
            m_i[reg] = mn;
            float s = 0.f;
#pragma unroll
            for (int nt = 0; nt < 4; nt++) {
                float p = __expf(pv[nt][reg] - mn);
                pv[nt][reg] = p;
                s += p;
            }
            rsum[reg] = s;
        }
#pragma unroll
        for (int m = 1; m < 16; m <<= 1)
#pragma unroll
            for (int reg = 0; reg < 4; reg++)
                rsum[reg] += __shfl_xor(rsum[reg], m);
#pragma unroll
        for (int reg = 0; reg < 4; reg++)
            l_i[reg] = l_i[reg] * alpha[reg] + rsum[reg];
#pragma unroll
        for (int nt = 0; nt < 4; nt++)
#pragma unroll
            for (int reg = 0; reg < 4; reg++)
                Ps[w * 1024 + (nt >> 1) * 512 + (fq * 4 + reg) * 32 + (nt & 1) * 16 + fm]
                    = f2b(pv[nt][reg]);
#pragma unroll
        for (int n2 = 0; n2 < 8; n2++)
#pragma unroll
            for (int reg = 0; reg < 4; reg++)
                accO[n2][reg] *= alpha[reg];
        short8 pf[2];
#pragma unroll
        for (int kc = 0; kc < 2; kc++)
            pf[kc] = *(const short8*)(Ps + w * 1024 + kc * 512 + fm * 32 + fq * 8);
#pragma unroll
        for (int n2 = 0; n2 < 8; n2++)
#pragma unroll
            for (int kc = 0; kc < 2; kc++) {
                short8 vf = *(const short8*)(Vs + kc * 4096 + (n2 * 16 + fm) * 32 + fq * 8);
                accO[n2] = __builtin_amdgcn_mfma_f32_16x16x32_bf16(pf[kc], vf, accO[n2], 0, 0, 0);
            }
        __syncthreads();
    }
#pragma unroll
    for (int reg = 0; reg < 4; reg++) {
        int row = q0 + w * 16 + fq * 4 + reg;
        float inv = 1.f / l_i[reg];
#pragma unroll
        for (int n2 = 0; n2 < 8; n2++)
            O[(size_t)row * 1024 + h * 128 + n2 * 16 + fm] = f2b(accO[n2][reg] * inv);
    }
}

// ---------------------------------------------------------------------------
// RMSNorm: fp32 in -> fp32 + bf16 out
// ---------------------------------------------------------------------------
__launch_bounds__(256)
__global__ void rmsnorm_dual(const float* __restrict__ X, const float* __restrict__ w,
                             float* __restrict__ O32, u16* __restrict__ O16, int cols)
{
    int r = blockIdx.x, tid = threadIdx.x;
    const float* xr = X + (size_t)r * cols;
    float ss = 0.f;
    for (int j = tid; j < cols; j += 256) { float v = xr[j]; ss += v * v; }
    __shared__ float red[256];
    red[tid] = ss; __syncthreads();
    for (int st = 128; st > 0; st >>= 1) { if (tid < st) red[tid] += red[tid + st]; __syncthreads(); }
    float scale = rsqrtf(red[0] / cols + 1e-6f);
    for (int j = tid; j < cols; j += 256) {
        float v = xr[j] * scale * w[j];
        O32[(size_t)r * cols + j] = v;
        O16[(size_t)r * cols + j] = f2b(v);
    }
}

// two rmsnorms (bf16 out) in one launch: blocks [0,1024) -> (X0,c0), rest -> (X1,c1)
__launch_bounds__(256)
__global__ void rmsnorm2x(const float* __restrict__ X0, const float* __restrict__ w0,
                          u16* __restrict__ O0, int c0,
                          const float* __restrict__ X1, const float* __restrict__ w1,
                          u16* __restrict__ O1, int c1)
{
    int b = blockIdx.x, tid = threadIdx.x;
    const float* X; const float* w; u16* O; int cols; int r;
    if (b < 1024) { X = X0; w = w0; O = O0; cols = c0; r = b; }
    else          { X = X1; w = w1; O = O1; cols = c1; r = b - 1024; }
    const float* xr = X + (size_t)r * cols;
    float ss = 0.f;
    for (int j = tid; j < cols; j += 256) { float v = xr[j]; ss += v * v; }
    __shared__ float red[256];
    red[tid] = ss; __syncthreads();
    for (int st = 128; st > 0; st >>= 1) { if (tid < st) red[tid] += red[tid + st]; __syncthreads(); }
    float scale = rsqrtf(red[0] / cols + 1e-6f);
    for (int j = tid; j < cols; j += 256)
        O[(size_t)r * cols + j] = f2b(xr[j] * scale * w[j]);
}

// ---------------------------------------------------------------------------
// pack_all: blocks [0,1024): per-token s — compute KR rmsnorm+rope from KRraw
// (in-block), pack Q (with QR rope) and K into [h][s][192].
// Blocks [1024,1280): transpose V (bf16 [s][d] -> [d][s]).
// ---------------------------------------------------------------------------
__launch_bounds__(256)
__global__ void pack_all(const float* __restrict__ QC, const float* __restrict__ QRr,
                         const float* __restrict__ KRraw, const float* __restrict__ krw,
                         const float* __restrict__ KC,
                         const u16* __restrict__ VCb,
                         const float* __restrict__ fcos, const float* __restrict__ fsin,
                         u16* __restrict__ Qp, u16* __restrict__ Kp, u16* __restrict__ VT)
{
    __shared__ u16 Ts[64][68];
    __shared__ float kshared[64];
    int b = blockIdx.x, tid = threadIdx.x;
    if (b < 1024) {
        int s = b;
        if (tid < 64) {
            float v = KRraw[(size_t)s * 64 + tid];
            float ss = v * v;
#pragma unroll
            for (int m = 1; m < 64; m <<= 1) ss += __shfl_xor(ss, m);
            float scale = rsqrtf(ss / 64.f + 1e-6f);
            int j = tid >> 1;
            float c = fcos[s * 32 + j], sn = fsin[s * 32 + j];
            float x0 = KRraw[(size_t)s * 64 + (tid & ~1)] * scale * krw[tid & ~1];
            float x1 = KRraw[(size_t)s * 64 + (tid | 1)]  * scale * krw[tid | 1];
            kshared[tid] = (tid & 1) ? (x0 * sn + x1 * c) : (x0 * c - x1 * sn);
        }
        __syncthreads();
        for (int e = tid; e < 1536; e += 256) {
            int h = e / 192, d = e % 192;
            float q;
            if (d < 128) {
                q = QC[(size_t)s * 1024 + h * 128 + d];
            } else {
                int dd = d - 128, j = dd >> 1;
                float c = fcos[s * 32 + j], sn = fsin[s * 32 + j];
                float x0 = QRr[(size_t)s * 512 + h * 64 + (dd & ~1)];
                float x1 = QRr[(size_t)s * 512 + h * 64 + (dd | 1)];
                q = (dd & 1) ? (x0 * sn + x1 * c) : (x0 * c - x1 * sn);
            }
            Qp[((size_t)h * 1024 + s) * 192 + d] = f2b(q);
            float k = (d < 64) ? kshared[d]
                               : KC[(size_t)s * 1024 + h * 128 + d - 64];
            Kp[((size_t)h * 1024 + s) * 192 + d] = f2b(k);
        }
    } else {
        int idx = b - 1024;
        int s0 = (idx & 15) * 64, d0 = (idx >> 4) * 64;
        for (int k = 0; k < 16; k++) {
            int e = tid + k * 256, r = e >> 6, c = e & 63;
            Ts[r][c] = VCb[(size_t)(s0 + r) * 1024 + d0 + c];
        }
        __syncthreads();
        for (int k = 0; k < 16; k++) {
            int e = tid + k * 256, d = e >> 6, s = e & 63;
            VT[(size_t)(d0 + d) * 1024 + s0 + s] = Ts[s][d];
        }
    }
}

// ---------------------------------------------------------------------------
// silu-mul: G = bf16(silu(U) * V)
// ---------------------------------------------------------------------------
__launch_bounds__(256)
__global__ void silu_mul(const u16* __restrict__ U, const u16* __restrict__ V,
                         u16* __restrict__ G, int n)
{
    int i = blockIdx.x * 256 + threadIdx.x;
    if (i < n) {
        float u = b2f(U[i]), v = b2f(V[i]);
        G[i] = f2b(u / (1.f + expf(-u)) * v);
    }
}

// ---------------------------------------------------------------------------
// Fused fp32->bf16 cast of 14 weight arrays (wkr padded to 128 rows with
// zeros) + the X rmsnorm (blocks >= NCAST).
// ---------------------------------------------------------------------------
#define NCAST 4096
__launch_bounds__(256)
__global__ void fused_cast(const float* p0, const float* p1, const float* p2,
                           const float* p3, const float* p4, const float* p5,
                           const float* p6, const float* p7, const float* p8,
                           const float* p9, const float* p10, const float* p11,
                           const float* p12, const float* pkr,
                           u16* __restrict__ dst,
                           const float* __restrict__ hX, const float* __restrict__ attnw,
                           u16* __restrict__ X16)
{
    __shared__ float red[256];
    int b = blockIdx.x, tid = threadIdx.x;
    if (b < NCAST) {
        const int NQ = 18087936 / 4;   // 17956864 cast + 65536 wkr + 65536 zero-pad
        for (int i = b * 256 + tid; i < NQ; i += NCAST * 256) {
            int e = i * 4;
            ushort4 o;
            if (e >= 18022400) {
                o.x = o.y = o.z = o.w = 0;
            } else {
                const float* s; int base;
                if      (e <   786432) { s = p0;  base = 0; }
                else if (e <  1048576) { s = p1;  base =   786432; }
                else if (e <  1835008) { s = p2;  base =  1048576; }
                else if (e <  2228224) { s = p3;  base =  1835008; }
                else if (e <  2490368) { s = p4;  base =  2228224; }
                else if (e <  2752512) { s = p5;  base =  2490368; }
                else if (e <  3801088) { s = p6;  base =  2752512; }
                else if (e <  4325376) { s = p7;  base =  3801088; }
                else if (e <  4849664) { s = p8;  base =  4325376; }
                else if (e <  5373952) { s = p9;  base =  4849664; }
                else if (e <  9568256) { s = p10; base =  5373952; }
                else if (e < 13762560) { s = p11; base =  9568256; }
                else if (e < 17956864) { s = p12; base = 13762560; }
                else                   { s = pkr; base = 17956864; }
                float4 v = *(const float4*)(s + (e - base));
                o.x = f2b(v.x); o.y = f2b(v.y); o.z = f2b(v.z); o.w = f2b(v.w);
            }
            *(ushort4*)(dst + e) = o;
        }
    } else {
        int r = b - NCAST;
        const float* xr = hX + (size_t)r * 1024;
        float ss = 0.f;
        for (int j = tid; j < 1024; j += 256) { float v = xr[j]; ss += v * v; }
        red[tid] = ss; __syncthreads();
        for (int st = 128; st > 0; st >>= 1) { if (tid < st) red[tid] += red[tid + st]; __syncthreads(); }
        float scale = rsqrtf(red[0] / 1024.f + 1e-6f);
        for (int j = tid; j < 1024; j += 256)
            X16[(size_t)r * 1024 + j] = f2b(xr[j] * scale * attnw[j]);
    }
}

// ---------------------------------------------------------------------------
// Routing (fp32)
// ---------------------------------------------------------------------------
__launch_bounds__(256)
__global__ void route_kernel(const float* __restrict__ Y, const float* __restrict__ cent,
                             const float* __restrict__ biases,
                             int* __restrict__ counts, int* __restrict__ lists,
                             float* __restrict__ glist)
{
    int t = blockIdx.x, tid = threadIdx.x;
    float acc[8] = {};
    for (int j = tid; j < 1024; j += 256) {
        float yv = Y[(size_t)t * 1024 + j];
#pragma unroll
        for (int e = 0; e < 8; e++) acc[e] += yv * cent[e * 1024 + j];
    }
    __shared__ float red[256];
    __shared__ float aff[8];
    for (int e = 0; e < 8; e++) {
        red[tid] = acc[e]; __syncthreads();
        for (int st = 128; st > 0; st >>= 1) { if (tid < st) red[tid] += red[tid + st]; __syncthreads(); }
        if (tid == 0) aff[e] = 1.f / (1.f + expf(-red[0]));
        __syncthreads();
    }
    if (tid == 0) {
        float sb[8];
#pragma unroll
        for (int e = 0; e < 8; e++) sb[e] = aff[e] + biases[e];
        int i0 = 0;
        for (int e = 1; e < 8; e++) if (sb[e] > sb[i0]) i0 = e;
        int i1 = -1;
        for (int e = 0; e < 8; e++) { if (e == i0) continue; if (i1 < 0 || sb[e] > sb[i1]) i1 = e; }
        float a0 = aff[i0], a1 = aff[i1];
        float mx = fmaxf(a0, a1);
        float e0 = expf(a0 - mx), e1 = expf(a1 - mx);
        float inv = 1.f / (e0 + e1);
        int p0 = atomicAdd(&counts[i0], 1);
        lists[i0 * 1024 + p0] = t; glist[i0 * 1024 + p0] = e0 * inv;
        int p1 = atomicAdd(&counts[i1], 1);
        lists[i1 * 1024 + p1] = t; glist[i1 * 1024 + p1] = e1 * inv;
    }
}

// ---------------------------------------------------------------------------
extern "C" void kernel_launch(void* const* d_in, const int* in_sizes, int n_in,
                              void* d_out, int out_size, void* d_ws, size_t ws_size,
                              hipStream_t stream)
{
    (void)in_sizes; (void)n_in; (void)ws_size; (void)out_size;
    const float* h       = (const float*)d_in[0];
    const float* fcos    = (const float*)d_in[1];
    const float* fsin    = (const float*)d_in[2];
    const float* attn_w  = (const float*)d_in[4];
    const float* ffn_w   = (const float*)d_in[5];
    const float* wq_down = (const float*)d_in[6];
    const float* bq_down = (const float*)d_in[7];
    const float* q_norm  = (const float*)d_in[8];
    const float* wqc     = (const float*)d_in[9];
    const float* bqc     = (const float*)d_in[10];
    const float* wqr     = (const float*)d_in[11];
    const float* bqr     = (const float*)d_in[12];
    const float* wkr     = (const float*)d_in[13];
    const float* bkr     = (const float*)d_in[14];
    const float* kr_norm = (const float*)d_in[15];
    const float* wkv     = (const float*)d_in[16];
    const float* bkv     = (const float*)d_in[17];
    const float* kv_norm = (const float*)d_in[18];
    const float* wkc     = (const float*)d_in[19];
    const float* bkc     = (const float*)d_in[20];
    const float* wvc     = (const float*)d_in[21];
    const float* bvc     = (const float*)d_in[22];
    const float* wo      = (const float*)d_in[23];
    const float* bo      = (const float*)d_in[24];
    const float* sw1     = (const float*)d_in[25];
    const float* sb1     = (const float*)d_in[26];
    const float* sw2     = (const float*)d_in[27];
    const float* sb2     = (const float*)d_in[28];
    const float* sw3     = (const float*)d_in[29];
    const float* sb3     = (const float*)d_in[30];
    const float* ew1     = (const float*)d_in[31];
    const float* eb1     = (const float*)d_in[32];
    const float* ew2     = (const float*)d_in[33];
    const float* eb2     = (const float*)d_in[34];
    const float* ew3     = (const float*)d_in[35];
    const float* eb3     = (const float*)d_in[36];
    const float* cent    = (const float*)d_in[37];
    const float* biases  = (const float*)d_in[38];

    char* wsb = (char*)d_ws;
    const size_t U5 = 512 * 1024;  // 0.5 MB unit
    u16*   H1    = (u16*)(wsb + 0);            // 8 MB  (MoE phase)
    u16*   X16   = (u16*)(wsb + 8 * U5);       // 2 MB
    float* QRr   = (float*)(wsb + 12 * U5);    // 2 MB  (raw QR, rope in pack)
    float* CQraw = (float*)(wsb + 16 * U5);    // 3 MB  (early)
    u16*   ATT16 = (u16*)(wsb + 16 * U5);      // 2 MB  (attn out, after CQraw dead)
    u16*   G16   = (u16*)(wsb + 20 * U5);      // 1 MB
    u16*   CQ16  = (u16*)(wsb + 22 * U5);      // 1.5 MB
    float* CKVraw= (float*)(wsb + 25 * U5);    // 1 MB
    u16*   CKV16 = (u16*)(wsb + 27 * U5);      // 0.5 MB
    float* KRraw = (float*)(wsb + 28 * U5);    // 0.25 MB (pre-norm KR)
    float* QC    = (float*)(wsb + 29 * U5);    // 4 MB  (dead after pack)
    float* KC    = (float*)(wsb + 37 * U5);    // 4 MB  (dead after pack)
    u16*   Vb    = (u16*)(wsb + 29 * U5);      // 8 MB  (GLU V; overlays QC+KC)
    float* X1    = (float*)(wsb + 53 * U5);    // 4 MB
    float* Y32   = (float*)(wsb + 61 * U5);    // 4 MB
    u16*   Y16   = (u16*)(wsb + 69 * U5);      // 2 MB
    u16*   Ub    = (u16*)(wsb + 73 * U5);      // 8 MB
    float* GL    = (float*)(wsb + 89 * U5);
    int*   lists = (int*)(wsb + 89 * U5 + 32 * 1024);
    int*   counts= (int*)(wsb + 89 * U5 + 64 * 1024);

    // bf16 weight arena (contiguous, order matches fused_cast; wkr padded)
    u16* wb = (u16*)(wsb + 90 * U5);
    u16 *c_wq  = wb;
    u16 *c_wkv = c_wq  + 786432;
    u16 *c_wqc = c_wkv + 262144;
    u16 *c_wqr = c_wqc + 786432;
    u16 *c_wkc = c_wqr + 393216;
    u16 *c_wvc = c_wkc + 262144;
    u16 *c_wo  = c_wvc + 262144;
    u16 *c_sw1 = c_wo  + 1048576;
    u16 *c_sw3 = c_sw1 + 524288;
    u16 *c_sw2 = c_sw3 + 524288;
    u16 *c_ew1 = c_sw2 + 524288;
    u16 *c_ew3 = c_ew1 + 4194304;
    u16 *c_ew2 = c_ew3 + 4194304;
    u16 *c_wkr = c_ew2 + 4194304;                 // 128x1024 (64 real + 64 zero)
    u16* VCb = (u16*)(wsb + 90 * U5 + 36175872);  // 2 MB  bf16 V [s][d]
    u16* VTp = VCb + 1048576;                     // 2 MB  bf16 V^T [d][s]
    u16* Qpk = VTp + 1048576;                     // 3 MB
    u16* Kpk = Qpk + 1572864;                     // 3 MB

    // weight cast + wkr pad + X rmsnorm, one launch
    fused_cast<<<NCAST + 1024, 256, 0, stream>>>(wq_down, wkv, wqc, wqr, wkc, wvc, wo,
                                                 sw1, sw3, sw2, ew1, ew3, ew2, wkr, wb,
                                                 h, attn_w, X16);

    // --- attention branch ---
    {
        GArgs g = {};
        g.A[0] = X16; g.lda[0] = 1024; g.K[0] = 1024;
        g.seg[0] = { c_wq,  bq_down, CQraw,  768, 0, 0, 0 };
        g.seg[1] = { c_wkv, bkv,     CKVraw, 256, 0, 6, 0 };
        g.seg[2] = { c_wkr, bkr,     KRraw,  64,  4, 8, 0 };
        g.nseg = 3; g.res = nullptr;
        mgemm4<<<dim3(9, 8), 256, 0, stream>>>(g);
    }
    rmsnorm2x<<<2048, 256, 0, stream>>>(CQraw, q_norm, CQ16, 768,
                                        CKVraw, kv_norm, CKV16, 256);
    {
        GArgs g = {};
        g.A[0] = CQ16;  g.lda[0] = 768; g.K[0] = 768;
        g.A[1] = CKV16; g.lda[1] = 256; g.K[1] = 256;
        g.seg[0] = { c_wqc, bqc, QC,   1024, 0, 0,  0 };
        g.seg[1] = { c_wqr, bqr, QRr,  512,  0, 8,  0 };
        g.seg[2] = { c_wkc, bkc, KC,   1024, 0, 12, 1 };
        g.seg[3] = { c_wvc, bvc, VCb,  1024, 3, 20, 1 };
        g.nseg = 4; g.res = nullptr;
        mgemm4<<<dim3(28, 8), 256, 0, stream>>>(g);
    }
    pack_all<<<1280, 256, 0, stream>>>(QC, QRr, KRraw, kr_norm, KC, VCb, fcos, fsin,
                                       Qpk, Kpk, VTp);
    attn_mfma<<<dim3(16, 8), 256, 0, stream>>>(Qpk, Kpk, VTp, ATT16);
    {
        GArgs g = {};
        g.A[0] = ATT16; g.lda[0] = 1024; g.K[0] = 1024;
        g.seg[0] = { c_wo, bo, X1, 1024, 1, 0, 0 };
        g.nseg = 1; g.res = h;
        mgemm4<<<dim3(8, 8), 256, 0, stream>>>(g);
    }

    // --- FFN branch + routing ---
    rmsnorm_dual<<<1024, 256, 0, stream>>>(X1, ffn_w, Y32, Y16, 1024);
    hipMemsetAsync(counts, 0, 32, stream);
    route_kernel<<<1024, 256, 0, stream>>>(Y32, cent, biases, counts, lists, GL);
    {
        GArgs g = {};
        g.A[0] = Y16; g.lda[0] = 1024; g.K[0] = 1024;
        g.seg[0] = { c_sw1, sb1, Ub, 512, 3, 0, 0 };
        g.seg[1] = { c_sw3, sb3, Vb, 512, 3, 4, 0 };
        g.nseg = 2; g.res = nullptr;
        mgemm4<<<dim3(8, 8), 256, 0, stream>>>(g);
    }
    silu_mul<<<2048, 256, 0, stream>>>(Ub, Vb, G16, 524288);
    {
        GArgs g = {};
        g.A[0] = G16; g.lda[0] = 512; g.K[0] = 512;
        g.seg[0] = { c_sw2, sb2, d_out, 1024, 1, 0, 0 };
        g.nseg = 1; g.res = X1;
        mgemm4<<<dim3(8, 8), 256, 0, stream>>>(g);
    }

    // --- MoE ---
    mgemm<3, 3, 1><<<dim3(8, 8, 8), 256, 0, stream>>>(Y16, 1024, 0, c_ew1, 1024, (size_t)512 * 1024, eb1, 512,
        Ub, 512, (size_t)1024 * 512, 1024, c_ew3, eb3, Vb, 512, 4, lists, nullptr, counts);
    silu_mul<<<16384, 256, 0, stream>>>(Ub, Vb, H1, 4194304);
    mgemm<2, 0, 0><<<dim3(8, 8, 8), 256, 0, stream>>>(H1, 512, (size_t)1024 * 512, c_ew2, 512, (size_t)1024 * 512, eb2, 1024,
        (float*)d_out, 1024, 0, 512, nullptr, nullptr, nullptr, 0, 8, lists, GL, counts);
}

// Round 9
// 439.997 us; speedup vs baseline: 4.1268x; 1.1889x over previous
//
#include <hip/hip_runtime.h>

typedef unsigned short u16;
typedef __attribute__((ext_vector_type(8))) short short8;   // 8 bf16 (4 VGPRs)
typedef __attribute__((ext_vector_type(4))) float f32x4;    // 4 fp32 acc

__device__ __forceinline__ float b2f(u16 u) { return __uint_as_float(((unsigned)u) << 16); }
__device__ __forceinline__ u16 f2b(float f) {
    unsigned x = __float_as_uint(f);
    return (u16)((x + 0x7fffu + ((x >> 16) & 1u)) >> 16);
}

// async global->LDS, 16B per lane; LDS dest = wave-uniform base + lane*16
#define GLDS16(gp, lp) __builtin_amdgcn_global_load_lds( \
    (const __attribute__((address_space(1))) void*)(gp), \
    (__attribute__((address_space(3))) void*)(lp), 16, 0, 0)

// ---------------------------------------------------------------------------
// Grouped MFMA GEMM: up to 4 column-segments, 2 A operands.
// Tile 128M x 64N, BK=64 (2 x 32-k chunks in LDS), 4 waves (each 32M x 64N).
// epi: 0 fp32 out; 1 fp32 out += res; 3 bf16 out.
// bx0 in 64-col tile units.
// ---------------------------------------------------------------------------
struct Seg { const u16* W; const float* bias; void* C; int ldc; int epi; int bx0; int aidx; };
struct GArgs {
    const u16* A[2]; int lda[2]; int K[2];
    Seg seg[4]; int nseg;
    const float* res;
};

__launch_bounds__(256)
__global__ void mgemm4(GArgs ga)
{
    __shared__ u16 As[8192];   // 2 chunks x [128 rows][32 k]
    __shared__ u16 Bs[4096];   // 2 chunks x [64 rows][32 k]
    int bx = blockIdx.x, by = blockIdx.y;
    int si = 0;
#pragma unroll
    for (int i = 1; i < 4; i++)
        if (i < ga.nseg && bx >= ga.seg[i].bx0) si = i;
    const u16* Wp = ga.seg[si].W;
    const float* bp = ga.seg[si].bias;
    void* Cp = ga.seg[si].C;
    const int ldco = ga.seg[si].ldc;
    const int epi = ga.seg[si].epi;
    const int ai = ga.seg[si].aidx;
    const u16* Ap = ga.A[ai];
    const int lda = ga.lda[ai], K = ga.K[ai];
    const int col0 = (bx - ga.seg[si].bx0) * 64;
    const int row0 = by * 128;

    int tid = threadIdx.x;
    int lane = tid & 63, w = tid >> 6;
    int r0 = (w << 4) + (lane >> 2), kc8 = (lane & 3) << 3;
    const u16* ga0 = Ap + (size_t)(row0 + r0) * lda + kc8;
    const u16* ga1 = Ap + (size_t)(row0 + r0 + 64) * lda + kc8;
    const u16* gb0 = Wp + (size_t)(col0 + r0) * lda + kc8;   // ldw == lda (K-major)
    u16* lA = As + (w << 9);
    u16* lB = Bs + (w << 9);

    int wrow = w << 5;                 // wave covers rows wrow..wrow+31
    int fm = lane & 15, fq = lane >> 4;
    f32x4 acc[2][4] = {};

    for (int k0 = 0; k0 < K; k0 += 64) {
        GLDS16(ga0 + k0, lA);                 // A chunk0 rows w*16
        GLDS16(ga0 + k0 + 32, lA + 4096);     // A chunk1
        GLDS16(ga1 + k0, lA + 2048);          // A chunk0 rows w*16+64
        GLDS16(ga1 + k0 + 32, lA + 2048 + 4096);
        GLDS16(gb0 + k0, lB);                 // B chunk0
        GLDS16(gb0 + k0 + 32, lB + 2048);     // B chunk1
        __syncthreads();
#pragma unroll
        for (int ks = 0; ks < 2; ks++) {
            short8 af[2], bf[4];
#pragma unroll
            for (int mt = 0; mt < 2; mt++)
                af[mt] = *(const short8*)(As + ks * 4096 + (wrow + (mt << 4) + fm) * 32 + fq * 8);
#pragma unroll
            for (int nt = 0; nt < 4; nt++)
                bf[nt] = *(const short8*)(Bs + ks * 2048 + ((nt << 4) + fm) * 32 + fq * 8);
#pragma unroll
            for (int mt = 0; mt < 2; mt++)
#pragma unroll
                for (int nt = 0; nt < 4; nt++)
                    acc[mt][nt] = __builtin_amdgcn_mfma_f32_16x16x32_bf16(af[mt], bf[nt], acc[mt][nt], 0, 0, 0);
        }
        __syncthreads();
    }

    // C/D layout: col = lane&15, row = (lane>>4)*4 + reg   [m89/m91]
#pragma unroll
    for (int mt = 0; mt < 2; mt++) {
        int rbase = row0 + wrow + (mt << 4) + (fq << 2);
#pragma unroll
        for (int nt = 0; nt < 4; nt++) {
            int c = col0 + (nt << 4) + fm;
            float bcol = bp[c];
#pragma unroll
            for (int reg = 0; reg < 4; reg++) {
                int r = rbase + reg;
                float v = acc[mt][nt][reg] + bcol;
                if (epi == 3)
                    ((u16*)Cp)[(size_t)r * ldco + c] = f2b(v);
                else if (epi == 1)
                    ((float*)Cp)[(size_t)r * ldco + c] = v + ga.res[(size_t)r * ldco + c];
                else
                    ((float*)Cp)[(size_t)r * ldco + c] = v;
            }
        }
    }
}

// ---------------------------------------------------------------------------
// MoE MFMA GEMM (per-expert z-dim, gather / atomic-scatter).
// Tile 128M x 64N, BK=64.  EPI: 2 atomicAdd(gate*(acc+bias)); 3 bf16 out.
// GATHER: A row via lists.  nsplit in 64-col units.
// ---------------------------------------------------------------------------
template<int EPI, int EPI2, int GATHER>
__launch_bounds__(256)
__global__ void mgemm(const u16* __restrict__ A, int lda, size_t astride,
                      const u16* __restrict__ W, int ldw, size_t wstride,
                      const float* __restrict__ bias, int bstride,
                      void* __restrict__ Cv, int ldc, size_t cstride,
                      int K,
                      const u16* __restrict__ W2, const float* __restrict__ bias2,
                      void* __restrict__ C2v, int ldc2, int nsplit,
                      const int* __restrict__ lists, const float* __restrict__ glist,
                      const int* __restrict__ counts)
{
    __shared__ u16 As[8192];
    __shared__ u16 Bs[4096];
    int bx = blockIdx.x, by = blockIdx.y, e = blockIdx.z;
    int cnt = counts[e];
    const int* list = lists + (e << 10);
    const float* gl = (EPI == 2) ? glist + (e << 10) : nullptr;
    int row0 = by * 128;
    if (row0 >= cnt) return;
    bool is2 = false;
    const u16* Wp = W; const float* bp = bias; void* Cp = Cv; int ldco = ldc;
    if (W2 && bx >= nsplit) { is2 = true; Wp = W2; bp = bias2; Cp = C2v; ldco = ldc2; bx -= nsplit; }
    Wp += (size_t)e * wstride;
    bp += (size_t)e * bstride;
    const u16* Ap = A + (size_t)e * astride;
    int col0 = bx * 64;

    int tid = threadIdx.x;
    int lane = tid & 63, w = tid >> 6;
    int r0 = (w << 4) + (lane >> 2), kc8 = (lane & 3) << 3;
    int ar0g = row0 + r0, ar1g = row0 + r0 + 64;
    if (GATHER) {
        int i0 = ar0g < cnt ? ar0g : cnt - 1;
        int i1 = ar1g < cnt ? ar1g : cnt - 1;
        ar0g = list[i0]; ar1g = list[i1];
    }
    const u16* ga0 = Ap + (size_t)ar0g * lda + kc8;
    const u16* ga1 = Ap + (size_t)ar1g * lda + kc8;
    const u16* gb0 = Wp + (size_t)(col0 + r0) * ldw + kc8;
    u16* lA = As + (w << 9);
    u16* lB = Bs + (w << 9);

    int wrow = w << 5;
    int fm = lane & 15, fq = lane >> 4;
    f32x4 acc[2][4] = {};

    for (int k0 = 0; k0 < K; k0 += 64) {
        GLDS16(ga0 + k0, lA);
        GLDS16(ga0 + k0 + 32, lA + 4096);
        GLDS16(ga1 + k0, lA + 2048);
        GLDS16(ga1 + k0 + 32, lA + 2048 + 4096);
        GLDS16(gb0 + k0, lB);
        GLDS16(gb0 + k0 + 32, lB + 2048);
        __syncthreads();
#pragma unroll
        for (int ks = 0; ks < 2; ks++) {
            short8 af[2], bf[4];
#pragma unroll
            for (int mt = 0; mt < 2; mt++)
                af[mt] = *(const short8*)(As + ks * 4096 + (wrow + (mt << 4) + fm) * 32 + fq * 8);
#pragma unroll
            for (int nt = 0; nt < 4; nt++)
                bf[nt] = *(const short8*)(Bs + ks * 2048 + ((nt << 4) + fm) * 32 + fq * 8);
#pragma unroll
            for (int mt = 0; mt < 2; mt++)
#pragma unroll
                for (int nt = 0; nt < 4; nt++)
                    acc[mt][nt] = __builtin_amdgcn_mfma_f32_16x16x32_bf16(af[mt], bf[nt], acc[mt][nt], 0, 0, 0);
        }
        __syncthreads();
    }

    const int epi = is2 ? EPI2 : EPI;
#pragma unroll
    for (int mt = 0; mt < 2; mt++) {
        int rbase = row0 + wrow + (mt << 4) + (fq << 2);
#pragma unroll
        for (int nt = 0; nt < 4; nt++) {
            int c = col0 + (nt << 4) + fm;
            float bcol = bp[c];
#pragma unroll
            for (int reg = 0; reg < 4; reg++) {
                int r = rbase + reg;
                if (r >= cnt) continue;
                float v = acc[mt][nt][reg] + bcol;
                if (epi == 3)
                    ((u16*)Cp)[(size_t)e * cstride + (size_t)r * ldco + c] = f2b(v);
                else
                    atomicAdd(&((float*)Cp)[(size_t)list[r] * ldco + c], gl[r] * v);
            }
        }
    }
}

// ---------------------------------------------------------------------------
// MFMA flash attention. Qp[h][s][192]=[qC|qR], Kp=[kR|kC], VT[d][kv].
// ---------------------------------------------------------------------------
__launch_bounds__(256)
__global__ void attn_mfma(const u16* __restrict__ Qp, const u16* __restrict__ Kp,
                          const u16* __restrict__ VT, u16* __restrict__ O)
{
    const int qt = blockIdx.x, h = blockIdx.y;
    const int q0 = qt * 64;
    const int tid = threadIdx.x;
    const int lane = tid & 63, w = tid >> 6;
    const int fm = lane & 15, fq = lane >> 4;

    __shared__ u16 Ks[6 * 2048];
    __shared__ u16 Vs[2 * 4096];
    __shared__ u16 Ps[4 * 1024];

    const u16* qrow = Qp + ((size_t)h * 1024 + q0 + w * 16 + fm) * 192;
    short8 qf[6];
#pragma unroll
    for (int c = 0; c < 6; c++)
        qf[c] = *(const short8*)(qrow + c * 32 + fq * 8);

    const u16* Kb = Kp + (size_t)h * 1024 * 192;
    const u16* Vb = VT + (size_t)h * 128 * 1024;

    float m_i[4], l_i[4];
#pragma unroll
    for (int r = 0; r < 4; r++) { m_i[r] = -1e30f; l_i[r] = 0.f; }
    f32x4 accO[8] = {};
    const float scale = 0.07216878364870323f;  // 1/sqrt(192)

    for (int kt = 0; kt <= qt; ++kt) {
        const int kt0 = kt * 64;
#pragma unroll
        for (int i = 0; i < 6; i++) {
            int idx = w + 4 * i;
            int c = idx >> 2, k4 = idx & 3;
            const u16* g = Kb + (size_t)(kt0 + k4 * 16 + (lane >> 2)) * 192 + c * 32 + (lane & 3) * 8;
            GLDS16(g, Ks + c * 2048 + k4 * 512 + lane * 8);
        }
#pragma unroll
        for (int i = 0; i < 4; i++) {
            int idx = w + 4 * i;
            int kc = idx >> 3, k8 = idx & 7;
            const u16* g = Vb + (size_t)(k8 * 16 + (lane >> 2)) * 1024 + kt0 + kc * 32 + (lane & 3) * 8;
            GLDS16(g, Vs + kc * 4096 + k8 * 512 + lane * 8);
        }
        __syncthreads();
        f32x4 sacc[4] = {};
#pragma unroll
        for (int nt = 0; nt < 4; nt++)
#pragma unroll
            for (int c = 0; c < 6; c++) {
                short8 kf = *(const short8*)(Ks + c * 2048 + (nt * 16 + fm) * 32 + fq * 8);
                sacc[nt] = __builtin_amdgcn_mfma_f32_16x16x32_bf16(qf[c], kf, sacc[nt], 0, 0, 0);
            }
        const bool diag = (kt == qt);
        const int rbase = w * 16 + fq * 4;
        float pv[4][4], rmax[4];
#pragma unroll
        for (int reg = 0; reg < 4; reg++) {
            float mx = -1e30f;
#pragma unroll
            for (int nt = 0; nt < 4; nt++) {
                float s = sacc[nt][reg] * scale;
                if (diag && (nt * 16 + fm) > (rbase + reg)) s = -1e30f;
                pv[nt][reg] = s;
                mx = fmaxf(mx, s);
            }
            rmax[reg] = mx;
        }
#pragma unroll
        for (int m = 1; m < 16; m <<= 1)
#pragma unroll
            for (int reg = 0; reg < 4; reg++)
                rmax[reg] = fmaxf(rmax[reg], __shfl_xor(rmax[reg], m));
        float alpha[4], rsum[4];
#pragma unroll
        for (int reg = 0; reg < 4; reg++) {
            float mn = fmaxf(m_i[reg], rmax[reg]);
            alpha[reg] = __expf(m_i[reg] - mn);
            m_i[reg] = mn;
            float s = 0.f;
#pragma unroll
            for (int nt = 0; nt < 4; nt++) {
                float p = __expf(pv[nt][reg] - mn);
                pv[nt][reg] = p;
                s += p;
            }
            rsum[reg] = s;
        }
#pragma unroll
        for (int m = 1; m < 16; m <<= 1)
#pragma unroll
            for (int reg = 0; reg < 4; reg++)
                rsum[reg] += __shfl_xor(rsum[reg], m);
#pragma unroll
        for (int reg = 0; reg < 4; reg++)
            l_i[reg] = l_i[reg] * alpha[reg] + rsum[reg];
#pragma unroll
        for (int nt = 0; nt < 4; nt++)
#pragma unroll
            for (int reg = 0; reg < 4; reg++)
                Ps[w * 1024 + (nt >> 1) * 512 + (fq * 4 + reg) * 32 + (nt & 1) * 16 + fm]
                    = f2b(pv[nt][reg]);
#pragma unroll
        for (int n2 = 0; n2 < 8; n2++)
#pragma unroll
            for (int reg = 0; reg < 4; reg++)
                accO[n2][reg] *= alpha[reg];
        short8 pf[2];
#pragma unroll
        for (int kc = 0; kc < 2; kc++)
            pf[kc] = *(const short8*)(Ps + w * 1024 + kc * 512 + fm * 32 + fq * 8);
#pragma unroll
        for (int n2 = 0; n2 < 8; n2++)
#pragma unroll
            for (int kc = 0; kc < 2; kc++) {
                short8 vf = *(const short8*)(Vs + kc * 4096 + (n2 * 16 + fm) * 32 + fq * 8);
                accO[n2] = __builtin_amdgcn_mfma_f32_16x16x32_bf16(pf[kc], vf, accO[n2], 0, 0, 0);
            }
        __syncthreads();
    }
#pragma unroll
    for (int reg = 0; reg < 4; reg++) {
        int row = q0 + w * 16 + fq * 4 + reg;
        float inv = 1.f / l_i[reg];
#pragma unroll
        for (int n2 = 0; n2 < 8; n2++)
            O[(size_t)row * 1024 + h * 128 + n2 * 16 + fm] = f2b(accO[n2][reg] * inv);
    }
}

// two rmsnorms (bf16 out) in one launch: blocks [0,1024) -> (X0,c0), rest -> (X1,c1)
__launch_bounds__(256)
__global__ void rmsnorm2x(const float* __restrict__ X0, const float* __restrict__ w0,
                          u16* __restrict__ O0, int c0,
                          const float* __restrict__ X1, const float* __restrict__ w1,
                          u16* __restrict__ O1, int c1)
{
    int b = blockIdx.x, tid = threadIdx.x;
    const float* X; const float* w; u16* O; int cols; int r;
    if (b < 1024) { X = X0; w = w0; O = O0; cols = c0; r = b; }
    else          { X = X1; w = w1; O = O1; cols = c1; r = b - 1024; }
    const float* xr = X + (size_t)r * cols;
    float ss = 0.f;
    for (int j = tid; j < cols; j += 256) { float v = xr[j]; ss += v * v; }
    __shared__ float red[256];
    red[tid] = ss; __syncthreads();
    for (int st = 128; st > 0; st >>= 1) { if (tid < st) red[tid] += red[tid + st]; __syncthreads(); }
    float scale = rsqrtf(red[0] / cols + 1e-6f);
    for (int j = tid; j < cols; j += 256)
        O[(size_t)r * cols + j] = f2b(xr[j] * scale * w[j]);
}

// ---------------------------------------------------------------------------
// rmsnorm_route: blocks [0,1024): Y16 = bf16(rmsnorm(X1,ffn_w)).
// blocks [1024,2048): routing for token t=b-1024 — affinity dot accumulated
// pre-scale (linear), sigmoid+top2 post-reduction.
// ---------------------------------------------------------------------------
__launch_bounds__(256)
__global__ void rmsnorm_route(const float* __restrict__ X1, const float* __restrict__ ffnw,
                              u16* __restrict__ Y16,
                              const float* __restrict__ cent, const float* __restrict__ biases,
                              int* __restrict__ counts, int* __restrict__ lists,
                              float* __restrict__ glist)
{
    __shared__ float red[256];
    int b = blockIdx.x, tid = threadIdx.x;
    if (b < 1024) {
        int r = b;
        const float* xr = X1 + (size_t)r * 1024;
        float ss = 0.f;
        for (int j = tid; j < 1024; j += 256) { float v = xr[j]; ss += v * v; }
        red[tid] = ss; __syncthreads();
        for (int st = 128; st > 0; st >>= 1) { if (tid < st) red[tid] += red[tid + st]; __syncthreads(); }
        float scale = rsqrtf(red[0] / 1024.f + 1e-6f);
        for (int j = tid; j < 1024; j += 256)
            Y16[(size_t)r * 1024 + j] = f2b(xr[j] * scale * ffnw[j]);
    } else {
        int t = b - 1024;
        const float* xr = X1 + (size_t)t * 1024;
        float ss = 0.f;
        float acc[8] = {};
        for (int j = tid; j < 1024; j += 256) {
            float x = xr[j];
            ss += x * x;
            float yp = x * ffnw[j];
#pragma unroll
            for (int e = 0; e < 8; e++) acc[e] += yp * cent[e * 1024 + j];
        }
        red[tid] = ss; __syncthreads();
        for (int st = 128; st > 0; st >>= 1) { if (tid < st) red[tid] += red[tid + st]; __syncthreads(); }
        float scale = rsqrtf(red[0] / 1024.f + 1e-6f);
        __syncthreads();
        __shared__ float aff[8];
        for (int e = 0; e < 8; e++) {
            red[tid] = acc[e]; __syncthreads();
            for (int st = 128; st > 0; st >>= 1) { if (tid < st) red[tid] += red[tid + st]; __syncthreads(); }
            if (tid == 0) aff[e] = 1.f / (1.f + expf(-red[0] * scale));
            __syncthreads();
        }
        if (tid == 0) {
            float sb[8];
#pragma unroll
            for (int e = 0; e < 8; e++) sb[e] = aff[e] + biases[e];
            int i0 = 0;
            for (int e = 1; e < 8; e++) if (sb[e] > sb[i0]) i0 = e;
            int i1 = -1;
            for (int e = 0; e < 8; e++) { if (e == i0) continue; if (i1 < 0 || sb[e] > sb[i1]) i1 = e; }
            float a0 = aff[i0], a1 = aff[i1];
            float mx = fmaxf(a0, a1);
            float e0 = expf(a0 - mx), e1 = expf(a1 - mx);
            float inv = 1.f / (e0 + e1);
            int p0 = atomicAdd(&counts[i0], 1);
            lists[i0 * 1024 + p0] = t; glist[i0 * 1024 + p0] = e0 * inv;
            int p1 = atomicAdd(&counts[i1], 1);
            lists[i1 * 1024 + p1] = t; glist[i1 * 1024 + p1] = e1 * inv;
        }
    }
}

// ---------------------------------------------------------------------------
// pack_all: blocks [0,1024): per-token s — KR rmsnorm+rope from KRraw,
// pack Q (with QR rope) and K into [h][s][192].
// Blocks [1024,1280): transpose V (bf16 [s][d] -> [d][s]).
// ---------------------------------------------------------------------------
__launch_bounds__(256)
__global__ void pack_all(const float* __restrict__ QC, const float* __restrict__ QRr,
                         const float* __restrict__ KRraw, const float* __restrict__ krw,
                         const float* __restrict__ KC,
                         const u16* __restrict__ VCb,
                         const float* __restrict__ fcos, const float* __restrict__ fsin,
                         u16* __restrict__ Qp, u16* __restrict__ Kp, u16* __restrict__ VT)
{
    __shared__ u16 Ts[64][68];
    __shared__ float kshared[64];
    int b = blockIdx.x, tid = threadIdx.x;
    if (b < 1024) {
        int s = b;
        if (tid < 64) {
            float v = KRraw[(size_t)s * 64 + tid];
            float ss = v * v;
#pragma unroll
            for (int m = 1; m < 64; m <<= 1) ss += __shfl_xor(ss, m);
            float scale = rsqrtf(ss / 64.f + 1e-6f);
            int j = tid >> 1;
            float c = fcos[s * 32 + j], sn = fsin[s * 32 + j];
            float x0 = KRraw[(size_t)s * 64 + (tid & ~1)] * scale * krw[tid & ~1];
            float x1 = KRraw[(size_t)s * 64 + (tid | 1)]  * scale * krw[tid | 1];
            kshared[tid] = (tid & 1) ? (x0 * sn + x1 * c) : (x0 * c - x1 * sn);
        }
        __syncthreads();
        for (int e = tid; e < 1536; e += 256) {
            int h = e / 192, d = e % 192;
            float q;
            if (d < 128) {
                q = QC[(size_t)s * 1024 + h * 128 + d];
            } else {
                int dd = d - 128, j = dd >> 1;
                float c = fcos[s * 32 + j], sn = fsin[s * 32 + j];
                float x0 = QRr[(size_t)s * 512 + h * 64 + (dd & ~1)];
                float x1 = QRr[(size_t)s * 512 + h * 64 + (dd | 1)];
                q = (dd & 1) ? (x0 * sn + x1 * c) : (x0 * c - x1 * sn);
            }
            Qp[((size_t)h * 1024 + s) * 192 + d] = f2b(q);
            float k = (d < 64) ? kshared[d]
                               : KC[(size_t)s * 1024 + h * 128 + d - 64];
            Kp[((size_t)h * 1024 + s) * 192 + d] = f2b(k);
        }
    } else {
        int idx = b - 1024;
        int s0 = (idx & 15) * 64, d0 = (idx >> 4) * 64;
        for (int k = 0; k < 16; k++) {
            int e = tid + k * 256, r = e >> 6, c = e & 63;
            Ts[r][c] = VCb[(size_t)(s0 + r) * 1024 + d0 + c];
        }
        __syncthreads();
        for (int k = 0; k < 16; k++) {
            int e = tid + k * 256, d = e >> 6, s = e & 63;
            VT[(size_t)(d0 + d) * 1024 + s0 + s] = Ts[s][d];
        }
    }
}

// ---------------------------------------------------------------------------
// silu-mul: G = bf16(silu(U) * V)
// ---------------------------------------------------------------------------
__launch_bounds__(256)
__global__ void silu_mul(const u16* __restrict__ U, const u16* __restrict__ V,
                         u16* __restrict__ G, int n)
{
    int i = blockIdx.x * 256 + threadIdx.x;
    if (i < n) {
        float u = b2f(U[i]), v = b2f(V[i]);
        G[i] = f2b(u / (1.f + expf(-u)) * v);
    }
}

// ---------------------------------------------------------------------------
// Fused fp32->bf16 cast of 14 weight arrays + the X rmsnorm (blocks >= NCAST).
// ---------------------------------------------------------------------------
#define NCAST 4096
__launch_bounds__(256)
__global__ void fused_cast(const float* p0, const float* p1, const float* p2,
                           const float* p3, const float* p4, const float* p5,
                           const float* p6, const float* p7, const float* p8,
                           const float* p9, const float* p10, const float* p11,
                           const float* p12, const float* pkr,
                           u16* __restrict__ dst,
                           const float* __restrict__ hX, const float* __restrict__ attnw,
                           u16* __restrict__ X16)
{
    __shared__ float red[256];
    int b = blockIdx.x, tid = threadIdx.x;
    if (b < NCAST) {
        const int NQ = 18022400 / 4;   // 17956864 + 65536 (wkr)
        for (int i = b * 256 + tid; i < NQ; i += NCAST * 256) {
            int e = i * 4;
            const float* s; int base;
            if      (e <   786432) { s = p0;  base = 0; }
            else if (e <  1048576) { s = p1;  base =   786432; }
            else if (e <  1835008) { s = p2;  base =  1048576; }
            else if (e <  2228224) { s = p3;  base =  1835008; }
            else if (e <  2490368) { s = p4;  base =  2228224; }
            else if (e <  2752512) { s = p5;  base =  2490368; }
            else if (e <  3801088) { s = p6;  base =  2752512; }
            else if (e <  4325376) { s = p7;  base =  3801088; }
            else if (e <  4849664) { s = p8;  base =  4325376; }
            else if (e <  5373952) { s = p9;  base =  4849664; }
            else if (e <  9568256) { s = p10; base =  5373952; }
            else if (e < 13762560) { s = p11; base =  9568256; }
            else if (e < 17956864) { s = p12; base = 13762560; }
            else                   { s = pkr; base = 17956864; }
            float4 v = *(const float4*)(s + (e - base));
            ushort4 o;
            o.x = f2b(v.x); o.y = f2b(v.y); o.z = f2b(v.z); o.w = f2b(v.w);
            *(ushort4*)(dst + e) = o;
        }
    } else {
        int r = b - NCAST;
        const float* xr = hX + (size_t)r * 1024;
        float ss = 0.f;
        for (int j = tid; j < 1024; j += 256) { float v = xr[j]; ss += v * v; }
        red[tid] = ss; __syncthreads();
        for (int st = 128; st > 0; st >>= 1) { if (tid < st) red[tid] += red[tid + st]; __syncthreads(); }
        float scale = rsqrtf(red[0] / 1024.f + 1e-6f);
        for (int j = tid; j < 1024; j += 256)
            X16[(size_t)r * 1024 + j] = f2b(xr[j] * scale * attnw[j]);
    }
}

// ---------------------------------------------------------------------------
extern "C" void kernel_launch(void* const* d_in, const int* in_sizes, int n_in,
                              void* d_out, int out_size, void* d_ws, size_t ws_size,
                              hipStream_t stream)
{
    (void)in_sizes; (void)n_in; (void)ws_size; (void)out_size;
    const float* h       = (const float*)d_in[0];
    const float* fcos    = (const float*)d_in[1];
    const float* fsin    = (const float*)d_in[2];
    const float* attn_w  = (const float*)d_in[4];
    const float* ffn_w   = (const float*)d_in[5];
    const float* wq_down = (const float*)d_in[6];
    const float* bq_down = (const float*)d_in[7];
    const float* q_norm  = (const float*)d_in[8];
    const float* wqc     = (const float*)d_in[9];
    const float* bqc     = (const float*)d_in[10];
    const float* wqr     = (const float*)d_in[11];
    const float* bqr     = (const float*)d_in[12];
    const float* wkr     = (const float*)d_in[13];
    const float* bkr     = (const float*)d_in[14];
    const float* kr_norm = (const float*)d_in[15];
    const float* wkv     = (const float*)d_in[16];
    const float* bkv     = (const float*)d_in[17];
    const float* kv_norm = (const float*)d_in[18];
    const float* wkc     = (const float*)d_in[19];
    const float* bkc     = (const float*)d_in[20];
    const float* wvc     = (const float*)d_in[21];
    const float* bvc     = (const float*)d_in[22];
    const float* wo      = (const float*)d_in[23];
    const float* bo      = (const float*)d_in[24];
    const float* sw1     = (const float*)d_in[25];
    const float* sb1     = (const float*)d_in[26];
    const float* sw2     = (const float*)d_in[27];
    const float* sb2     = (const float*)d_in[28];
    const float* sw3     = (const float*)d_in[29];
    const float* sb3     = (const float*)d_in[30];
    const float* ew1     = (const float*)d_in[31];
    const float* eb1     = (const float*)d_in[32];
    const float* ew2     = (const float*)d_in[33];
    const float* eb2     = (const float*)d_in[34];
    const float* ew3     = (const float*)d_in[35];
    const float* eb3     = (const float*)d_in[36];
    const float* cent    = (const float*)d_in[37];
    const float* biases  = (const float*)d_in[38];

    char* wsb = (char*)d_ws;
    const size_t U5 = 512 * 1024;  // 0.5 MB unit
    u16*   H1    = (u16*)(wsb + 0);            // 8 MB  (MoE phase)
    u16*   X16   = (u16*)(wsb + 8 * U5);       // 2 MB
    float* QRr   = (float*)(wsb + 12 * U5);    // 2 MB  (raw QR, rope in pack)
    float* CQraw = (float*)(wsb + 16 * U5);    // 3 MB  (early)
    u16*   ATT16 = (u16*)(wsb + 16 * U5);      // 2 MB  (attn out, after CQraw dead)
    u16*   G16   = (u16*)(wsb + 20 * U5);      // 1 MB
    u16*   CQ16  = (u16*)(wsb + 22 * U5);      // 1.5 MB
    float* CKVraw= (float*)(wsb + 25 * U5);    // 1 MB
    u16*   CKV16 = (u16*)(wsb + 27 * U5);      // 0.5 MB
    float* KRraw = (float*)(wsb + 28 * U5);    // 0.25 MB (pre-norm KR)
    float* QC    = (float*)(wsb + 29 * U5);    // 4 MB  (dead after pack)
    float* KC    = (float*)(wsb + 37 * U5);    // 4 MB  (dead after pack)
    u16*   Vb    = (u16*)(wsb + 29 * U5);      // 8 MB  (GLU V; overlays QC+KC)
    float* X1    = (float*)(wsb + 53 * U5);    // 4 MB
    u16*   Y16   = (u16*)(wsb + 69 * U5);      // 2 MB
    u16*   Ub    = (u16*)(wsb + 73 * U5);      // 8 MB
    float* GL    = (float*)(wsb + 89 * U5);
    int*   lists = (int*)(wsb + 89 * U5 + 32 * 1024);
    int*   counts= (int*)(wsb + 89 * U5 + 64 * 1024);

    // bf16 weight arena (contiguous, order matches fused_cast)
    u16* wb = (u16*)(wsb + 90 * U5);
    u16 *c_wq  = wb;
    u16 *c_wkv = c_wq  + 786432;
    u16 *c_wqc = c_wkv + 262144;
    u16 *c_wqr = c_wqc + 786432;
    u16 *c_wkc = c_wqr + 393216;
    u16 *c_wvc = c_wkc + 262144;
    u16 *c_wo  = c_wvc + 262144;
    u16 *c_sw1 = c_wo  + 1048576;
    u16 *c_sw3 = c_sw1 + 524288;
    u16 *c_sw2 = c_sw3 + 524288;
    u16 *c_ew1 = c_sw2 + 524288;
    u16 *c_ew3 = c_ew1 + 4194304;
    u16 *c_ew2 = c_ew3 + 4194304;
    u16 *c_wkr = c_ew2 + 4194304;                 // 64x1024 (exact, no pad)
    u16* VCb = (u16*)(wsb + 90 * U5 + 36175872);  // 2 MB  bf16 V [s][d]
    u16* VTp = VCb + 1048576;                     // 2 MB  bf16 V^T [d][s]
    u16* Qpk = VTp + 1048576;                     // 3 MB
    u16* Kpk = Qpk + 1572864;                     // 3 MB

    // weight cast + X rmsnorm, one launch
    fused_cast<<<NCAST + 1024, 256, 0, stream>>>(wq_down, wkv, wqc, wqr, wkc, wvc, wo,
                                                 sw1, sw3, sw2, ew1, ew3, ew2, wkr, wb,
                                                 h, attn_w, X16);

    // --- attention branch ---
    {
        GArgs g = {};
        g.A[0] = X16; g.lda[0] = 1024; g.K[0] = 1024;
        g.seg[0] = { c_wq,  bq_down, CQraw,  768, 0, 0,  0 };
        g.seg[1] = { c_wkv, bkv,     CKVraw, 256, 0, 12, 0 };
        g.seg[2] = { c_wkr, bkr,     KRraw,  64,  0, 16, 0 };
        g.nseg = 3; g.res = nullptr;
        mgemm4<<<dim3(17, 8), 256, 0, stream>>>(g);
    }
    rmsnorm2x<<<2048, 256, 0, stream>>>(CQraw, q_norm, CQ16, 768,
                                        CKVraw, kv_norm, CKV16, 256);
    {
        GArgs g = {};
        g.A[0] = CQ16;  g.lda[0] = 768; g.K[0] = 768;
        g.A[1] = CKV16; g.lda[1] = 256; g.K[1] = 256;
        g.seg[0] = { c_wqc, bqc, QC,   1024, 0, 0,  0 };
        g.seg[1] = { c_wqr, bqr, QRr,  512,  0, 16, 0 };
        g.seg[2] = { c_wkc, bkc, KC,   1024, 0, 24, 1 };
        g.seg[3] = { c_wvc, bvc, VCb,  1024, 3, 40, 1 };
        g.nseg = 4; g.res = nullptr;
        mgemm4<<<dim3(56, 8), 256, 0, stream>>>(g);
    }
    pack_all<<<1280, 256, 0, stream>>>(QC, QRr, KRraw, kr_norm, KC, VCb, fcos, fsin,
                                       Qpk, Kpk, VTp);
    attn_mfma<<<dim3(16, 8), 256, 0, stream>>>(Qpk, Kpk, VTp, ATT16);
    {
        GArgs g = {};
        g.A[0] = ATT16; g.lda[0] = 1024; g.K[0] = 1024;
        g.seg[0] = { c_wo, bo, X1, 1024, 1, 0, 0 };
        g.nseg = 1; g.res = h;
        mgemm4<<<dim3(16, 8), 256, 0, stream>>>(g);
    }

    // --- FFN branch + routing (fused) ---
    hipMemsetAsync(counts, 0, 32, stream);
    rmsnorm_route<<<2048, 256, 0, stream>>>(X1, ffn_w, Y16, cent, biases,
                                            counts, lists, GL);
    {
        GArgs g = {};
        g.A[0] = Y16; g.lda[0] = 1024; g.K[0] = 1024;
        g.seg[0] = { c_sw1, sb1, Ub, 512, 3, 0, 0 };
        g.seg[1] = { c_sw3, sb3, Vb, 512, 3, 8, 0 };
        g.nseg = 2; g.res = nullptr;
        mgemm4<<<dim3(16, 8), 256, 0, stream>>>(g);
    }
    silu_mul<<<2048, 256, 0, stream>>>(Ub, Vb, G16, 524288);
    {
        GArgs g = {};
        g.A[0] = G16; g.lda[0] = 512; g.K[0] = 512;
        g.seg[0] = { c_sw2, sb2, d_out, 1024, 1, 0, 0 };
        g.nseg = 1; g.res = X1;
        mgemm4<<<dim3(16, 8), 256, 0, stream>>>(g);
    }

    // --- MoE ---
    mgemm<3, 3, 1><<<dim3(16, 8, 8), 256, 0, stream>>>(Y16, 1024, 0, c_ew1, 1024, (size_t)512 * 1024, eb1, 512,
        Ub, 512, (size_t)1024 * 512, 1024, c_ew3, eb3, Vb, 512, 8, lists, nullptr, counts);
    silu_mul<<<16384, 256, 0, stream>>>(Ub, Vb, H1, 4194304);
    mgemm<2, 0, 0><<<dim3(16, 8, 8), 256, 0, stream>>>(H1, 512, (size_t)1024 * 512, c_ew2, 512, (size_t)1024 * 512, eb2, 1024,
        (float*)d_out, 1024, 0, 512, nullptr, nullptr, nullptr, 0, 16, lists, GL, counts);
}

// Round 10
// 424.206 us; speedup vs baseline: 4.2804x; 1.0372x over previous
//
#include <hip/hip_runtime.h>

typedef unsigned short u16;
typedef __attribute__((ext_vector_type(8))) short short8;   // 8 bf16 (4 VGPRs)
typedef __attribute__((ext_vector_type(4))) float f32x4;    // 4 fp32 acc

__device__ __forceinline__ float b2f(u16 u) { return __uint_as_float(((unsigned)u) << 16); }
__device__ __forceinline__ u16 f2b(float f) {
    unsigned x = __float_as_uint(f);
    return (u16)((x + 0x7fffu + ((x >> 16) & 1u)) >> 16);
}

// async global->LDS, 16B per lane; LDS dest = wave-uniform base + lane*16
#define GLDS16(gp, lp) __builtin_amdgcn_global_load_lds( \
    (const __attribute__((address_space(1))) void*)(gp), \
    (__attribute__((address_space(3))) void*)(lp), 16, 0, 0)

// ---------------------------------------------------------------------------
// Grouped MFMA GEMM: up to 4 column-segments, 2 A operands.
// Tile 128M x 64N, BK=64, 4 waves. epi: 0 fp32; 1 fp32 += res (dual-dest via
// dst2); 3 bf16.  bx0 in 64-col units.
// ---------------------------------------------------------------------------
struct Seg { const u16* W; const float* bias; void* C; int ldc; int epi; int bx0; int aidx; };
struct GArgs {
    const u16* A[2]; int lda[2]; int K[2];
    Seg seg[4]; int nseg;
    const float* res;
    float* dst2;
};

__launch_bounds__(256)
__global__ void mgemm4(GArgs ga)
{
    __shared__ u16 As[8192];   // 2 chunks x [128 rows][32 k]
    __shared__ u16 Bs[4096];   // 2 chunks x [64 rows][32 k]
    int bx = blockIdx.x, by = blockIdx.y;
    int si = 0;
#pragma unroll
    for (int i = 1; i < 4; i++)
        if (i < ga.nseg && bx >= ga.seg[i].bx0) si = i;
    const u16* Wp = ga.seg[si].W;
    const float* bp = ga.seg[si].bias;
    void* Cp = ga.seg[si].C;
    const int ldco = ga.seg[si].ldc;
    const int epi = ga.seg[si].epi;
    const int ai = ga.seg[si].aidx;
    const u16* Ap = ga.A[ai];
    const int lda = ga.lda[ai], K = ga.K[ai];
    const int col0 = (bx - ga.seg[si].bx0) * 64;
    const int row0 = by * 128;

    int tid = threadIdx.x;
    int lane = tid & 63, w = tid >> 6;
    int r0 = (w << 4) + (lane >> 2), kc8 = (lane & 3) << 3;
    const u16* ga0 = Ap + (size_t)(row0 + r0) * lda + kc8;
    const u16* ga1 = Ap + (size_t)(row0 + r0 + 64) * lda + kc8;
    const u16* gb0 = Wp + (size_t)(col0 + r0) * lda + kc8;   // ldw == lda
    u16* lA = As + (w << 9);
    u16* lB = Bs + (w << 9);

    int wrow = w << 5;
    int fm = lane & 15, fq = lane >> 4;
    f32x4 acc[2][4] = {};

    for (int k0 = 0; k0 < K; k0 += 64) {
        GLDS16(ga0 + k0, lA);
        GLDS16(ga0 + k0 + 32, lA + 4096);
        GLDS16(ga1 + k0, lA + 2048);
        GLDS16(ga1 + k0 + 32, lA + 2048 + 4096);
        GLDS16(gb0 + k0, lB);
        GLDS16(gb0 + k0 + 32, lB + 2048);
        __syncthreads();
#pragma unroll
        for (int ks = 0; ks < 2; ks++) {
            short8 af[2], bf[4];
#pragma unroll
            for (int mt = 0; mt < 2; mt++)
                af[mt] = *(const short8*)(As + ks * 4096 + (wrow + (mt << 4) + fm) * 32 + fq * 8);
#pragma unroll
            for (int nt = 0; nt < 4; nt++)
                bf[nt] = *(const short8*)(Bs + ks * 2048 + ((nt << 4) + fm) * 32 + fq * 8);
#pragma unroll
            for (int mt = 0; mt < 2; mt++)
#pragma unroll
                for (int nt = 0; nt < 4; nt++)
                    acc[mt][nt] = __builtin_amdgcn_mfma_f32_16x16x32_bf16(af[mt], bf[nt], acc[mt][nt], 0, 0, 0);
        }
        __syncthreads();
    }

    // C/D layout: col = lane&15, row = (lane>>4)*4 + reg   [m89/m91]
#pragma unroll
    for (int mt = 0; mt < 2; mt++) {
        int rbase = row0 + wrow + (mt << 4) + (fq << 2);
#pragma unroll
        for (int nt = 0; nt < 4; nt++) {
            int c = col0 + (nt << 4) + fm;
            float bcol = bp[c];
#pragma unroll
            for (int reg = 0; reg < 4; reg++) {
                int r = rbase + reg;
                float v = acc[mt][nt][reg] + bcol;
                if (epi == 3)
                    ((u16*)Cp)[(size_t)r * ldco + c] = f2b(v);
                else if (epi == 1) {
                    float o = v + ga.res[(size_t)r * ldco + c];
                    ((float*)Cp)[(size_t)r * ldco + c] = o;
                    if (ga.dst2) ga.dst2[(size_t)r * ldco + c] = o;
                } else
                    ((float*)Cp)[(size_t)r * ldco + c] = v;
            }
        }
    }
}

// ---------------------------------------------------------------------------
// mega_glu: shared GLU (z=0: sw1/sw3, 1024 rows) + experts (z=1..8: ew1/ew3,
// gathered rows).  bx 0..7 -> W1 path (out U), bx 8..15 -> W3 path (out V).
// Out bf16 at z*524288, ld 512.
// ---------------------------------------------------------------------------
__launch_bounds__(256)
__global__ void mega_glu(const u16* __restrict__ Y16,
                         const u16* __restrict__ sw1, const float* __restrict__ sb1,
                         const u16* __restrict__ sw3, const float* __restrict__ sb3,
                         const u16* __restrict__ ew1, const float* __restrict__ eb1,
                         const u16* __restrict__ ew3, const float* __restrict__ eb3,
                         u16* __restrict__ Ub, u16* __restrict__ Vb,
                         const int* __restrict__ lists, const int* __restrict__ counts)
{
    __shared__ u16 As[8192];
    __shared__ u16 Bs[4096];
    int bx = blockIdx.x, by = blockIdx.y, z = blockIdx.z;
    bool w3 = bx >= 8;
    int col0 = (w3 ? bx - 8 : bx) * 64;
    int cnt = 1024; const int* list = nullptr;
    const u16* Wp; const float* bp;
    if (z == 0) {
        Wp = w3 ? sw3 : sw1; bp = w3 ? sb3 : sb1;
    } else {
        int e = z - 1; cnt = counts[e]; list = lists + (e << 10);
        Wp = (w3 ? ew3 : ew1) + (size_t)e * 512 * 1024;
        bp = (w3 ? eb3 : eb1) + e * 512;
    }
    int row0 = by * 128;
    if (row0 >= cnt) return;
    u16* Cp = (w3 ? Vb : Ub) + (size_t)z * 524288;

    int tid = threadIdx.x, lane = tid & 63, w = tid >> 6;
    int r0 = (w << 4) + (lane >> 2), kc8 = (lane & 3) << 3;
    int ar0 = row0 + r0, ar1 = row0 + r0 + 64;
    if (z > 0) {
        ar0 = list[ar0 < cnt ? ar0 : cnt - 1];
        ar1 = list[ar1 < cnt ? ar1 : cnt - 1];
    }
    const u16* ga0 = Y16 + (size_t)ar0 * 1024 + kc8;
    const u16* ga1 = Y16 + (size_t)ar1 * 1024 + kc8;
    const u16* gb0 = Wp + (size_t)(col0 + r0) * 1024 + kc8;
    u16* lA = As + (w << 9);
    u16* lB = Bs + (w << 9);

    int wrow = w << 5, fm = lane & 15, fq = lane >> 4;
    f32x4 acc[2][4] = {};

    for (int k0 = 0; k0 < 1024; k0 += 64) {
        GLDS16(ga0 + k0, lA);
        GLDS16(ga0 + k0 + 32, lA + 4096);
        GLDS16(ga1 + k0, lA + 2048);
        GLDS16(ga1 + k0 + 32, lA + 2048 + 4096);
        GLDS16(gb0 + k0, lB);
        GLDS16(gb0 + k0 + 32, lB + 2048);
        __syncthreads();
#pragma unroll
        for (int ks = 0; ks < 2; ks++) {
            short8 af[2], bf[4];
#pragma unroll
            for (int mt = 0; mt < 2; mt++)
                af[mt] = *(const short8*)(As + ks * 4096 + (wrow + (mt << 4) + fm) * 32 + fq * 8);
#pragma unroll
            for (int nt = 0; nt < 4; nt++)
                bf[nt] = *(const short8*)(Bs + ks * 2048 + ((nt << 4) + fm) * 32 + fq * 8);
#pragma unroll
            for (int mt = 0; mt < 2; mt++)
#pragma unroll
                for (int nt = 0; nt < 4; nt++)
                    acc[mt][nt] = __builtin_amdgcn_mfma_f32_16x16x32_bf16(af[mt], bf[nt], acc[mt][nt], 0, 0, 0);
        }
        __syncthreads();
    }

#pragma unroll
    for (int mt = 0; mt < 2; mt++) {
        int rbase = row0 + wrow + (mt << 4) + (fq << 2);
#pragma unroll
        for (int nt = 0; nt < 4; nt++) {
            int c = col0 + (nt << 4) + fm;
            float bcol = bp[c];
#pragma unroll
            for (int reg = 0; reg < 4; reg++) {
                int r = rbase + reg;
                if (r >= cnt) continue;
                Cp[(size_t)r * 512 + c] = f2b(acc[mt][nt][reg] + bcol);
            }
        }
    }
}

// ---------------------------------------------------------------------------
// mega_down: out[tok] += g * (silu(U)*V @ W2^T + b2).  A computed in-kernel
// from staged U,V tiles (same f2b rounding as the old silu_mul).  z=0 shared
// (g=1, tok=r), z>=1 experts (gate, scatter).  All writes atomicAdd (d_out
// pre-filled with X1 by the wo GEMM).
// ---------------------------------------------------------------------------
__launch_bounds__(256)
__global__ void mega_down(const u16* __restrict__ Ub, const u16* __restrict__ Vb,
                          const u16* __restrict__ sw2, const float* __restrict__ sb2,
                          const u16* __restrict__ ew2, const float* __restrict__ eb2,
                          float* __restrict__ out,
                          const int* __restrict__ lists, const float* __restrict__ glist,
                          const int* __restrict__ counts)
{
    __shared__ u16 Us[8192];
    __shared__ u16 Vs[8192];
    __shared__ u16 Bs[4096];
    int bx = blockIdx.x, by = blockIdx.y, z = blockIdx.z;
    int cnt = 1024; const int* list = nullptr; const float* gl = nullptr;
    const u16* Wp; const float* bp;
    if (z == 0) { Wp = sw2; bp = sb2; }
    else {
        int e = z - 1;
        cnt = counts[e]; list = lists + (e << 10); gl = glist + (e << 10);
        Wp = ew2 + (size_t)e * 1024 * 512; bp = eb2 + e * 1024;
    }
    int row0 = by * 128;
    if (row0 >= cnt) return;
    const u16* Ap = Ub + (size_t)z * 524288;
    const u16* Vp = Vb + (size_t)z * 524288;
    int col0 = bx * 64;

    int tid = threadIdx.x, lane = tid & 63, w = tid >> 6;
    int r0 = (w << 4) + (lane >> 2), kc8 = (lane & 3) << 3;
    const u16* gu0 = Ap + (size_t)(row0 + r0) * 512 + kc8;
    const u16* gu1 = Ap + (size_t)(row0 + r0 + 64) * 512 + kc8;
    const u16* gv0 = Vp + (size_t)(row0 + r0) * 512 + kc8;
    const u16* gv1 = Vp + (size_t)(row0 + r0 + 64) * 512 + kc8;
    const u16* gb0 = Wp + (size_t)(col0 + r0) * 512 + kc8;
    u16* lU = Us + (w << 9);
    u16* lV = Vs + (w << 9);
    u16* lB = Bs + (w << 9);

    int wrow = w << 5, fm = lane & 15, fq = lane >> 4;
    f32x4 acc[2][4] = {};

    for (int k0 = 0; k0 < 512; k0 += 64) {
        GLDS16(gu0 + k0, lU);        GLDS16(gu0 + k0 + 32, lU + 4096);
        GLDS16(gu1 + k0, lU + 2048); GLDS16(gu1 + k0 + 32, lU + 2048 + 4096);
        GLDS16(gv0 + k0, lV);        GLDS16(gv0 + k0 + 32, lV + 4096);
        GLDS16(gv1 + k0, lV + 2048); GLDS16(gv1 + k0 + 32, lV + 2048 + 4096);
        GLDS16(gb0 + k0, lB);        GLDS16(gb0 + k0 + 32, lB + 2048);
        __syncthreads();
#pragma unroll
        for (int ks = 0; ks < 2; ks++) {
            short8 gf[2], bf[4];
#pragma unroll
            for (int mt = 0; mt < 2; mt++) {
                int off = ks * 4096 + (wrow + (mt << 4) + fm) * 32 + fq * 8;
                short8 u8 = *(const short8*)(Us + off);
                short8 v8 = *(const short8*)(Vs + off);
#pragma unroll
                for (int i = 0; i < 8; i++) {
                    float u = b2f((u16)u8[i]), v = b2f((u16)v8[i]);
                    gf[mt][i] = (short)f2b(u / (1.f + __expf(-u)) * v);
                }
            }
#pragma unroll
            for (int nt = 0; nt < 4; nt++)
                bf[nt] = *(const short8*)(Bs + ks * 2048 + ((nt << 4) + fm) * 32 + fq * 8);
#pragma unroll
            for (int mt = 0; mt < 2; mt++)
#pragma unroll
                for (int nt = 0; nt < 4; nt++)
                    acc[mt][nt] = __builtin_amdgcn_mfma_f32_16x16x32_bf16(gf[mt], bf[nt], acc[mt][nt], 0, 0, 0);
        }
        __syncthreads();
    }

#pragma unroll
    for (int mt = 0; mt < 2; mt++) {
        int rbase = row0 + wrow + (mt << 4) + (fq << 2);
#pragma unroll
        for (int nt = 0; nt < 4; nt++) {
            int c = col0 + (nt << 4) + fm;
            float bcol = bp[c];
#pragma unroll
            for (int reg = 0; reg < 4; reg++) {
                int r = rbase + reg;
                int tok; float g;
                if (z == 0) { tok = r; g = 1.f; }
                else { if (r >= cnt) continue; tok = list[r]; g = gl[r]; }
                atomicAdd(&out[(size_t)tok * 1024 + c], g * (acc[mt][nt][reg] + bcol));
            }
        }
    }
}

// ---------------------------------------------------------------------------
// MFMA flash attention, 128-wide K-tiles (2 barriers per 128 cols).
// Qp[h][s][192]=[qC|qR], Kp=[kR|kC], VT[d][kv].  Causal mask per-element.
// ---------------------------------------------------------------------------
__launch_bounds__(256)
__global__ void attn_mfma(const u16* __restrict__ Qp, const u16* __restrict__ Kp,
                          const u16* __restrict__ VT, u16* __restrict__ O)
{
    const int qt = blockIdx.x, h = blockIdx.y;
    const int q0 = qt * 64;
    const int tid = threadIdx.x;
    const int lane = tid & 63, w = tid >> 6;
    const int fm = lane & 15, fq = lane >> 4;

    __shared__ u16 Ks[2 * 12288];   // 2 halves x 6 chunks x [64 kv][32 k]
    __shared__ u16 Vs[4 * 4096];    // 4 kc x [128 d][32 kv]
    __shared__ u16 Ps[4 * 2048];    // per wave: [4 kc][16 m][32 kv]

    const u16* qrow = Qp + ((size_t)h * 1024 + q0 + w * 16 + fm) * 192;
    short8 qf[6];
#pragma unroll
    for (int c = 0; c < 6; c++)
        qf[c] = *(const short8*)(qrow + c * 32 + fq * 8);

    const u16* Kb = Kp + (size_t)h * 1024 * 192;
    const u16* Vb = VT + (size_t)h * 128 * 1024;

    float m_i[4], l_i[4];
#pragma unroll
    for (int r = 0; r < 4; r++) { m_i[r] = -1e30f; l_i[r] = 0.f; }
    f32x4 accO[8] = {};
    const float scale = 0.07216878364870323f;  // 1/sqrt(192)
    const int nkt = (qt >> 1) + 1;
    const int rbase = w * 16 + fq * 4;

    for (int kt = 0; kt < nkt; ++kt) {
        const int kt0 = kt * 128;
#pragma unroll
        for (int half = 0; half < 2; half++) {
            const int o = kt0 + half * 64;
#pragma unroll
            for (int i = 0; i < 6; i++) {
                int idx = w + 4 * i;
                int c = idx >> 2, k4 = idx & 3;
                const u16* g = Kb + (size_t)(o + k4 * 16 + (lane >> 2)) * 192 + c * 32 + (lane & 3) * 8;
                GLDS16(g, Ks + half * 12288 + c * 2048 + k4 * 512 + lane * 8);
            }
#pragma unroll
            for (int i = 0; i < 4; i++) {
                int idx = w + 4 * i;
                int kc = idx >> 3, k8 = idx & 7;
                const u16* g = Vb + (size_t)(k8 * 16 + (lane >> 2)) * 1024 + o + kc * 32 + (lane & 3) * 8;
                GLDS16(g, Vs + (half * 2 + kc) * 4096 + k8 * 512 + lane * 8);
            }
        }
        __syncthreads();
        // ---- S = Q K^T (48 MFMAs over 128 cols) ----
        f32x4 sacc[8];
#pragma unroll
        for (int nt = 0; nt < 8; nt++) {
            sacc[nt] = (f32x4){0.f, 0.f, 0.f, 0.f};
#pragma unroll
            for (int c = 0; c < 6; c++) {
                short8 kf = *(const short8*)(Ks + (nt >> 2) * 12288 + c * 2048 + ((nt & 3) * 16 + fm) * 32 + fq * 8);
                sacc[nt] = __builtin_amdgcn_mfma_f32_16x16x32_bf16(qf[c], kf, sacc[nt], 0, 0, 0);
            }
        }
        // ---- online softmax (mask: global col index > q row) ----
        float pv[8][4], rmax[4];
#pragma unroll
        for (int reg = 0; reg < 4; reg++) {
            int q = q0 + rbase + reg;
            float mx = -1e30f;
#pragma unroll
            for (int nt = 0; nt < 8; nt++) {
                int gk = kt0 + nt * 16 + fm;
                float s = sacc[nt][reg] * scale;
                if (gk > q) s = -1e30f;
                pv[nt][reg] = s;
                mx = fmaxf(mx, s);
            }
            rmax[reg] = mx;
        }
#pragma unroll
        for (int m = 1; m < 16; m <<= 1)
#pragma unroll
            for (int reg = 0; reg < 4; reg++)
                rmax[reg] = fmaxf(rmax[reg], __shfl_xor(rmax[reg], m));
        float alpha[4], rsum[4];
#pragma unroll
        for (int reg = 0; reg < 4; reg++) {
            float mn = fmaxf(m_i[reg], rmax[reg]);
            alpha[reg] = __expf(m_i[reg] - mn);
            m_i[reg] = mn;
            float s = 0.f;
#pragma unroll
            for (int nt = 0; nt < 8; nt++) {
                float p = __expf(pv[nt][reg] - mn);
                pv[nt][reg] = p;
                s += p;
            }
            rsum[reg] = s;
        }
#pragma unroll
        for (int m = 1; m < 16; m <<= 1)
#pragma unroll
            for (int reg = 0; reg < 4; reg++)
                rsum[reg] += __shfl_xor(rsum[reg], m);
#pragma unroll
        for (int reg = 0; reg < 4; reg++)
            l_i[reg] = l_i[reg] * alpha[reg] + rsum[reg];
        // ---- P (C-layout) -> LDS (A-layout, bf16); per-wave slice ----
#pragma unroll
        for (int nt = 0; nt < 8; nt++)
#pragma unroll
            for (int reg = 0; reg < 4; reg++)
                Ps[w * 2048 + (nt >> 1) * 512 + (fq * 4 + reg) * 32 + (nt & 1) * 16 + fm]
                    = f2b(pv[nt][reg]);
        // ---- rescale O, then O += P V (32 MFMAs) ----
#pragma unroll
        for (int n2 = 0; n2 < 8; n2++)
#pragma unroll
            for (int reg = 0; reg < 4; reg++)
                accO[n2][reg] *= alpha[reg];
        short8 pf[4];
#pragma unroll
        for (int kc = 0; kc < 4; kc++)
            pf[kc] = *(const short8*)(Ps + w * 2048 + kc * 512 + fm * 32 + fq * 8);
#pragma unroll
        for (int n2 = 0; n2 < 8; n2++)
#pragma unroll
            for (int kc = 0; kc < 4; kc++) {
                short8 vf = *(const short8*)(Vs + kc * 4096 + (n2 * 16 + fm) * 32 + fq * 8);
                accO[n2] = __builtin_amdgcn_mfma_f32_16x16x32_bf16(pf[kc], vf, accO[n2], 0, 0, 0);
            }
        __syncthreads();
    }
#pragma unroll
    for (int reg = 0; reg < 4; reg++) {
        int row = q0 + rbase + reg;
        float inv = 1.f / l_i[reg];
#pragma unroll
        for (int n2 = 0; n2 < 8; n2++)
            O[(size_t)row * 1024 + h * 128 + n2 * 16 + fm] = f2b(accO[n2][reg] * inv);
    }
}

// two rmsnorms (bf16 out) in one launch
__launch_bounds__(256)
__global__ void rmsnorm2x(const float* __restrict__ X0, const float* __restrict__ w0,
                          u16* __restrict__ O0, int c0,
                          const float* __restrict__ X1, const float* __restrict__ w1,
                          u16* __restrict__ O1, int c1)
{
    int b = blockIdx.x, tid = threadIdx.x;
    const float* X; const float* w; u16* O; int cols; int r;
    if (b < 1024) { X = X0; w = w0; O = O0; cols = c0; r = b; }
    else          { X = X1; w = w1; O = O1; cols = c1; r = b - 1024; }
    const float* xr = X + (size_t)r * cols;
    float ss = 0.f;
    for (int j = tid; j < cols; j += 256) { float v = xr[j]; ss += v * v; }
    __shared__ float red[256];
    red[tid] = ss; __syncthreads();
    for (int st = 128; st > 0; st >>= 1) { if (tid < st) red[tid] += red[tid + st]; __syncthreads(); }
    float scale = rsqrtf(red[0] / cols + 1e-6f);
    for (int j = tid; j < cols; j += 256)
        O[(size_t)r * cols + j] = f2b(xr[j] * scale * w[j]);
}

// ---------------------------------------------------------------------------
// rmsnorm_route: blocks [0,1024): Y16 = bf16(rmsnorm(X1,ffn_w)); blocks
// [1024,2048): routing (affinity dot pre-scale, sigmoid+top2 post-reduce).
// ---------------------------------------------------------------------------
__launch_bounds__(256)
__global__ void rmsnorm_route(const float* __restrict__ X1, const float* __restrict__ ffnw,
                              u16* __restrict__ Y16,
                              const float* __restrict__ cent, const float* __restrict__ biases,
                              int* __restrict__ counts, int* __restrict__ lists,
                              float* __restrict__ glist)
{
    __shared__ float red[256];
    int b = blockIdx.x, tid = threadIdx.x;
    if (b < 1024) {
        int r = b;
        const float* xr = X1 + (size_t)r * 1024;
        float ss = 0.f;
        for (int j = tid; j < 1024; j += 256) { float v = xr[j]; ss += v * v; }
        red[tid] = ss; __syncthreads();
        for (int st = 128; st > 0; st >>= 1) { if (tid < st) red[tid] += red[tid + st]; __syncthreads(); }
        float scale = rsqrtf(red[0] / 1024.f + 1e-6f);
        for (int j = tid; j < 1024; j += 256)
            Y16[(size_t)r * 1024 + j] = f2b(xr[j] * scale * ffnw[j]);
    } else {
        int t = b - 1024;
        const float* xr = X1 + (size_t)t * 1024;
        float ss = 0.f;
        float acc[8] = {};
        for (int j = tid; j < 1024; j += 256) {
            float x = xr[j];
            ss += x * x;
            float yp = x * ffnw[j];
#pragma unroll
            for (int e = 0; e < 8; e++) acc[e] += yp * cent[e * 1024 + j];
        }
        red[tid] = ss; __syncthreads();
        for (int st = 128; st > 0; st >>= 1) { if (tid < st) red[tid] += red[tid + st]; __syncthreads(); }
        float scale = rsqrtf(red[0] / 1024.f + 1e-6f);
        __syncthreads();
        __shared__ float aff[8];
        for (int e = 0; e < 8; e++) {
            red[tid] = acc[e]; __syncthreads();
            for (int st = 128; st > 0; st >>= 1) { if (tid < st) red[tid] += red[tid + st]; __syncthreads(); }
            if (tid == 0) aff[e] = 1.f / (1.f + expf(-red[0] * scale));
            __syncthreads();
        }
        if (tid == 0) {
            float sb[8];
#pragma unroll
            for (int e = 0; e < 8; e++) sb[e] = aff[e] + biases[e];
            int i0 = 0;
            for (int e = 1; e < 8; e++) if (sb[e] > sb[i0]) i0 = e;
            int i1 = -1;
            for (int e = 0; e < 8; e++) { if (e == i0) continue; if (i1 < 0 || sb[e] > sb[i1]) i1 = e; }
            float a0 = aff[i0], a1 = aff[i1];
            float mx = fmaxf(a0, a1);
            float e0 = expf(a0 - mx), e1 = expf(a1 - mx);
            float inv = 1.f / (e0 + e1);
            int p0 = atomicAdd(&counts[i0], 1);
            lists[i0 * 1024 + p0] = t; glist[i0 * 1024 + p0] = e0 * inv;
            int p1 = atomicAdd(&counts[i1], 1);
            lists[i1 * 1024 + p1] = t; glist[i1 * 1024 + p1] = e1 * inv;
        }
    }
}

// ---------------------------------------------------------------------------
// pack_all: blocks [0,1024): KR rmsnorm+rope, pack Q (QR rope) and K.
// Blocks [1024,1280): transpose V (bf16 [s][d] -> [d][s]).
// ---------------------------------------------------------------------------
__launch_bounds__(256)
__global__ void pack_all(const float* __restrict__ QC, const float* __restrict__ QRr,
                         const float* __restrict__ KRraw, const float* __restrict__ krw,
                         const float* __restrict__ KC,
                         const u16* __restrict__ VCb,
                         const float* __restrict__ fcos, const float* __restrict__ fsin,
                         u16* __restrict__ Qp, u16* __restrict__ Kp, u16* __restrict__ VT)
{
    __shared__ u16 Ts[64][68];
    __shared__ float kshared[64];
    int b = blockIdx.x, tid = threadIdx.x;
    if (b < 1024) {
        int s = b;
        if (tid < 64) {
            float v = KRraw[(size_t)s * 64 + tid];
            float ss = v * v;
#pragma unroll
            for (int m = 1; m < 64; m <<= 1) ss += __shfl_xor(ss, m);
            float scale = rsqrtf(ss / 64.f + 1e-6f);
            int j = tid >> 1;
            float c = fcos[s * 32 + j], sn = fsin[s * 32 + j];
            float x0 = KRraw[(size_t)s * 64 + (tid & ~1)] * scale * krw[tid & ~1];
            float x1 = KRraw[(size_t)s * 64 + (tid | 1)]  * scale * krw[tid | 1];
            kshared[tid] = (tid & 1) ? (x0 * sn + x1 * c) : (x0 * c - x1 * sn);
        }
        __syncthreads();
        for (int e = tid; e < 1536; e += 256) {
            int h = e / 192, d = e % 192;
            float q;
            if (d < 128) {
                q = QC[(size_t)s * 1024 + h * 128 + d];
            } else {
                int dd = d - 128, j = dd >> 1;
                float c = fcos[s * 32 + j], sn = fsin[s * 32 + j];
                float x0 = QRr[(size_t)s * 512 + h * 64 + (dd & ~1)];
                float x1 = QRr[(size_t)s * 512 + h * 64 + (dd | 1)];
                q = (dd & 1) ? (x0 * sn + x1 * c) : (x0 * c - x1 * sn);
            }
            Qp[((size_t)h * 1024 + s) * 192 + d] = f2b(q);
            float k = (d < 64) ? kshared[d]
                               : KC[(size_t)s * 1024 + h * 128 + d - 64];
            Kp[((size_t)h * 1024 + s) * 192 + d] = f2b(k);
        }
    } else {
        int idx = b - 1024;
        int s0 = (idx & 15) * 64, d0 = (idx >> 4) * 64;
        for (int k = 0; k < 16; k++) {
            int e = tid + k * 256, r = e >> 6, c = e & 63;
            Ts[r][c] = VCb[(size_t)(s0 + r) * 1024 + d0 + c];
        }
        __syncthreads();
        for (int k = 0; k < 16; k++) {
            int e = tid + k * 256, d = e >> 6, s = e & 63;
            VT[(size_t)(d0 + d) * 1024 + s0 + s] = Ts[s][d];
        }
    }
}

// ---------------------------------------------------------------------------
// Fused fp32->bf16 cast of 14 weight arrays + the X rmsnorm (blocks >= NCAST).
// ---------------------------------------------------------------------------
#define NCAST 4096
__launch_bounds__(256)
__global__ void fused_cast(const float* p0, const float* p1, const float* p2,
                           const float* p3, const float* p4, const float* p5,
                           const float* p6, const float* p7, const float* p8,
                           const float* p9, const float* p10, const float* p11,
                           const float* p12, const float* pkr,
                           u16* __restrict__ dst,
                           const float* __restrict__ hX, const float* __restrict__ attnw,
                           u16* __restrict__ X16)
{
    __shared__ float red[256];
    int b = blockIdx.x, tid = threadIdx.x;
    if (b < NCAST) {
        const int NQ = 18022400 / 4;   // 17956864 + 65536 (wkr)
        for (int i = b * 256 + tid; i < NQ; i += NCAST * 256) {
            int e = i * 4;
            const float* s; int base;
            if      (e <   786432) { s = p0;  base = 0; }
            else if (e <  1048576) { s = p1;  base =   786432; }
            else if (e <  1835008) { s = p2;  base =  1048576; }
            else if (e <  2228224) { s = p3;  base =  1835008; }
            else if (e <  2490368) { s = p4;  base =  2228224; }
            else if (e <  2752512) { s = p5;  base =  2490368; }
            else if (e <  3801088) { s = p6;  base =  2752512; }
            else if (e <  4325376) { s = p7;  base =  3801088; }
            else if (e <  4849664) { s = p8;  base =  4325376; }
            else if (e <  5373952) { s = p9;  base =  4849664; }
            else if (e <  9568256) { s = p10; base =  5373952; }
            else if (e < 13762560) { s = p11; base =  9568256; }
            else if (e < 17956864) { s = p12; base = 13762560; }
            else                   { s = pkr; base = 17956864; }
            float4 v = *(const float4*)(s + (e - base));
            ushort4 o;
            o.x = f2b(v.x); o.y = f2b(v.y); o.z = f2b(v.z); o.w = f2b(v.w);
            *(ushort4*)(dst + e) = o;
        }
    } else {
        int r = b - NCAST;
        const float* xr = hX + (size_t)r * 1024;
        float ss = 0.f;
        for (int j = tid; j < 1024; j += 256) { float v = xr[j]; ss += v * v; }
        red[tid] = ss; __syncthreads();
        for (int st = 128; st > 0; st >>= 1) { if (tid < st) red[tid] += red[tid + st]; __syncthreads(); }
        float scale = rsqrtf(red[0] / 1024.f + 1e-6f);
        for (int j = tid; j < 1024; j += 256)
            X16[(size_t)r * 1024 + j] = f2b(xr[j] * scale * attnw[j]);
    }
}

// ---------------------------------------------------------------------------
extern "C" void kernel_launch(void* const* d_in, const int* in_sizes, int n_in,
                              void* d_out, int out_size, void* d_ws, size_t ws_size,
                              hipStream_t stream)
{
    (void)in_sizes; (void)n_in; (void)ws_size; (void)out_size;
    const float* h       = (const float*)d_in[0];
    const float* fcos    = (const float*)d_in[1];
    const float* fsin    = (const float*)d_in[2];
    const float* attn_w  = (const float*)d_in[4];
    const float* ffn_w   = (const float*)d_in[5];
    const float* wq_down = (const float*)d_in[6];
    const float* bq_down = (const float*)d_in[7];
    const float* q_norm  = (const float*)d_in[8];
    const float* wqc     = (const float*)d_in[9];
    const float* bqc     = (const float*)d_in[10];
    const float* wqr     = (const float*)d_in[11];
    const float* bqr     = (const float*)d_in[12];
    const float* wkr     = (const float*)d_in[13];
    const float* bkr     = (const float*)d_in[14];
    const float* kr_norm = (const float*)d_in[15];
    const float* wkv     = (const float*)d_in[16];
    const float* bkv     = (const float*)d_in[17];
    const float* kv_norm = (const float*)d_in[18];
    const float* wkc     = (const float*)d_in[19];
    const float* bkc     = (const float*)d_in[20];
    const float* wvc     = (const float*)d_in[21];
    const float* bvc     = (const float*)d_in[22];
    const float* wo      = (const float*)d_in[23];
    const float* bo      = (const float*)d_in[24];
    const float* sw1     = (const float*)d_in[25];
    const float* sb1     = (const float*)d_in[26];
    const float* sw2     = (const float*)d_in[27];
    const float* sb2     = (const float*)d_in[28];
    const float* sw3     = (const float*)d_in[29];
    const float* sb3     = (const float*)d_in[30];
    const float* ew1     = (const float*)d_in[31];
    const float* eb1     = (const float*)d_in[32];
    const float* ew2     = (const float*)d_in[33];
    const float* eb2     = (const float*)d_in[34];
    const float* ew3     = (const float*)d_in[35];
    const float* eb3     = (const float*)d_in[36];
    const float* cent    = (const float*)d_in[37];
    const float* biases  = (const float*)d_in[38];

    char* wsb = (char*)d_ws;
    const size_t U5 = 512 * 1024;  // 0.5 MB unit
    u16*   X16   = (u16*)(wsb + 8 * U5);       // 2 MB
    float* QRr   = (float*)(wsb + 12 * U5);    // 2 MB
    float* CQraw = (float*)(wsb + 16 * U5);    // 3 MB (early)
    u16*   ATT16 = (u16*)(wsb + 16 * U5);      // 2 MB (after CQraw dead)
    u16*   CQ16  = (u16*)(wsb + 22 * U5);      // 1.5 MB
    float* CKVraw= (float*)(wsb + 25 * U5);    // 1 MB
    u16*   CKV16 = (u16*)(wsb + 27 * U5);      // 0.5 MB
    float* KRraw = (float*)(wsb + 28 * U5);    // 0.25 MB
    float* QC    = (float*)(wsb + 29 * U5);    // 4 MB (dead after pack)
    float* KC    = (float*)(wsb + 37 * U5);    // 4 MB (dead after pack)
    u16*   Vb    = (u16*)(wsb + 29 * U5);      // 9 MB (GLU V; overlays QC+KC, 29..46)
    float* X1    = (float*)(wsb + 53 * U5);    // 4 MB
    float* GL    = (float*)(wsb + 61 * U5);
    int*   lists = (int*)(wsb + 61 * U5 + 32 * 1024);
    int*   counts= (int*)(wsb + 61 * U5 + 64 * 1024);
    u16*   Y16   = (u16*)(wsb + 69 * U5);      // 2 MB
    u16*   Ub    = (u16*)(wsb + 73 * U5);      // 9 MB (73..90)

    // bf16 weight arena (contiguous, order matches fused_cast)
    u16* wb = (u16*)(wsb + 92 * U5);
    u16 *c_wq  = wb;
    u16 *c_wkv = c_wq  + 786432;
    u16 *c_wqc = c_wkv + 262144;
    u16 *c_wqr = c_wqc + 786432;
    u16 *c_wkc = c_wqr + 393216;
    u16 *c_wvc = c_wkc + 262144;
    u16 *c_wo  = c_wvc + 262144;
    u16 *c_sw1 = c_wo  + 1048576;
    u16 *c_sw3 = c_sw1 + 524288;
    u16 *c_sw2 = c_sw3 + 524288;
    u16 *c_ew1 = c_sw2 + 524288;
    u16 *c_ew3 = c_ew1 + 4194304;
    u16 *c_ew2 = c_ew3 + 4194304;
    u16 *c_wkr = c_ew2 + 4194304;                 // 64x1024 (exact)
    u16* VCb = (u16*)(wsb + 92 * U5 + 36175872);  // 2 MB bf16 V [s][d]
    u16* VTp = VCb + 1048576;                     // 2 MB bf16 V^T [d][s]
    u16* Qpk = VTp + 1048576;                     // 3 MB
    u16* Kpk = Qpk + 1572864;                     // 3 MB

    // weight cast + X rmsnorm, one launch
    fused_cast<<<NCAST + 1024, 256, 0, stream>>>(wq_down, wkv, wqc, wqr, wkc, wvc, wo,
                                                 sw1, sw3, sw2, ew1, ew3, ew2, wkr, wb,
                                                 h, attn_w, X16);

    // --- attention branch ---
    {
        GArgs g = {};
        g.A[0] = X16; g.lda[0] = 1024; g.K[0] = 1024;
        g.seg[0] = { c_wq,  bq_down, CQraw,  768, 0, 0,  0 };
        g.seg[1] = { c_wkv, bkv,     CKVraw, 256, 0, 12, 0 };
        g.seg[2] = { c_wkr, bkr,     KRraw,  64,  0, 16, 0 };
        g.nseg = 3;
        mgemm4<<<dim3(17, 8), 256, 0, stream>>>(g);
    }
    rmsnorm2x<<<2048, 256, 0, stream>>>(CQraw, q_norm, CQ16, 768,
                                        CKVraw, kv_norm, CKV16, 256);
    {
        GArgs g = {};
        g.A[0] = CQ16;  g.lda[0] = 768; g.K[0] = 768;
        g.A[1] = CKV16; g.lda[1] = 256; g.K[1] = 256;
        g.seg[0] = { c_wqc, bqc, QC,   1024, 0, 0,  0 };
        g.seg[1] = { c_wqr, bqr, QRr,  512,  0, 16, 0 };
        g.seg[2] = { c_wkc, bkc, KC,   1024, 0, 24, 1 };
        g.seg[3] = { c_wvc, bvc, VCb,  1024, 3, 40, 1 };
        g.nseg = 4;
        mgemm4<<<dim3(56, 8), 256, 0, stream>>>(g);
    }
    pack_all<<<1280, 256, 0, stream>>>(QC, QRr, KRraw, kr_norm, KC, VCb, fcos, fsin,
                                       Qpk, Kpk, VTp);
    attn_mfma<<<dim3(16, 8), 256, 0, stream>>>(Qpk, Kpk, VTp, ATT16);
    {
        // wo GEMM: X1 = h + ATT@wo^T, ALSO pre-fills d_out with X1 so the
        // down-projections can accumulate atomically on top.
        GArgs g = {};
        g.A[0] = ATT16; g.lda[0] = 1024; g.K[0] = 1024;
        g.seg[0] = { c_wo, bo, X1, 1024, 1, 0, 0 };
        g.nseg = 1; g.res = h; g.dst2 = (float*)d_out;
        mgemm4<<<dim3(16, 8), 256, 0, stream>>>(g);
    }

    // --- FFN + routing ---
    hipMemsetAsync(counts, 0, 32, stream);
    rmsnorm_route<<<2048, 256, 0, stream>>>(X1, ffn_w, Y16, cent, biases,
                                            counts, lists, GL);
    // shared GLU + all experts' GLU (gathered), one launch
    mega_glu<<<dim3(16, 8, 9), 256, 0, stream>>>(Y16, c_sw1, sb1, c_sw3, sb3,
                                                 c_ew1, eb1, c_ew3, eb3,
                                                 Ub, Vb, lists, counts);
    // shared down + experts' down, fused silu, atomicAdd into d_out
    mega_down<<<dim3(16, 8, 9), 256, 0, stream>>>(Ub, Vb, c_sw2, sb2, c_ew2, eb2,
                                                  (float*)d_out, lists, GL, counts);
}